// Round 6
// baseline (535.266 us; speedup 1.0000x reference)
//
#include <hip/hip_runtime.h>
#include <hip/hip_bf16.h>

#define BB 16
#define LL 2048
#define DD 128
#define SCALE 0.03125f   // 1/sqrt(1024)

#define QT 64
#define KT 64
#define NT (LL/KT)       // 32
#define SPLIT 2
#define HKT (NT/SPLIT)   // 16
#define SPLIT_S 4
#define SKT (NT/SPLIT_S) // 8
#define THREADS 256
#define NWG   (BB*(LL/QT))          // 512  (fallback grid)
#define NWGS  (BB*SPLIT*(LL/QT))    // 1024 (main grid)
#define NWG_S (BB*SPLIT_S*(LL/QT))  // 2048 (sums grid)

using bf16x8 = __attribute__((ext_vector_type(8))) short;
using f32x4  = __attribute__((ext_vector_type(4))) float;
using u16x4  = __attribute__((ext_vector_type(4))) unsigned short;
typedef unsigned long long u64;

__device__ __forceinline__ unsigned short f2bf(float f){
    __hip_bfloat16 h = __float2bfloat16(f);
    return *reinterpret_cast<unsigned short*>(&h);
}
__device__ __forceinline__ float bf2f(unsigned short u){
    union { unsigned u; float f; } a; a.u = ((unsigned)u) << 16;
    return a.f;
}

// Detect mask element layout: 0 = 4-byte int, 1 = 1-byte bool, 2 = 4-byte float.
__global__ void detect_mask(const unsigned* __restrict__ m, int* __restrict__ flag){
    int lane = threadIdx.x & 63;
    unsigned hi = 0, nl = 0;
    #pragma unroll
    for (int i = 0; i < 16; ++i){
        unsigned d = m[lane*16 + i];
        hi |= (d & 0xFFFFFF00u);
        nl |= (d & 0xFEFEFEFEu);
    }
    unsigned long long bh = __ballot(hi != 0u);
    unsigned long long bn = __ballot(nl != 0u);
    if (lane == 0){
        int f = 0;
        if (bn != 0ull) f = 2;
        else if (bh != 0ull) f = 1;
        flag[0] = f;
    }
}

__global__ void prepack_mask(const unsigned char* __restrict__ m,
                             const int* __restrict__ flagp,
                             u64* __restrict__ mb){
    int id = blockIdx.x * THREADS + threadIdx.x;
    int fl = flagp[0];
    u64 bits = 0;
    if (fl == 1){
        const uint4* mp = (const uint4*)(m + (size_t)id * 64);
        #pragma unroll
        for (int c = 0; c < 4; ++c){
            uint4 u = mp[c];
            unsigned wd[4] = {u.x, u.y, u.z, u.w};
            #pragma unroll
            for (int wi = 0; wi < 4; ++wi){
                #pragma unroll
                for (int b = 0; b < 4; ++b)
                    if ((wd[wi] >> (8*b)) & 0xFFu) bits |= 1ull << (c*16 + wi*4 + b);
            }
        }
    } else {
        const uint4* mp = (const uint4*)m + (size_t)id * 16;
        #pragma unroll
        for (int c = 0; c < 16; ++c){
            uint4 u = mp[c];
            if (u.x) bits |= 1ull << (c*4+0);
            if (u.y) bits |= 1ull << (c*4+1);
            if (u.z) bits |= 1ull << (c*4+2);
            if (u.w) bits |= 1ull << (c*4+3);
        }
    }
    mb[id] = bits;
}

// ---------------- staging macros (shared by kernels) ----------------
#define K_LOAD(T) { const float* kp_ = kbase + (size_t)(T)*KT*DD; \
    _Pragma("unroll") for (int i_ = 0; i_ < 8; ++i_) \
        kpre[i_] = *(const f32x4*)(kp_ + (i_*8 + r0)*DD + c4*4); }

#define K_WRITE() { _Pragma("unroll") for (int i_ = 0; i_ < 8; ++i_){ \
        int row_ = i_*8 + r0; int e_ = (c4*4) ^ (8*(row_ & 7)); \
        u16x4 pk_ = { f2bf(kpre[i_][0]), f2bf(kpre[i_][1]), f2bf(kpre[i_][2]), f2bf(kpre[i_][3]) }; \
        *(u16x4*)(&k_s[row_*DD + e_]) = pk_; } }

// V prefetch into persistent regs (loads issue in compute phase of prev tile)
#define V_LOAD(T) { const float* vp_ = vbase + (size_t)(T)*KT*DD; \
    _Pragma("unroll") for (int i_ = 0; i_ < 2; ++i_) \
        _Pragma("unroll") for (int rr_ = 0; rr_ < 4; ++rr_) \
            vpre[i_][rr_] = *(const f32x4*)(vp_ + ((r0 + 8*i_)*4 + rr_)*DD + c4*4); }

#define V_WRITE() { _Pragma("unroll") for (int i_ = 0; i_ < 2; ++i_){ \
        int rb_ = (r0 + 8*i_)*4; int kk_ = rb_ ^ (8*(c4 & 7)); \
        _Pragma("unroll") for (int cc_ = 0; cc_ < 4; ++cc_){ \
            int d_ = c4*4 + cc_; \
            u16x4 pk_ = { f2bf(vpre[i_][0][cc_]), f2bf(vpre[i_][1][cc_]), \
                          f2bf(vpre[i_][2][cc_]), f2bf(vpre[i_][3][cc_]) }; \
            *(u16x4*)(&vT_s[d_*KT + kk_]) = pk_; } } }

#define M_LOADB(DST, T) { _Pragma("unroll") for (int r_ = 0; r_ < 4; ++r_) DST[r_] = mbB[r_*NT + (T)]; }

#define QK_MFMA(ACC, CG) { \
    const int krow_ = (CG)*16 + ln15; \
    const unsigned short* kb_ = &k_s[krow_*DD]; \
    const int sw_ = 8*(krow_ & 7); \
    _Pragma("unroll") for (int c_ = 0; c_ < 4; ++c_){ \
        bf16x8 bf_ = *(const bf16x8*)(kb_ + ((c_*32 + g*8) ^ sw_)); \
        ACC = __builtin_amdgcn_mfma_f32_16x16x32_bf16(qa[c_], bf_, ACC, 0, 0, 0); } }

#define Q_FRAGS() { \
    const float* qp_ = q + ((size_t)bb*LL + qw0 + ln15)*DD + g*8; \
    _Pragma("unroll") for (int c_ = 0; c_ < 4; ++c_){ \
        f32x4 x_ = *(const f32x4*)(qp_ + c_*32); \
        f32x4 y_ = *(const f32x4*)(qp_ + c_*32 + 4); \
        bf16x8 t_; \
        t_[0]=(short)f2bf(x_[0]); t_[1]=(short)f2bf(x_[1]); t_[2]=(short)f2bf(x_[2]); t_[3]=(short)f2bf(x_[3]); \
        t_[4]=(short)f2bf(y_[0]); t_[5]=(short)f2bf(y_[1]); t_[6]=(short)f2bf(y_[2]); t_[7]=(short)f2bf(y_[3]); \
        qa[c_] = t_; } }

// ================= split kernel 1: partial row sums (SPLIT_S=4) =================
// launch_bounds 4 (NOT 5): 5 capped VGPR at ~102 < live set -> scratch spill in
// the K-loop was ~2x on this kernel (round 4/5 regression).
__global__ __launch_bounds__(THREADS, 4) void attn_sums(
    const float* __restrict__ q, const float* __restrict__ k,
    const u64* __restrict__ mb, float* __restrict__ lpart)
{
    __shared__ __attribute__((aligned(16))) unsigned short k_s[KT*DD];   // 16 KB

    const int tid  = threadIdx.x;
    const int w    = tid >> 6;
    const int lane = tid & 63;
    const int ln15 = lane & 15;
    const int g    = lane >> 4;
    const int r0   = tid >> 5;
    const int c4   = tid & 31;

    const int hw    = blockIdx.x;
    const int bidx  = (hw & 7) * (NWG_S/8) + (hw >> 3);   // XCD-contiguous
    const int bb    = bidx >> 7;                          // /128
    const int quart = (bidx >> 5) & 3;
    const int qt0   = (bidx & 31) * QT;
    const int qw0   = qt0 + w*16;

    bf16x8 qa[4];
    Q_FRAGS();

    const u64* mbB = mb + ((size_t)bb*LL + qw0 + 4*g) * NT;

    const float* kbase = k + (size_t)bb*LL*DD;
    f32x4 kpre[8];
    u64 mc[4] = {0,0,0,0}, mn[4] = {0,0,0,0};

    const int T0 = quart * SKT;
    float rs[4] = {0.f, 0.f, 0.f, 0.f};
    K_LOAD(T0); M_LOADB(mc, T0);
    for (int tt = 0; tt < SKT; ++tt){
        const int t = T0 + tt;
        __syncthreads();
        K_WRITE();
        if (tt+1 < SKT){ K_LOAD(t+1); M_LOADB(mn, t+1); }
        __syncthreads();
        #pragma unroll
        for (int cg = 0; cg < 4; ++cg){
            f32x4 acc = {0.f, 0.f, 0.f, 0.f};
            QK_MFMA(acc, cg);
            const int kc = cg*16 + ln15;
            #pragma unroll
            for (int r = 0; r < 4; ++r){
                bool msk = (mc[r] >> kc) & 1ull;
                rs[r] += msk ? 0.f : __expf(acc[r] * SCALE);
            }
        }
        #pragma unroll
        for (int r = 0; r < 4; ++r) mc[r] = mn[r];
    }
    #pragma unroll
    for (int r = 0; r < 4; ++r){
        float s = rs[r];
        s += __shfl_xor(s, 1); s += __shfl_xor(s, 2);
        s += __shfl_xor(s, 4); s += __shfl_xor(s, 8);
        if (ln15 == 0)
            lpart[(size_t)quart*BB*LL + (size_t)bb*LL + qw0 + 4*g + r] = s;
    }
}

// ============ split kernel 2: attn write + partial PV (SPLIT=2) ============
// V prefetched in persistent regs: its HBM latency hides under the previous
// tile's compute phase (round-5's V_STAGE put it naked between barriers).
__global__ __launch_bounds__(THREADS, 4) void attn_main(
    const float* __restrict__ q, const float* __restrict__ k, const float* __restrict__ v,
    const u64* __restrict__ mb, const float* __restrict__ lpart,
    float* __restrict__ attn, float* __restrict__ pO)
{
    __shared__ __attribute__((aligned(16))) unsigned short k_s[KT*DD];    // 16 KB
    __shared__ __attribute__((aligned(16))) unsigned short vT_s[DD*KT];   // 16 KB
    __shared__ __attribute__((aligned(16))) unsigned short p_bf[4*16*64]; // 8 KB

    const int tid  = threadIdx.x;
    const int w    = tid >> 6;
    const int lane = tid & 63;
    const int ln15 = lane & 15;
    const int g    = lane >> 4;
    const int r0   = tid >> 5;
    const int c4   = tid & 31;

    const int hw   = blockIdx.x;
    const int bidx = (hw & 7) * (NWGS/8) + (hw >> 3);
    const int bb   = bidx >> 6;
    const int half = (bidx >> 5) & 1;
    const int qt0  = (bidx & 31) * QT;
    const int qw0  = qt0 + w*16;

    bf16x8 qa[4];
    Q_FRAGS();

    const u64* mbB = mb + ((size_t)bb*LL + qw0 + 4*g) * NT;
    float invl[4];
    #pragma unroll
    for (int r = 0; r < 4; ++r){
        size_t row = (size_t)bb*LL + qw0 + 4*g + r;
        float s = 0.f;
        #pragma unroll
        for (int sl = 0; sl < SPLIT_S; ++sl)
            s += lpart[(size_t)sl*BB*LL + row];
        invl[r] = 1.0f / s;
    }

    const float* kbase = k + (size_t)bb*LL*DD;
    const float* vbase = v + (size_t)bb*LL*DD;
    f32x4 kpre[8];
    f32x4 vpre[2][4];
    u64 mc[4] = {0,0,0,0};

    f32x4 oacc[8];
    #pragma unroll
    for (int d8 = 0; d8 < 8; ++d8) oacc[d8] = (f32x4){0.f, 0.f, 0.f, 0.f};

    unsigned short* pw = &p_bf[w*1024];   // 16 rows x 64 cols bf16
    const int w4 = ln15 >> 2;             // reader-side swizzle key (= writer g)

    const int T0 = half * HKT;
    K_LOAD(T0); V_LOAD(T0);
    for (int tt = 0; tt < HKT; ++tt){
        const int t = T0 + tt;
        __syncthreads();
        K_WRITE(); V_WRITE();
        if (tt+1 < HKT){ K_LOAD(t+1); V_LOAD(t+1); }
        M_LOADB(mc, t);
        __syncthreads();
        #pragma unroll
        for (int cg = 0; cg < 4; ++cg){
            f32x4 acc = {0.f, 0.f, 0.f, 0.f};
            QK_MFMA(acc, cg);
            const int kc = cg*16 + ln15;
            #pragma unroll
            for (int r = 0; r < 4; ++r){
                bool msk = (mc[r] >> kc) & 1ull;
                float p = msk ? 0.f : __expf(acc[r] * SCALE) * invl[r];
                pw[(4*g + r)*64 + (kc ^ (g << 4))] = f2bf(p);
            }
        }
        // vectorized attn stores: lane reads 4 bf16 of one row, stores f32x4
        #pragma unroll
        for (int it = 0; it < 4; ++it){
            int row = it*4 + g;                      // row>>2 == it (writer key)
            u16x4 pb = *(const u16x4*)(&pw[row*64 + ((ln15*4) ^ (it << 4))]);
            f32x4 val = { bf2f(pb[0]), bf2f(pb[1]), bf2f(pb[2]), bf2f(pb[3]) };
            *(f32x4*)(&attn[((size_t)bb*LL + qw0 + row)*(size_t)LL + t*KT + ln15*4]) = val;
        }
        // PV: A-frags from bf16 P (swizzled, contiguous b128), B-frags from vT
        const unsigned short* par = pw + ln15*64;
        bf16x8 pa0 = *(const bf16x8*)(par + ((g*8)      ^ (w4 << 4)));
        bf16x8 pa1 = *(const bf16x8*)(par + ((32 + g*8) ^ (w4 << 4)));
        #pragma unroll
        for (int d8 = 0; d8 < 8; ++d8){
            const int d = d8*16 + ln15;
            const unsigned short* vb = &vT_s[d*KT];
            const int ev = 8*((4*d8 + (ln15 >> 2)) & 7);
            bf16x8 b0 = *(const bf16x8*)(vb + ((g*8) ^ ev));
            bf16x8 b1 = *(const bf16x8*)(vb + ((32 + g*8) ^ ev));
            oacc[d8] = __builtin_amdgcn_mfma_f32_16x16x32_bf16(pa0, b0, oacc[d8], 0, 0, 0);
            oacc[d8] = __builtin_amdgcn_mfma_f32_16x16x32_bf16(pa1, b1, oacc[d8], 0, 0, 0);
        }
    }

    // epilogue: partial O (plain stores; 64B segments per 16-lane group)
    float* po = pO + (size_t)half*BB*LL*DD;
    #pragma unroll
    for (int d8 = 0; d8 < 8; ++d8){
        #pragma unroll
        for (int r = 0; r < 4; ++r){
            po[((size_t)bb*LL + qw0 + 4*g + r)*DD + d8*16 + ln15] = oacc[d8][r];
        }
    }
}

__global__ void combine_out(const float* __restrict__ pO, float* __restrict__ out){
    size_t i = ((size_t)blockIdx.x*THREADS + threadIdx.x) * 4;
    f32x4 a = *(const f32x4*)(pO + i);
    f32x4 b = *(const f32x4*)(pO + (size_t)BB*LL*DD + i);
    *(f32x4*)(out + i) = a + b;
}

// ================= fallback: fused two-pass =================
template<int USE_BITS>
__global__ __launch_bounds__(THREADS, 3) void attn_fused(
    const float* __restrict__ q, const float* __restrict__ k, const float* __restrict__ v,
    const unsigned char* __restrict__ maskb, const int* __restrict__ flagp,
    const u64* __restrict__ mb,
    float* __restrict__ out, float* __restrict__ attn)
{
    __shared__ __attribute__((aligned(16))) unsigned short k_s[KT*DD];
    __shared__ __attribute__((aligned(16))) unsigned short vT_s[DD*KT];
    __shared__ __attribute__((aligned(16))) unsigned short p_bf[4*16*64];

    const int tid  = threadIdx.x;
    const int w    = tid >> 6;
    const int lane = tid & 63;
    const int ln15 = lane & 15;
    const int g    = lane >> 4;
    const int r0   = tid >> 5;
    const int c4   = tid & 31;

    const int bidx = blockIdx.x;
    const int bb   = bidx >> 5;
    const int qt0  = (bidx & 31) * QT;
    const int qw0  = qt0 + w*16;

    int msh = 0, madd = 0;
    if (!USE_BITS){
        const int mflag = flagp[0];
        msh  = (mflag == 1) ? 0 : 2;
        madd = (mflag == 2) ? 3 : 0;
    }

    bf16x8 qa[4];
    Q_FRAGS();

    size_t mrow[4];
    const u64* mbB = mb + ((size_t)bb*LL + qw0 + 4*g) * NT;
    #pragma unroll
    for (int r = 0; r < 4; ++r)
        mrow[r] = ((size_t)bb*LL + qw0 + 4*g + r) * (size_t)LL;

    const float* kbase = k + (size_t)bb*LL*DD;
    const float* vbase = v + (size_t)bb*LL*DD;

    f32x4 kpre[8];
    f32x4 vpre[2][4];
    u64 mc[4] = {0,0,0,0}, mn[4] = {0,0,0,0};

    float rs[4] = {0.f, 0.f, 0.f, 0.f};
    K_LOAD(0); if (USE_BITS) M_LOADB(mc, 0);
    for (int t = 0; t < NT; ++t){
        __syncthreads();
        K_WRITE();
        if (t+1 < NT){ K_LOAD(t+1); if (USE_BITS) M_LOADB(mn, t+1); }
        __syncthreads();
        #pragma unroll
        for (int cg = 0; cg < 4; ++cg){
            f32x4 acc = {0.f, 0.f, 0.f, 0.f};
            QK_MFMA(acc, cg);
            const int kc = cg*16 + ln15;
            #pragma unroll
            for (int r = 0; r < 4; ++r){
                bool msk;
                if (USE_BITS) msk = (mc[r] >> kc) & 1ull;
                else          msk = maskb[((mrow[r] + t*KT + kc) << msh) + madd] != 0;
                rs[r] += msk ? 0.f : __expf(acc[r] * SCALE);
            }
        }
        if (USE_BITS){
            #pragma unroll
            for (int r = 0; r < 4; ++r) mc[r] = mn[r];
        }
    }

    float invl[4];
    #pragma unroll
    for (int r = 0; r < 4; ++r){
        float s = rs[r];
        s += __shfl_xor(s, 1); s += __shfl_xor(s, 2);
        s += __shfl_xor(s, 4); s += __shfl_xor(s, 8);
        invl[r] = 1.0f / s;
    }

    f32x4 oacc[8];
    #pragma unroll
    for (int d8 = 0; d8 < 8; ++d8) oacc[d8] = (f32x4){0.f, 0.f, 0.f, 0.f};

    unsigned short* pw = &p_bf[w*1024];
    const int w4 = ln15 >> 2;

    K_LOAD(0); V_LOAD(0); if (USE_BITS) M_LOADB(mc, 0);
    for (int t = 0; t < NT; ++t){
        __syncthreads();
        K_WRITE(); V_WRITE();
        if (t+1 < NT){ K_LOAD(t+1); V_LOAD(t+1); if (USE_BITS) M_LOADB(mn, t+1); }
        __syncthreads();
        #pragma unroll
        for (int cg = 0; cg < 4; ++cg){
            f32x4 acc = {0.f, 0.f, 0.f, 0.f};
            QK_MFMA(acc, cg);
            const int kc = cg*16 + ln15;
            #pragma unroll
            for (int r = 0; r < 4; ++r){
                bool msk;
                if (USE_BITS) msk = (mc[r] >> kc) & 1ull;
                else          msk = maskb[((mrow[r] + t*KT + kc) << msh) + madd] != 0;
                float p = msk ? 0.f : __expf(acc[r] * SCALE) * invl[r];
                pw[(4*g + r)*64 + (kc ^ (g << 4))] = f2bf(p);
            }
        }
        #pragma unroll
        for (int it = 0; it < 4; ++it){
            int row = it*4 + g;
            u16x4 pb = *(const u16x4*)(&pw[row*64 + ((ln15*4) ^ (it << 4))]);
            f32x4 val = { bf2f(pb[0]), bf2f(pb[1]), bf2f(pb[2]), bf2f(pb[3]) };
            *(f32x4*)(&attn[((size_t)bb*LL + qw0 + row)*(size_t)LL + t*KT + ln15*4]) = val;
        }
        const unsigned short* par = pw + ln15*64;
        bf16x8 pa0 = *(const bf16x8*)(par + ((g*8)      ^ (w4 << 4)));
        bf16x8 pa1 = *(const bf16x8*)(par + ((32 + g*8) ^ (w4 << 4)));
        #pragma unroll
        for (int d8 = 0; d8 < 8; ++d8){
            const int d = d8*16 + ln15;
            const unsigned short* vb = &vT_s[d*KT];
            const int ev = 8*((4*d8 + (ln15 >> 2)) & 7);
            bf16x8 b0 = *(const bf16x8*)(vb + ((g*8) ^ ev));
            bf16x8 b1 = *(const bf16x8*)(vb + ((32 + g*8) ^ ev));
            oacc[d8] = __builtin_amdgcn_mfma_f32_16x16x32_bf16(pa0, b0, oacc[d8], 0, 0, 0);
            oacc[d8] = __builtin_amdgcn_mfma_f32_16x16x32_bf16(pa1, b1, oacc[d8], 0, 0, 0);
        }
        if (USE_BITS){
            #pragma unroll
            for (int r = 0; r < 4; ++r) mc[r] = mn[r];
        }
    }

    #pragma unroll
    for (int d8 = 0; d8 < 8; ++d8){
        #pragma unroll
        for (int r = 0; r < 4; ++r){
            out[((size_t)bb*LL + qw0 + 4*g + r)*DD + d8*16 + ln15] = oacc[d8][r];
        }
    }
}

extern "C" void kernel_launch(void* const* d_in, const int* in_sizes, int n_in,
                              void* d_out, int out_size, void* d_ws, size_t ws_size,
                              hipStream_t stream)
{
    const float* q = (const float*)d_in[0];
    const float* k = (const float*)d_in[1];
    const float* v = (const float*)d_in[2];
    const unsigned char* mask = (const unsigned char*)d_in[3];

    float* out  = (float*)d_out;
    float* attn = out + (size_t)BB*LL*DD;

    const size_t bits_sz = (size_t)BB*LL*NT*sizeof(u64);           // 8 MB
    const size_t off_l   = 256 + bits_sz;
    const size_t l_sz    = (size_t)SPLIT_S*BB*LL*sizeof(float);    // 512 KB
    const size_t off_pO  = off_l + l_sz;
    const size_t pO_sz   = (size_t)SPLIT*BB*LL*DD*sizeof(float);   // 32 MB
    const size_t need_split = off_pO + pO_sz;
    const size_t need_bits  = 256 + bits_sz;

    int*   flag  = (int*)d_ws;
    u64*   mb    = (u64*)((char*)d_ws + 256);
    float* lpart = (float*)((char*)d_ws + off_l);
    float* pO    = (float*)((char*)d_ws + off_pO);

    detect_mask<<<1, 64, 0, stream>>>((const unsigned*)mask, flag);
    if (ws_size >= need_split){
        prepack_mask<<<(BB*LL*NT)/THREADS, THREADS, 0, stream>>>(mask, flag, mb);
        attn_sums<<<NWG_S, THREADS, 0, stream>>>(q, k, mb, lpart);
        attn_main<<<NWGS, THREADS, 0, stream>>>(q, k, v, mb, lpart, attn, pO);
        combine_out<<<(BB*LL*DD)/(4*THREADS), THREADS, 0, stream>>>(pO, out);
    } else if (ws_size >= need_bits){
        prepack_mask<<<(BB*LL*NT)/THREADS, THREADS, 0, stream>>>(mask, flag, mb);
        attn_fused<1><<<NWG, THREADS, 0, stream>>>(q, k, v, mask, flag, mb, out, attn);
    } else {
        attn_fused<0><<<NWG, THREADS, 0, stream>>>(q, k, v, mask, flag, mb, out, attn);
    }
}

// Round 7
// 337.670 us; speedup vs baseline: 1.5852x; 1.5852x over previous
//
#include <hip/hip_runtime.h>
#include <hip/hip_bf16.h>

#define BB 16
#define LL 2048
#define DD 128
#define SCALE 0.03125f   // 1/sqrt(1024)

#define QT 64
#define KT 64
#define NT (LL/KT)       // 32
#define SPLIT 2
#define HKT (NT/SPLIT)   // 16
#define SPLIT_S 4
#define SKT (NT/SPLIT_S) // 8
#define THREADS 256
#define NWG   (BB*(LL/QT))          // 512  (fallback grid)
#define NWGS  (BB*SPLIT*(LL/QT))    // 1024 (main grid)
#define NWG_S (BB*SPLIT_S*(LL/QT))  // 2048 (sums grid)

using bf16x8 = __attribute__((ext_vector_type(8))) short;
using f32x4  = __attribute__((ext_vector_type(4))) float;
using u16x4  = __attribute__((ext_vector_type(4))) unsigned short;
typedef unsigned long long u64;

__device__ __forceinline__ unsigned short f2bf(float f){
    __hip_bfloat16 h = __float2bfloat16(f);
    return *reinterpret_cast<unsigned short*>(&h);
}
__device__ __forceinline__ float bf2f(unsigned short u){
    union { unsigned u; float f; } a; a.u = ((unsigned)u) << 16;
    return a.f;
}

// Detect mask element layout: 0 = 4-byte int, 1 = 1-byte bool, 2 = 4-byte float.
__global__ void detect_mask(const unsigned* __restrict__ m, int* __restrict__ flag){
    int lane = threadIdx.x & 63;
    unsigned hi = 0, nl = 0;
    #pragma unroll
    for (int i = 0; i < 16; ++i){
        unsigned d = m[lane*16 + i];
        hi |= (d & 0xFFFFFF00u);
        nl |= (d & 0xFEFEFEFEu);
    }
    unsigned long long bh = __ballot(hi != 0u);
    unsigned long long bn = __ballot(nl != 0u);
    if (lane == 0){
        int f = 0;
        if (bn != 0ull) f = 2;
        else if (bh != 0ull) f = 1;
        flag[0] = f;
    }
}

__global__ void prepack_mask(const unsigned char* __restrict__ m,
                             const int* __restrict__ flagp,
                             u64* __restrict__ mb){
    int id = blockIdx.x * THREADS + threadIdx.x;
    int fl = flagp[0];
    u64 bits = 0;
    if (fl == 1){
        const uint4* mp = (const uint4*)(m + (size_t)id * 64);
        #pragma unroll
        for (int c = 0; c < 4; ++c){
            uint4 u = mp[c];
            unsigned wd[4] = {u.x, u.y, u.z, u.w};
            #pragma unroll
            for (int wi = 0; wi < 4; ++wi){
                #pragma unroll
                for (int b = 0; b < 4; ++b)
                    if ((wd[wi] >> (8*b)) & 0xFFu) bits |= 1ull << (c*16 + wi*4 + b);
            }
        }
    } else {
        const uint4* mp = (const uint4*)m + (size_t)id * 16;
        #pragma unroll
        for (int c = 0; c < 16; ++c){
            uint4 u = mp[c];
            if (u.x) bits |= 1ull << (c*4+0);
            if (u.y) bits |= 1ull << (c*4+1);
            if (u.z) bits |= 1ull << (c*4+2);
            if (u.w) bits |= 1ull << (c*4+3);
        }
    }
    mb[id] = bits;
}

// ---------------- staging macros (shared by kernels) ----------------
#define K_LOAD(T) { const float* kp_ = kbase + (size_t)(T)*KT*DD; \
    _Pragma("unroll") for (int i_ = 0; i_ < 8; ++i_) \
        kpre[i_] = *(const f32x4*)(kp_ + (i_*8 + r0)*DD + c4*4); }

#define K_WRITE() { _Pragma("unroll") for (int i_ = 0; i_ < 8; ++i_){ \
        int row_ = i_*8 + r0; int e_ = (c4*4) ^ (8*(row_ & 7)); \
        u16x4 pk_ = { f2bf(kpre[i_][0]), f2bf(kpre[i_][1]), f2bf(kpre[i_][2]), f2bf(kpre[i_][3]) }; \
        *(u16x4*)(&k_s[row_*DD + e_]) = pk_; } }

// V: load + convert + write in one phase (TRANSIENT regs only — fits the
// 64-VGPR allocation; persistent vpre across the barrier spilled, r6: 224->404us)
#define V_STAGE(T) { const float* vp_ = vbase + (size_t)(T)*KT*DD; \
    _Pragma("unroll") for (int i_ = 0; i_ < 2; ++i_){ \
        f32x4 vv_[4]; \
        _Pragma("unroll") for (int rr_ = 0; rr_ < 4; ++rr_) \
            vv_[rr_] = *(const f32x4*)(vp_ + ((r0 + 8*i_)*4 + rr_)*DD + c4*4); \
        int rb_ = (r0 + 8*i_)*4; int kk_ = rb_ ^ (8*(c4 & 7)); \
        _Pragma("unroll") for (int cc_ = 0; cc_ < 4; ++cc_){ \
            int d_ = c4*4 + cc_; \
            u16x4 pk_ = { f2bf(vv_[0][cc_]), f2bf(vv_[1][cc_]), \
                          f2bf(vv_[2][cc_]), f2bf(vv_[3][cc_]) }; \
            *(u16x4*)(&vT_s[d_*KT + kk_]) = pk_; } } }

#define M_LOADB(DST, T) { _Pragma("unroll") for (int r_ = 0; r_ < 4; ++r_) DST[r_] = mbB[r_*NT + (T)]; }

#define QK_MFMA(ACC, CG) { \
    const int krow_ = (CG)*16 + ln15; \
    const unsigned short* kb_ = &k_s[krow_*DD]; \
    const int sw_ = 8*(krow_ & 7); \
    _Pragma("unroll") for (int c_ = 0; c_ < 4; ++c_){ \
        bf16x8 bf_ = *(const bf16x8*)(kb_ + ((c_*32 + g*8) ^ sw_)); \
        ACC = __builtin_amdgcn_mfma_f32_16x16x32_bf16(qa[c_], bf_, ACC, 0, 0, 0); } }

#define Q_FRAGS() { \
    const float* qp_ = q + ((size_t)bb*LL + qw0 + ln15)*DD + g*8; \
    _Pragma("unroll") for (int c_ = 0; c_ < 4; ++c_){ \
        f32x4 x_ = *(const f32x4*)(qp_ + c_*32); \
        f32x4 y_ = *(const f32x4*)(qp_ + c_*32 + 4); \
        bf16x8 t_; \
        t_[0]=(short)f2bf(x_[0]); t_[1]=(short)f2bf(x_[1]); t_[2]=(short)f2bf(x_[2]); t_[3]=(short)f2bf(x_[3]); \
        t_[4]=(short)f2bf(y_[0]); t_[5]=(short)f2bf(y_[1]); t_[6]=(short)f2bf(y_[2]); t_[7]=(short)f2bf(y_[3]); \
        qa[c_] = t_; } }

// ================= split kernel 1: partial row sums (SPLIT_S=4) =================
// launch_bounds 4 (NOT 5): 5 forced spill (r5: sums ~230us); 4 is clean (r6).
__global__ __launch_bounds__(THREADS, 4) void attn_sums(
    const float* __restrict__ q, const float* __restrict__ k,
    const u64* __restrict__ mb, float* __restrict__ lpart)
{
    __shared__ __attribute__((aligned(16))) unsigned short k_s[KT*DD];   // 16 KB

    const int tid  = threadIdx.x;
    const int w    = tid >> 6;
    const int lane = tid & 63;
    const int ln15 = lane & 15;
    const int g    = lane >> 4;
    const int r0   = tid >> 5;
    const int c4   = tid & 31;

    const int hw    = blockIdx.x;
    const int bidx  = (hw & 7) * (NWG_S/8) + (hw >> 3);   // XCD-contiguous
    const int bb    = bidx >> 7;                          // /128
    const int quart = (bidx >> 5) & 3;
    const int qt0   = (bidx & 31) * QT;
    const int qw0   = qt0 + w*16;

    bf16x8 qa[4];
    Q_FRAGS();

    const u64* mbB = mb + ((size_t)bb*LL + qw0 + 4*g) * NT;

    const float* kbase = k + (size_t)bb*LL*DD;
    f32x4 kpre[8];
    u64 mc[4] = {0,0,0,0}, mn[4] = {0,0,0,0};

    const int T0 = quart * SKT;
    float rs[4] = {0.f, 0.f, 0.f, 0.f};
    K_LOAD(T0); M_LOADB(mc, T0);
    for (int tt = 0; tt < SKT; ++tt){
        const int t = T0 + tt;
        __syncthreads();
        K_WRITE();
        if (tt+1 < SKT){ K_LOAD(t+1); M_LOADB(mn, t+1); }
        __syncthreads();
        #pragma unroll
        for (int cg = 0; cg < 4; ++cg){
            f32x4 acc = {0.f, 0.f, 0.f, 0.f};
            QK_MFMA(acc, cg);
            const int kc = cg*16 + ln15;
            #pragma unroll
            for (int r = 0; r < 4; ++r){
                bool msk = (mc[r] >> kc) & 1ull;
                rs[r] += msk ? 0.f : __expf(acc[r] * SCALE);
            }
        }
        #pragma unroll
        for (int r = 0; r < 4; ++r) mc[r] = mn[r];
    }
    #pragma unroll
    for (int r = 0; r < 4; ++r){
        float s = rs[r];
        s += __shfl_xor(s, 1); s += __shfl_xor(s, 2);
        s += __shfl_xor(s, 4); s += __shfl_xor(s, 8);
        if (ln15 == 0)
            lpart[(size_t)quart*BB*LL + (size_t)bb*LL + qw0 + 4*g + r] = s;
    }
}

// ============ split kernel 2: attn write + partial PV (SPLIT=2) ============
// Round-5 structure (224us measured) + nontemporal VECTOR attn stores.
__global__ __launch_bounds__(THREADS, 4) void attn_main(
    const float* __restrict__ q, const float* __restrict__ k, const float* __restrict__ v,
    const u64* __restrict__ mb, const float* __restrict__ lpart,
    float* __restrict__ attn, float* __restrict__ pO)
{
    __shared__ __attribute__((aligned(16))) unsigned short k_s[KT*DD];    // 16 KB
    __shared__ __attribute__((aligned(16))) unsigned short vT_s[DD*KT];   // 16 KB
    __shared__ __attribute__((aligned(16))) unsigned short p_bf[4*16*64]; // 8 KB

    const int tid  = threadIdx.x;
    const int w    = tid >> 6;
    const int lane = tid & 63;
    const int ln15 = lane & 15;
    const int g    = lane >> 4;
    const int r0   = tid >> 5;
    const int c4   = tid & 31;

    const int hw   = blockIdx.x;
    const int bidx = (hw & 7) * (NWGS/8) + (hw >> 3);
    const int bb   = bidx >> 6;
    const int half = (bidx >> 5) & 1;
    const int qt0  = (bidx & 31) * QT;
    const int qw0  = qt0 + w*16;

    bf16x8 qa[4];
    Q_FRAGS();

    const u64* mbB = mb + ((size_t)bb*LL + qw0 + 4*g) * NT;
    float invl[4];
    #pragma unroll
    for (int r = 0; r < 4; ++r){
        size_t row = (size_t)bb*LL + qw0 + 4*g + r;
        float s = 0.f;
        #pragma unroll
        for (int sl = 0; sl < SPLIT_S; ++sl)
            s += lpart[(size_t)sl*BB*LL + row];
        invl[r] = 1.0f / s;
    }

    const float* kbase = k + (size_t)bb*LL*DD;
    const float* vbase = v + (size_t)bb*LL*DD;
    f32x4 kpre[8];
    u64 mc[4] = {0,0,0,0};

    f32x4 oacc[8];
    #pragma unroll
    for (int d8 = 0; d8 < 8; ++d8) oacc[d8] = (f32x4){0.f, 0.f, 0.f, 0.f};

    unsigned short* pw = &p_bf[w*1024];   // 16 rows x 64 cols bf16
    const int w4 = ln15 >> 2;             // reader-side swizzle key (= writer g)

    const int T0 = half * HKT;
    K_LOAD(T0);
    for (int tt = 0; tt < HKT; ++tt){
        const int t = T0 + tt;
        __syncthreads();
        K_WRITE();
        V_STAGE(t);
        if (tt+1 < HKT) K_LOAD(t+1);
        M_LOADB(mc, t);
        __syncthreads();
        #pragma unroll
        for (int cg = 0; cg < 4; ++cg){
            f32x4 acc = {0.f, 0.f, 0.f, 0.f};
            QK_MFMA(acc, cg);
            const int kc = cg*16 + ln15;
            #pragma unroll
            for (int r = 0; r < 4; ++r){
                bool msk = (mc[r] >> kc) & 1ull;
                float p = msk ? 0.f : __expf(acc[r] * SCALE) * invl[r];
                pw[(4*g + r)*64 + (kc ^ (g << 4))] = f2bf(p);
            }
        }
        // vectorized NONTEMPORAL attn stores: 16B/lane, 256B contiguous per
        // 16-lane row -> full 64B sectors (no RMW; r4's disaster was 4B NT).
        #pragma unroll
        for (int it = 0; it < 4; ++it){
            int row = it*4 + g;                      // row>>2 == it (writer key)
            u16x4 pb = *(const u16x4*)(&pw[row*64 + ((ln15*4) ^ (it << 4))]);
            f32x4 val = { bf2f(pb[0]), bf2f(pb[1]), bf2f(pb[2]), bf2f(pb[3]) };
            __builtin_nontemporal_store(val,
                (f32x4*)(&attn[((size_t)bb*LL + qw0 + row)*(size_t)LL + t*KT + ln15*4]));
        }
        // PV: A-frags from bf16 P (swizzled, contiguous b128), B-frags from vT
        const unsigned short* par = pw + ln15*64;
        bf16x8 pa0 = *(const bf16x8*)(par + ((g*8)      ^ (w4 << 4)));
        bf16x8 pa1 = *(const bf16x8*)(par + ((32 + g*8) ^ (w4 << 4)));
        #pragma unroll
        for (int d8 = 0; d8 < 8; ++d8){
            const int d = d8*16 + ln15;
            const unsigned short* vb = &vT_s[d*KT];
            const int ev = 8*((4*d8 + (ln15 >> 2)) & 7);
            bf16x8 b0 = *(const bf16x8*)(vb + ((g*8) ^ ev));
            bf16x8 b1 = *(const bf16x8*)(vb + ((32 + g*8) ^ ev));
            oacc[d8] = __builtin_amdgcn_mfma_f32_16x16x32_bf16(pa0, b0, oacc[d8], 0, 0, 0);
            oacc[d8] = __builtin_amdgcn_mfma_f32_16x16x32_bf16(pa1, b1, oacc[d8], 0, 0, 0);
        }
    }

    // epilogue: partial O (plain stores; 64B segments per 16-lane group)
    float* po = pO + (size_t)half*BB*LL*DD;
    #pragma unroll
    for (int d8 = 0; d8 < 8; ++d8){
        #pragma unroll
        for (int r = 0; r < 4; ++r){
            po[((size_t)bb*LL + qw0 + 4*g + r)*DD + d8*16 + ln15] = oacc[d8][r];
        }
    }
}

__global__ void combine_out(const float* __restrict__ pO, float* __restrict__ out){
    size_t i = ((size_t)blockIdx.x*THREADS + threadIdx.x) * 4;
    f32x4 a = *(const f32x4*)(pO + i);
    f32x4 b = *(const f32x4*)(pO + (size_t)BB*LL*DD + i);
    *(f32x4*)(out + i) = a + b;
}

// ================= fallback: fused two-pass =================
template<int USE_BITS>
__global__ __launch_bounds__(THREADS, 3) void attn_fused(
    const float* __restrict__ q, const float* __restrict__ k, const float* __restrict__ v,
    const unsigned char* __restrict__ maskb, const int* __restrict__ flagp,
    const u64* __restrict__ mb,
    float* __restrict__ out, float* __restrict__ attn)
{
    __shared__ __attribute__((aligned(16))) unsigned short k_s[KT*DD];
    __shared__ __attribute__((aligned(16))) unsigned short vT_s[DD*KT];
    __shared__ __attribute__((aligned(16))) unsigned short p_bf[4*16*64];

    const int tid  = threadIdx.x;
    const int w    = tid >> 6;
    const int lane = tid & 63;
    const int ln15 = lane & 15;
    const int g    = lane >> 4;
    const int r0   = tid >> 5;
    const int c4   = tid & 31;

    const int bidx = blockIdx.x;
    const int bb   = bidx >> 5;
    const int qt0  = (bidx & 31) * QT;
    const int qw0  = qt0 + w*16;

    int msh = 0, madd = 0;
    if (!USE_BITS){
        const int mflag = flagp[0];
        msh  = (mflag == 1) ? 0 : 2;
        madd = (mflag == 2) ? 3 : 0;
    }

    bf16x8 qa[4];
    Q_FRAGS();

    size_t mrow[4];
    const u64* mbB = mb + ((size_t)bb*LL + qw0 + 4*g) * NT;
    #pragma unroll
    for (int r = 0; r < 4; ++r)
        mrow[r] = ((size_t)bb*LL + qw0 + 4*g + r) * (size_t)LL;

    const float* kbase = k + (size_t)bb*LL*DD;
    const float* vbase = v + (size_t)bb*LL*DD;

    f32x4 kpre[8];
    u64 mc[4] = {0,0,0,0}, mn[4] = {0,0,0,0};

    float rs[4] = {0.f, 0.f, 0.f, 0.f};
    K_LOAD(0); if (USE_BITS) M_LOADB(mc, 0);
    for (int t = 0; t < NT; ++t){
        __syncthreads();
        K_WRITE();
        if (t+1 < NT){ K_LOAD(t+1); if (USE_BITS) M_LOADB(mn, t+1); }
        __syncthreads();
        #pragma unroll
        for (int cg = 0; cg < 4; ++cg){
            f32x4 acc = {0.f, 0.f, 0.f, 0.f};
            QK_MFMA(acc, cg);
            const int kc = cg*16 + ln15;
            #pragma unroll
            for (int r = 0; r < 4; ++r){
                bool msk;
                if (USE_BITS) msk = (mc[r] >> kc) & 1ull;
                else          msk = maskb[((mrow[r] + t*KT + kc) << msh) + madd] != 0;
                rs[r] += msk ? 0.f : __expf(acc[r] * SCALE);
            }
        }
        if (USE_BITS){
            #pragma unroll
            for (int r = 0; r < 4; ++r) mc[r] = mn[r];
        }
    }

    float invl[4];
    #pragma unroll
    for (int r = 0; r < 4; ++r){
        float s = rs[r];
        s += __shfl_xor(s, 1); s += __shfl_xor(s, 2);
        s += __shfl_xor(s, 4); s += __shfl_xor(s, 8);
        invl[r] = 1.0f / s;
    }

    f32x4 oacc[8];
    #pragma unroll
    for (int d8 = 0; d8 < 8; ++d8) oacc[d8] = (f32x4){0.f, 0.f, 0.f, 0.f};

    unsigned short* pw = &p_bf[w*1024];
    const int w4 = ln15 >> 2;

    K_LOAD(0); if (USE_BITS) M_LOADB(mc, 0);
    for (int t = 0; t < NT; ++t){
        __syncthreads();
        K_WRITE();
        V_STAGE(t);
        if (t+1 < NT){ K_LOAD(t+1); if (USE_BITS) M_LOADB(mn, t+1); }
        __syncthreads();
        #pragma unroll
        for (int cg = 0; cg < 4; ++cg){
            f32x4 acc = {0.f, 0.f, 0.f, 0.f};
            QK_MFMA(acc, cg);
            const int kc = cg*16 + ln15;
            #pragma unroll
            for (int r = 0; r < 4; ++r){
                bool msk;
                if (USE_BITS) msk = (mc[r] >> kc) & 1ull;
                else          msk = maskb[((mrow[r] + t*KT + kc) << msh) + madd] != 0;
                float p = msk ? 0.f : __expf(acc[r] * SCALE) * invl[r];
                pw[(4*g + r)*64 + (kc ^ (g << 4))] = f2bf(p);
            }
        }
        #pragma unroll
        for (int it = 0; it < 4; ++it){
            int row = it*4 + g;
            u16x4 pb = *(const u16x4*)(&pw[row*64 + ((ln15*4) ^ (it << 4))]);
            f32x4 val = { bf2f(pb[0]), bf2f(pb[1]), bf2f(pb[2]), bf2f(pb[3]) };
            *(f32x4*)(&attn[((size_t)bb*LL + qw0 + row)*(size_t)LL + t*KT + ln15*4]) = val;
        }
        const unsigned short* par = pw + ln15*64;
        bf16x8 pa0 = *(const bf16x8*)(par + ((g*8)      ^ (w4 << 4)));
        bf16x8 pa1 = *(const bf16x8*)(par + ((32 + g*8) ^ (w4 << 4)));
        #pragma unroll
        for (int d8 = 0; d8 < 8; ++d8){
            const int d = d8*16 + ln15;
            const unsigned short* vb = &vT_s[d*KT];
            const int ev = 8*((4*d8 + (ln15 >> 2)) & 7);
            bf16x8 b0 = *(const bf16x8*)(vb + ((g*8) ^ ev));
            bf16x8 b1 = *(const bf16x8*)(vb + ((32 + g*8) ^ ev));
            oacc[d8] = __builtin_amdgcn_mfma_f32_16x16x32_bf16(pa0, b0, oacc[d8], 0, 0, 0);
            oacc[d8] = __builtin_amdgcn_mfma_f32_16x16x32_bf16(pa1, b1, oacc[d8], 0, 0, 0);
        }
        if (USE_BITS){
            #pragma unroll
            for (int r = 0; r < 4; ++r) mc[r] = mn[r];
        }
    }

    #pragma unroll
    for (int d8 = 0; d8 < 8; ++d8){
        #pragma unroll
        for (int r = 0; r < 4; ++r){
            out[((size_t)bb*LL + qw0 + 4*g + r)*DD + d8*16 + ln15] = oacc[d8][r];
        }
    }
}

extern "C" void kernel_launch(void* const* d_in, const int* in_sizes, int n_in,
                              void* d_out, int out_size, void* d_ws, size_t ws_size,
                              hipStream_t stream)
{
    const float* q = (const float*)d_in[0];
    const float* k = (const float*)d_in[1];
    const float* v = (const float*)d_in[2];
    const unsigned char* mask = (const unsigned char*)d_in[3];

    float* out  = (float*)d_out;
    float* attn = out + (size_t)BB*LL*DD;

    const size_t bits_sz = (size_t)BB*LL*NT*sizeof(u64);           // 8 MB
    const size_t off_l   = 256 + bits_sz;
    const size_t l_sz    = (size_t)SPLIT_S*BB*LL*sizeof(float);    // 512 KB
    const size_t off_pO  = off_l + l_sz;
    const size_t pO_sz   = (size_t)SPLIT*BB*LL*DD*sizeof(float);   // 32 MB
    const size_t need_split = off_pO + pO_sz;
    const size_t need_bits  = 256 + bits_sz;

    int*   flag  = (int*)d_ws;
    u64*   mb    = (u64*)((char*)d_ws + 256);
    float* lpart = (float*)((char*)d_ws + off_l);
    float* pO    = (float*)((char*)d_ws + off_pO);

    detect_mask<<<1, 64, 0, stream>>>((const unsigned*)mask, flag);
    if (ws_size >= need_split){
        prepack_mask<<<(BB*LL*NT)/THREADS, THREADS, 0, stream>>>(mask, flag, mb);
        attn_sums<<<NWG_S, THREADS, 0, stream>>>(q, k, mb, lpart);
        attn_main<<<NWGS, THREADS, 0, stream>>>(q, k, v, mb, lpart, attn, pO);
        combine_out<<<(BB*LL*DD)/(4*THREADS), THREADS, 0, stream>>>(pO, out);
    } else if (ws_size >= need_bits){
        prepack_mask<<<(BB*LL*NT)/THREADS, THREADS, 0, stream>>>(mask, flag, mb);
        attn_fused<1><<<NWG, THREADS, 0, stream>>>(q, k, v, mask, flag, mb, out, attn);
    } else {
        attn_fused<0><<<NWG, THREADS, 0, stream>>>(q, k, v, mask, flag, mb, out, attn);
    }
}

// Round 8
// 288.443 us; speedup vs baseline: 1.8557x; 1.1707x over previous
//
#include <hip/hip_runtime.h>
#include <hip/hip_bf16.h>

#define BB 16
#define LL 2048
#define DD 128
#define SCALE 0.03125f   // 1/sqrt(1024)

#define QT 64
#define KT 64
#define NT (LL/KT)       // 32
#define SPLIT 2
#define HKT (NT/SPLIT)   // 16
#define SPLIT_S 4
#define SKT (NT/SPLIT_S) // 8
#define THREADS 256
#define NWG   (BB*(LL/QT))          // 512  (fallback grid)
#define NWGS  (BB*SPLIT*(LL/QT))    // 1024 (main grid)
#define NWG_S (BB*SPLIT_S*(LL/QT))  // 2048 (sums grid)

using bf16x8 = __attribute__((ext_vector_type(8))) short;
using f32x4  = __attribute__((ext_vector_type(4))) float;
using u16x4  = __attribute__((ext_vector_type(4))) unsigned short;
using u32x2  = __attribute__((ext_vector_type(2))) unsigned;
typedef unsigned long long u64;

__device__ __forceinline__ unsigned short f2bf(float f){
    __hip_bfloat16 h = __float2bfloat16(f);
    return *reinterpret_cast<unsigned short*>(&h);
}
__device__ __forceinline__ float bf2f(unsigned short u){
    union { unsigned u; float f; } a; a.u = ((unsigned)u) << 16;
    return a.f;
}
__device__ __forceinline__ unsigned pk2(float lo, float hi){
    return (unsigned)f2bf(lo) | ((unsigned)f2bf(hi) << 16);
}

// Detect mask element layout: 0 = 4-byte int, 1 = 1-byte bool, 2 = 4-byte float.
__global__ void detect_mask(const unsigned* __restrict__ m, int* __restrict__ flag){
    int lane = threadIdx.x & 63;
    unsigned hi = 0, nl = 0;
    #pragma unroll
    for (int i = 0; i < 16; ++i){
        unsigned d = m[lane*16 + i];
        hi |= (d & 0xFFFFFF00u);
        nl |= (d & 0xFEFEFEFEu);
    }
    unsigned long long bh = __ballot(hi != 0u);
    unsigned long long bn = __ballot(nl != 0u);
    if (lane == 0){
        int f = 0;
        if (bn != 0ull) f = 2;
        else if (bh != 0ull) f = 1;
        flag[0] = f;
    }
}

__global__ void prepack_mask(const unsigned char* __restrict__ m,
                             const int* __restrict__ flagp,
                             u64* __restrict__ mb){
    int id = blockIdx.x * THREADS + threadIdx.x;
    int fl = flagp[0];
    u64 bits = 0;
    if (fl == 1){
        const uint4* mp = (const uint4*)(m + (size_t)id * 64);
        #pragma unroll
        for (int c = 0; c < 4; ++c){
            uint4 u = mp[c];
            unsigned wd[4] = {u.x, u.y, u.z, u.w};
            #pragma unroll
            for (int wi = 0; wi < 4; ++wi){
                #pragma unroll
                for (int b = 0; b < 4; ++b)
                    if ((wd[wi] >> (8*b)) & 0xFFu) bits |= 1ull << (c*16 + wi*4 + b);
            }
        }
    } else {
        const uint4* mp = (const uint4*)m + (size_t)id * 16;
        #pragma unroll
        for (int c = 0; c < 16; ++c){
            uint4 u = mp[c];
            if (u.x) bits |= 1ull << (c*4+0);
            if (u.y) bits |= 1ull << (c*4+1);
            if (u.z) bits |= 1ull << (c*4+2);
            if (u.w) bits |= 1ull << (c*4+3);
        }
    }
    mb[id] = bits;
}

// ---------------- staging macros (shared by kernels) ----------------
#define K_LOAD(T) { const float* kp_ = kbase + (size_t)(T)*KT*DD; \
    _Pragma("unroll") for (int i_ = 0; i_ < 8; ++i_) \
        kpre[i_] = *(const f32x4*)(kp_ + (i_*8 + r0)*DD + c4*4); }

#define K_WRITE() { _Pragma("unroll") for (int i_ = 0; i_ < 8; ++i_){ \
        int row_ = i_*8 + r0; int e_ = (c4*4) ^ (8*(row_ & 7)); \
        u16x4 pk_ = { f2bf(kpre[i_][0]), f2bf(kpre[i_][1]), f2bf(kpre[i_][2]), f2bf(kpre[i_][3]) }; \
        *(u16x4*)(&k_s[row_*DD + e_]) = pk_; } }

// V: all 8 loads issue first (latency overlaps K_WRITE's LDS ops), then writes.
#define V_STAGE(T) { const float* vp_ = vbase + (size_t)(T)*KT*DD; \
    f32x4 vv_[8]; \
    _Pragma("unroll") for (int i_ = 0; i_ < 2; ++i_) \
        _Pragma("unroll") for (int rr_ = 0; rr_ < 4; ++rr_) \
            vv_[i_*4+rr_] = *(const f32x4*)(vp_ + ((r0 + 8*i_)*4 + rr_)*DD + c4*4); \
    _Pragma("unroll") for (int i_ = 0; i_ < 2; ++i_){ \
        int rb_ = (r0 + 8*i_)*4; int kk_ = rb_ ^ (8*(c4 & 7)); \
        _Pragma("unroll") for (int cc_ = 0; cc_ < 4; ++cc_){ \
            int d_ = c4*4 + cc_; \
            u16x4 pk_ = { f2bf(vv_[i_*4+0][cc_]), f2bf(vv_[i_*4+1][cc_]), \
                          f2bf(vv_[i_*4+2][cc_]), f2bf(vv_[i_*4+3][cc_]) }; \
            *(u16x4*)(&vT_s[d_*KT + kk_]) = pk_; } } }

#define M_LOADB(DST, T) { _Pragma("unroll") for (int r_ = 0; r_ < 4; ++r_) DST[r_] = mbB[r_*NT + (T)]; }

// original orientation (fallback only): acc[r] = S[q=4g+r][k=cg*16+ln15]
#define QK_MFMA(ACC, CG) { \
    const int krow_ = (CG)*16 + ln15; \
    const unsigned short* kb_ = &k_s[krow_*DD]; \
    const int sw_ = 8*(krow_ & 7); \
    _Pragma("unroll") for (int c_ = 0; c_ < 4; ++c_){ \
        bf16x8 bf_ = *(const bf16x8*)(kb_ + ((c_*32 + g*8) ^ sw_)); \
        ACC = __builtin_amdgcn_mfma_f32_16x16x32_bf16(qa[c_], bf_, ACC, 0, 0, 0); } }

// SWAPPED: acc[r] = S[q=ln15][k=cg*16+4g+r]  (A=K-frag, B=Q-frag; layouts symmetric)
#define QK_MFMA_SW(ACC, CG) { \
    const int krow_ = (CG)*16 + ln15; \
    const unsigned short* kb_ = &k_s[krow_*DD]; \
    const int sw_ = 8*(krow_ & 7); \
    _Pragma("unroll") for (int c_ = 0; c_ < 4; ++c_){ \
        bf16x8 bf_ = *(const bf16x8*)(kb_ + ((c_*32 + g*8) ^ sw_)); \
        ACC = __builtin_amdgcn_mfma_f32_16x16x32_bf16(bf_, qa[c_], ACC, 0, 0, 0); } }

#define Q_FRAGS() { \
    const float* qp_ = q + ((size_t)bb*LL + qw0 + ln15)*DD + g*8; \
    _Pragma("unroll") for (int c_ = 0; c_ < 4; ++c_){ \
        f32x4 x_ = *(const f32x4*)(qp_ + c_*32); \
        f32x4 y_ = *(const f32x4*)(qp_ + c_*32 + 4); \
        bf16x8 t_; \
        t_[0]=(short)f2bf(x_[0]); t_[1]=(short)f2bf(x_[1]); t_[2]=(short)f2bf(x_[2]); t_[3]=(short)f2bf(x_[3]); \
        t_[4]=(short)f2bf(y_[0]); t_[5]=(short)f2bf(y_[1]); t_[6]=(short)f2bf(y_[2]); t_[7]=(short)f2bf(y_[3]); \
        qa[c_] = t_; } }

// ================= split kernel 1: partial row sums (swapped QK) =================
__global__ __launch_bounds__(THREADS, 4) void attn_sums(
    const float* __restrict__ q, const float* __restrict__ k,
    const u64* __restrict__ mb, float* __restrict__ lpart)
{
    __shared__ __attribute__((aligned(16))) unsigned short k_s[KT*DD];   // 16 KB

    const int tid  = threadIdx.x;
    const int w    = tid >> 6;
    const int lane = tid & 63;
    const int ln15 = lane & 15;
    const int g    = lane >> 4;
    const int r0   = tid >> 5;
    const int c4   = tid & 31;

    const int hw    = blockIdx.x;
    const int bidx  = (hw & 7) * (NWG_S/8) + (hw >> 3);   // XCD-contiguous
    const int bb    = bidx >> 7;                          // /128
    const int quart = (bidx >> 5) & 3;
    const int qt0   = (bidx & 31) * QT;
    const int qw0   = qt0 + w*16;

    bf16x8 qa[4];
    Q_FRAGS();

    // per-lane q-row = qw0 + ln15 (swapped layout)
    const u64* mrow_bits = mb + ((size_t)bb*LL + qw0 + ln15) * NT;

    const float* kbase = k + (size_t)bb*LL*DD;
    f32x4 kpre[8];
    u64 mc = 0, mn = 0;

    const int T0 = quart * SKT;
    float rs = 0.f;
    K_LOAD(T0); mc = mrow_bits[T0];
    for (int tt = 0; tt < SKT; ++tt){
        const int t = T0 + tt;
        __syncthreads();
        K_WRITE();
        if (tt+1 < SKT){ K_LOAD(t+1); mn = mrow_bits[t+1]; }
        __syncthreads();
        #pragma unroll
        for (int cg = 0; cg < 4; ++cg){
            f32x4 acc = {0.f, 0.f, 0.f, 0.f};
            QK_MFMA_SW(acc, cg);
            const int kb0 = cg*16 + 4*g;
            const unsigned nib = (unsigned)(mc >> kb0) & 0xFu;
            #pragma unroll
            for (int r = 0; r < 4; ++r)
                rs += ((nib >> r) & 1u) ? 0.f : __expf(acc[r] * SCALE);
        }
        mc = mn;
    }
    // reduce over the 4 lanes (g=0..3) holding the same q-row
    rs += __shfl_xor(rs, 16);
    rs += __shfl_xor(rs, 32);
    if (lane < 16)
        lpart[(size_t)quart*BB*LL + (size_t)bb*LL + qw0 + lane] = rs;
}

// ============ split kernel 2 (swapped QK): attn from regs + partial PV ============
__global__ __launch_bounds__(THREADS, 4) void attn_main(
    const float* __restrict__ q, const float* __restrict__ k, const float* __restrict__ v,
    const u64* __restrict__ mb, const float* __restrict__ lpart,
    float* __restrict__ attn, float* __restrict__ pO)
{
    __shared__ __attribute__((aligned(16))) unsigned short k_s[KT*DD];    // 16 KB
    __shared__ __attribute__((aligned(16))) unsigned short vT_s[DD*KT];   // 16 KB
    __shared__ __attribute__((aligned(16))) unsigned p_u32[4*16*32];      // 8 KB

    const int tid  = threadIdx.x;
    const int w    = tid >> 6;
    const int lane = tid & 63;
    const int ln15 = lane & 15;
    const int g    = lane >> 4;
    const int r0   = tid >> 5;
    const int c4   = tid & 31;

    const int hw   = blockIdx.x;
    const int bidx = (hw & 7) * (NWGS/8) + (hw >> 3);
    const int bb   = bidx >> 6;
    const int half = (bidx >> 5) & 1;
    const int qt0  = (bidx & 31) * QT;
    const int qw0  = qt0 + w*16;

    bf16x8 qa[4];
    Q_FRAGS();

    // per-lane q-row
    const size_t qrow = (size_t)bb*LL + qw0 + ln15;
    const u64* mrow_bits = mb + qrow * NT;
    float* arow = attn + qrow * (size_t)LL;
    float invl;
    {
        float s = 0.f;
        #pragma unroll
        for (int sl = 0; sl < SPLIT_S; ++sl)
            s += lpart[(size_t)sl*BB*LL + qrow];
        invl = 1.0f / s;
    }

    const float* kbase = k + (size_t)bb*LL*DD;
    const float* vbase = v + (size_t)bb*LL*DD;
    f32x4 kpre[8];
    u64 mc = 0, mn = 0;

    f32x4 oacc[8];
    #pragma unroll
    for (int d8 = 0; d8 < 8; ++d8) oacc[d8] = (f32x4){0.f, 0.f, 0.f, 0.f};

    unsigned* pw = &p_u32[w*512];   // 16 rows x 32 u32 (64 bf16/row)

    const int T0 = half * HKT;
    K_LOAD(T0); mc = mrow_bits[T0];
    for (int tt = 0; tt < HKT; ++tt){
        const int t = T0 + tt;
        __syncthreads();
        K_WRITE();
        V_STAGE(t);
        if (tt+1 < HKT){ K_LOAD(t+1); mn = mrow_bits[t+1]; }
        __syncthreads();
        #pragma unroll
        for (int cg = 0; cg < 4; ++cg){
            f32x4 acc = {0.f, 0.f, 0.f, 0.f};
            QK_MFMA_SW(acc, cg);
            const int kb0 = cg*16 + 4*g;           // lane's 4 consecutive k
            const unsigned nib = (unsigned)(mc >> kb0) & 0xFu;
            f32x4 pv;
            #pragma unroll
            for (int r = 0; r < 4; ++r)
                pv[r] = ((nib >> r) & 1u) ? 0.f : __expf(acc[r] * SCALE) * invl;
            // attn: straight from regs, 16B/lane NT (64B/row segments per cg)
            __builtin_nontemporal_store(pv, (f32x4*)(arow + t*KT + kb0));
            // P bounce: 1 b64 write, chunk m = kb0/4, rotation swizzle
            const int m  = cg*4 + g;
            const int mp = (m + ln15) & 15;
            u32x2 wv = { pk2(pv[0], pv[1]), pk2(pv[2], pv[3]) };
            *(u32x2*)(&pw[ln15*32 + mp*2]) = wv;
        }
        // read back A-frags: chunks 2g,2g+1 (pa0) and 8+2g,8+2g+1 (pa1)
        const unsigned* prow_ = &pw[ln15*32];
        u32x2 a00 = *(const u32x2*)(&prow_[(((2*g  ) + ln15) & 15)*2]);
        u32x2 a01 = *(const u32x2*)(&prow_[(((2*g+1) + ln15) & 15)*2]);
        u32x2 a10 = *(const u32x2*)(&prow_[(((8+2*g ) + ln15) & 15)*2]);
        u32x2 a11 = *(const u32x2*)(&prow_[(((9+2*g ) + ln15) & 15)*2]);
        union { unsigned u[4]; bf16x8 v8; } A0, A1;
        A0.u[0]=a00[0]; A0.u[1]=a00[1]; A0.u[2]=a01[0]; A0.u[3]=a01[1];
        A1.u[0]=a10[0]; A1.u[1]=a10[1]; A1.u[2]=a11[0]; A1.u[3]=a11[1];
        const bf16x8 pa0 = A0.v8, pa1 = A1.v8;
        #pragma unroll
        for (int d8 = 0; d8 < 8; ++d8){
            const int d = d8*16 + ln15;
            const unsigned short* vb = &vT_s[d*KT];
            const int ev = 8*((4*d8 + (ln15 >> 2)) & 7);
            bf16x8 b0 = *(const bf16x8*)(vb + ((g*8) ^ ev));
            bf16x8 b1 = *(const bf16x8*)(vb + ((32 + g*8) ^ ev));
            oacc[d8] = __builtin_amdgcn_mfma_f32_16x16x32_bf16(pa0, b0, oacc[d8], 0, 0, 0);
            oacc[d8] = __builtin_amdgcn_mfma_f32_16x16x32_bf16(pa1, b1, oacc[d8], 0, 0, 0);
        }
        mc = mn;
    }

    // epilogue: partial O (unchanged: D row=4g+r -> q-row, col=ln15 -> d)
    float* po = pO + (size_t)half*BB*LL*DD;
    #pragma unroll
    for (int d8 = 0; d8 < 8; ++d8){
        #pragma unroll
        for (int r = 0; r < 4; ++r){
            po[((size_t)bb*LL + qw0 + 4*g + r)*DD + d8*16 + ln15] = oacc[d8][r];
        }
    }
}

__global__ void combine_out(const float* __restrict__ pO, float* __restrict__ out){
    size_t i = ((size_t)blockIdx.x*THREADS + threadIdx.x) * 4;
    f32x4 a = *(const f32x4*)(pO + i);
    f32x4 b = *(const f32x4*)(pO + (size_t)BB*LL*DD + i);
    *(f32x4*)(out + i) = a + b;
}

// ================= fallback: fused two-pass (r7 structure, unswapped) =================
template<int USE_BITS>
__global__ __launch_bounds__(THREADS, 3) void attn_fused(
    const float* __restrict__ q, const float* __restrict__ k, const float* __restrict__ v,
    const unsigned char* __restrict__ maskb, const int* __restrict__ flagp,
    const u64* __restrict__ mb,
    float* __restrict__ out, float* __restrict__ attn)
{
    __shared__ __attribute__((aligned(16))) unsigned short k_s[KT*DD];
    __shared__ __attribute__((aligned(16))) unsigned short vT_s[DD*KT];
    __shared__ __attribute__((aligned(16))) unsigned short p_bf[4*16*64];

    const int tid  = threadIdx.x;
    const int w    = tid >> 6;
    const int lane = tid & 63;
    const int ln15 = lane & 15;
    const int g    = lane >> 4;
    const int r0   = tid >> 5;
    const int c4   = tid & 31;

    const int bidx = blockIdx.x;
    const int bb   = bidx >> 5;
    const int qt0  = (bidx & 31) * QT;
    const int qw0  = qt0 + w*16;

    int msh = 0, madd = 0;
    if (!USE_BITS){
        const int mflag = flagp[0];
        msh  = (mflag == 1) ? 0 : 2;
        madd = (mflag == 2) ? 3 : 0;
    }

    bf16x8 qa[4];
    Q_FRAGS();

    size_t mrow[4];
    const u64* mbB = mb + ((size_t)bb*LL + qw0 + 4*g) * NT;
    #pragma unroll
    for (int r = 0; r < 4; ++r)
        mrow[r] = ((size_t)bb*LL + qw0 + 4*g + r) * (size_t)LL;

    const float* kbase = k + (size_t)bb*LL*DD;
    const float* vbase = v + (size_t)bb*LL*DD;

    f32x4 kpre[8];
    u64 mc[4] = {0,0,0,0}, mn[4] = {0,0,0,0};

    float rs[4] = {0.f, 0.f, 0.f, 0.f};
    K_LOAD(0); if (USE_BITS) M_LOADB(mc, 0);
    for (int t = 0; t < NT; ++t){
        __syncthreads();
        K_WRITE();
        if (t+1 < NT){ K_LOAD(t+1); if (USE_BITS) M_LOADB(mn, t+1); }
        __syncthreads();
        #pragma unroll
        for (int cg = 0; cg < 4; ++cg){
            f32x4 acc = {0.f, 0.f, 0.f, 0.f};
            QK_MFMA(acc, cg);
            const int kc = cg*16 + ln15;
            #pragma unroll
            for (int r = 0; r < 4; ++r){
                bool msk;
                if (USE_BITS) msk = (mc[r] >> kc) & 1ull;
                else          msk = maskb[((mrow[r] + t*KT + kc) << msh) + madd] != 0;
                rs[r] += msk ? 0.f : __expf(acc[r] * SCALE);
            }
        }
        if (USE_BITS){
            #pragma unroll
            for (int r = 0; r < 4; ++r) mc[r] = mn[r];
        }
    }

    float invl[4];
    #pragma unroll
    for (int r = 0; r < 4; ++r){
        float s = rs[r];
        s += __shfl_xor(s, 1); s += __shfl_xor(s, 2);
        s += __shfl_xor(s, 4); s += __shfl_xor(s, 8);
        invl[r] = 1.0f / s;
    }

    f32x4 oacc[8];
    #pragma unroll
    for (int d8 = 0; d8 < 8; ++d8) oacc[d8] = (f32x4){0.f, 0.f, 0.f, 0.f};

    unsigned short* pw = &p_bf[w*1024];
    const int w4 = ln15 >> 2;

    K_LOAD(0); if (USE_BITS) M_LOADB(mc, 0);
    for (int t = 0; t < NT; ++t){
        __syncthreads();
        K_WRITE();
        V_STAGE(t);
        if (t+1 < NT){ K_LOAD(t+1); if (USE_BITS) M_LOADB(mn, t+1); }
        __syncthreads();
        #pragma unroll
        for (int cg = 0; cg < 4; ++cg){
            f32x4 acc = {0.f, 0.f, 0.f, 0.f};
            QK_MFMA(acc, cg);
            const int kc = cg*16 + ln15;
            #pragma unroll
            for (int r = 0; r < 4; ++r){
                bool msk;
                if (USE_BITS) msk = (mc[r] >> kc) & 1ull;
                else          msk = maskb[((mrow[r] + t*KT + kc) << msh) + madd] != 0;
                float p = msk ? 0.f : __expf(acc[r] * SCALE) * invl[r];
                pw[(4*g + r)*64 + (kc ^ (g << 4))] = f2bf(p);
            }
        }
        #pragma unroll
        for (int it = 0; it < 4; ++it){
            int row = it*4 + g;
            u16x4 pb = *(const u16x4*)(&pw[row*64 + ((ln15*4) ^ (it << 4))]);
            f32x4 val = { bf2f(pb[0]), bf2f(pb[1]), bf2f(pb[2]), bf2f(pb[3]) };
            *(f32x4*)(&attn[((size_t)bb*LL + qw0 + row)*(size_t)LL + t*KT + ln15*4]) = val;
        }
        const unsigned short* par = pw + ln15*64;
        bf16x8 pa0 = *(const bf16x8*)(par + ((g*8)      ^ (w4 << 4)));
        bf16x8 pa1 = *(const bf16x8*)(par + ((32 + g*8) ^ (w4 << 4)));
        #pragma unroll
        for (int d8 = 0; d8 < 8; ++d8){
            const int d = d8*16 + ln15;
            const unsigned short* vb = &vT_s[d*KT];
            const int ev = 8*((4*d8 + (ln15 >> 2)) & 7);
            bf16x8 b0 = *(const bf16x8*)(vb + ((g*8) ^ ev));
            bf16x8 b1 = *(const bf16x8*)(vb + ((32 + g*8) ^ ev));
            oacc[d8] = __builtin_amdgcn_mfma_f32_16x16x32_bf16(pa0, b0, oacc[d8], 0, 0, 0);
            oacc[d8] = __builtin_amdgcn_mfma_f32_16x16x32_bf16(pa1, b1, oacc[d8], 0, 0, 0);
        }
        if (USE_BITS){
            #pragma unroll
            for (int r = 0; r < 4; ++r) mc[r] = mn[r];
        }
    }

    #pragma unroll
    for (int d8 = 0; d8 < 8; ++d8){
        #pragma unroll
        for (int r = 0; r < 4; ++r){
            out[((size_t)bb*LL + qw0 + 4*g + r)*DD + d8*16 + ln15] = oacc[d8][r];
        }
    }
}

extern "C" void kernel_launch(void* const* d_in, const int* in_sizes, int n_in,
                              void* d_out, int out_size, void* d_ws, size_t ws_size,
                              hipStream_t stream)
{
    const float* q = (const float*)d_in[0];
    const float* k = (const float*)d_in[1];
    const float* v = (const float*)d_in[2];
    const unsigned char* mask = (const unsigned char*)d_in[3];

    float* out  = (float*)d_out;
    float* attn = out + (size_t)BB*LL*DD;

    const size_t bits_sz = (size_t)BB*LL*NT*sizeof(u64);           // 8 MB
    const size_t off_l   = 256 + bits_sz;
    const size_t l_sz    = (size_t)SPLIT_S*BB*LL*sizeof(float);    // 512 KB
    const size_t off_pO  = off_l + l_sz;
    const size_t pO_sz   = (size_t)SPLIT*BB*LL*DD*sizeof(float);   // 32 MB
    const size_t need_split = off_pO + pO_sz;
    const size_t need_bits  = 256 + bits_sz;

    int*   flag  = (int*)d_ws;
    u64*   mb    = (u64*)((char*)d_ws + 256);
    float* lpart = (float*)((char*)d_ws + off_l);
    float* pO    = (float*)((char*)d_ws + off_pO);

    detect_mask<<<1, 64, 0, stream>>>((const unsigned*)mask, flag);
    if (ws_size >= need_split){
        prepack_mask<<<(BB*LL*NT)/THREADS, THREADS, 0, stream>>>(mask, flag, mb);
        attn_sums<<<NWG_S, THREADS, 0, stream>>>(q, k, mb, lpart);
        attn_main<<<NWGS, THREADS, 0, stream>>>(q, k, v, mb, lpart, attn, pO);
        combine_out<<<(BB*LL*DD)/(4*THREADS), THREADS, 0, stream>>>(pO, out);
    } else if (ws_size >= need_bits){
        prepack_mask<<<(BB*LL*NT)/THREADS, THREADS, 0, stream>>>(mask, flag, mb);
        attn_fused<1><<<NWG, THREADS, 0, stream>>>(q, k, v, mask, flag, mb, out, attn);
    } else {
        attn_fused<0><<<NWG, THREADS, 0, stream>>>(q, k, v, mask, flag, mb, out, attn);
    }
}

// Round 9
// 283.339 us; speedup vs baseline: 1.8891x; 1.0180x over previous
//
#include <hip/hip_runtime.h>
#include <hip/hip_bf16.h>

#define BB 16
#define LL 2048
#define DD 128
#define SCALE 0.03125f   // 1/sqrt(1024)

#define QT 64            // fallback q-tile
#define QTM 128          // main/sums q-tile (512-thread blocks)
#define KT 64
#define NT (LL/KT)       // 32
#define SPLIT 2
#define HKT (NT/SPLIT)   // 16
#define SPLIT_S 2
#define SKT (NT/SPLIT_S) // 16
#define THREADS 256
#define TMAIN 512
#define NWG  (BB*(LL/QT))        // 512 (fallback grid)
#define NWG2 (BB*SPLIT*(LL/QTM)) // 512 (main & sums grids)

using bf16x8 = __attribute__((ext_vector_type(8))) short;
using f32x4  = __attribute__((ext_vector_type(4))) float;
using u16x4  = __attribute__((ext_vector_type(4))) unsigned short;
using u32x2  = __attribute__((ext_vector_type(2))) unsigned;
typedef unsigned long long u64;

__device__ __forceinline__ unsigned short f2bf(float f){
    __hip_bfloat16 h = __float2bfloat16(f);
    return *reinterpret_cast<unsigned short*>(&h);
}
__device__ __forceinline__ float bf2f(unsigned short u){
    union { unsigned u; float f; } a; a.u = ((unsigned)u) << 16;
    return a.f;
}
__device__ __forceinline__ unsigned pk2(float lo, float hi){
    return (unsigned)f2bf(lo) | ((unsigned)f2bf(hi) << 16);
}

// Detect mask element layout: 0 = 4-byte int, 1 = 1-byte bool, 2 = 4-byte float.
__global__ void detect_mask(const unsigned* __restrict__ m, int* __restrict__ flag){
    int lane = threadIdx.x & 63;
    unsigned hi = 0, nl = 0;
    #pragma unroll
    for (int i = 0; i < 16; ++i){
        unsigned d = m[lane*16 + i];
        hi |= (d & 0xFFFFFF00u);
        nl |= (d & 0xFEFEFEFEu);
    }
    unsigned long long bh = __ballot(hi != 0u);
    unsigned long long bn = __ballot(nl != 0u);
    if (lane == 0){
        int f = 0;
        if (bn != 0ull) f = 2;
        else if (bh != 0ull) f = 1;
        flag[0] = f;
    }
}

__global__ void prepack_mask(const unsigned char* __restrict__ m,
                             const int* __restrict__ flagp,
                             u64* __restrict__ mb){
    int id = blockIdx.x * THREADS + threadIdx.x;
    int fl = flagp[0];
    u64 bits = 0;
    if (fl == 1){
        const uint4* mp = (const uint4*)(m + (size_t)id * 64);
        #pragma unroll
        for (int c = 0; c < 4; ++c){
            uint4 u = mp[c];
            unsigned wd[4] = {u.x, u.y, u.z, u.w};
            #pragma unroll
            for (int wi = 0; wi < 4; ++wi){
                #pragma unroll
                for (int b = 0; b < 4; ++b)
                    if ((wd[wi] >> (8*b)) & 0xFFu) bits |= 1ull << (c*16 + wi*4 + b);
            }
        }
    } else {
        const uint4* mp = (const uint4*)m + (size_t)id * 16;
        #pragma unroll
        for (int c = 0; c < 16; ++c){
            uint4 u = mp[c];
            if (u.x) bits |= 1ull << (c*4+0);
            if (u.y) bits |= 1ull << (c*4+1);
            if (u.z) bits |= 1ull << (c*4+2);
            if (u.w) bits |= 1ull << (c*4+3);
        }
    }
    mb[id] = bits;
}

// ---------------- 256-thread staging macros (fallback) ----------------
#define K_LOAD(T) { const float* kp_ = kbase + (size_t)(T)*KT*DD; \
    _Pragma("unroll") for (int i_ = 0; i_ < 8; ++i_) \
        kpre[i_] = *(const f32x4*)(kp_ + (i_*8 + r0)*DD + c4*4); }

#define K_WRITE() { _Pragma("unroll") for (int i_ = 0; i_ < 8; ++i_){ \
        int row_ = i_*8 + r0; int e_ = (c4*4) ^ (8*(row_ & 7)); \
        u16x4 pk_ = { f2bf(kpre[i_][0]), f2bf(kpre[i_][1]), f2bf(kpre[i_][2]), f2bf(kpre[i_][3]) }; \
        *(u16x4*)(&k_s[row_*DD + e_]) = pk_; } }

#define V_STAGE(T) { const float* vp_ = vbase + (size_t)(T)*KT*DD; \
    f32x4 vv_[8]; \
    _Pragma("unroll") for (int i_ = 0; i_ < 2; ++i_) \
        _Pragma("unroll") for (int rr_ = 0; rr_ < 4; ++rr_) \
            vv_[i_*4+rr_] = *(const f32x4*)(vp_ + ((r0 + 8*i_)*4 + rr_)*DD + c4*4); \
    _Pragma("unroll") for (int i_ = 0; i_ < 2; ++i_){ \
        int rb_ = (r0 + 8*i_)*4; int kk_ = rb_ ^ (8*(c4 & 7)); \
        _Pragma("unroll") for (int cc_ = 0; cc_ < 4; ++cc_){ \
            int d_ = c4*4 + cc_; \
            u16x4 pk_ = { f2bf(vv_[i_*4+0][cc_]), f2bf(vv_[i_*4+1][cc_]), \
                          f2bf(vv_[i_*4+2][cc_]), f2bf(vv_[i_*4+3][cc_]) }; \
            *(u16x4*)(&vT_s[d_*KT + kk_]) = pk_; } } }

#define M_LOADB(DST, T) { _Pragma("unroll") for (int r_ = 0; r_ < 4; ++r_) DST[r_] = mbB[r_*NT + (T)]; }

// ---------------- 512-thread staging macros (main & sums) ----------------
// r0 = tid>>5 in [0,16), c4 = tid&31. One f32x4 per thread per iter.
#define K_LOAD4(T) { const float* kp_ = kbase + (size_t)(T)*KT*DD; \
    _Pragma("unroll") for (int i_ = 0; i_ < 4; ++i_) \
        kpre[i_] = *(const f32x4*)(kp_ + (i_*16 + r0)*DD + c4*4); }

#define K_WRITE4() { _Pragma("unroll") for (int i_ = 0; i_ < 4; ++i_){ \
        int row_ = i_*16 + r0; int e_ = (c4*4) ^ (8*(row_ & 7)); \
        u16x4 pk_ = { f2bf(kpre[i_][0]), f2bf(kpre[i_][1]), f2bf(kpre[i_][2]), f2bf(kpre[i_][3]) }; \
        *(u16x4*)(&k_s[row_*DD + e_]) = pk_; } }

// V: thread owns rows r0*4..+3 at cols c4*4..+3 -> 4x4 transpose block
#define V_LOAD4(T) { const float* vp_ = vbase + (size_t)(T)*KT*DD; \
    _Pragma("unroll") for (int rr_ = 0; rr_ < 4; ++rr_) \
        vpre[rr_] = *(const f32x4*)(vp_ + (r0*4 + rr_)*DD + c4*4); }

#define V_WRITE4() { int kk_ = (r0*4) ^ (8*(c4 & 7)); \
    _Pragma("unroll") for (int cc_ = 0; cc_ < 4; ++cc_){ \
        int d_ = c4*4 + cc_; \
        u16x4 pk_ = { f2bf(vpre[0][cc_]), f2bf(vpre[1][cc_]), \
                      f2bf(vpre[2][cc_]), f2bf(vpre[3][cc_]) }; \
        *(u16x4*)(&vT_s[d_*KT + kk_]) = pk_; } }

// original orientation (fallback only): acc[r] = S[q=4g+r][k=cg*16+ln15]
#define QK_MFMA(ACC, CG) { \
    const int krow_ = (CG)*16 + ln15; \
    const unsigned short* kb_ = &k_s[krow_*DD]; \
    const int sw_ = 8*(krow_ & 7); \
    _Pragma("unroll") for (int c_ = 0; c_ < 4; ++c_){ \
        bf16x8 bf_ = *(const bf16x8*)(kb_ + ((c_*32 + g*8) ^ sw_)); \
        ACC = __builtin_amdgcn_mfma_f32_16x16x32_bf16(qa[c_], bf_, ACC, 0, 0, 0); } }

// SWAPPED: acc[r] = S[q=ln15][k=cg*16+4g+r]
#define QK_MFMA_SW(ACC, CG) { \
    const int krow_ = (CG)*16 + ln15; \
    const unsigned short* kb_ = &k_s[krow_*DD]; \
    const int sw_ = 8*(krow_ & 7); \
    _Pragma("unroll") for (int c_ = 0; c_ < 4; ++c_){ \
        bf16x8 bf_ = *(const bf16x8*)(kb_ + ((c_*32 + g*8) ^ sw_)); \
        ACC = __builtin_amdgcn_mfma_f32_16x16x32_bf16(bf_, qa[c_], ACC, 0, 0, 0); } }

#define Q_FRAGS() { \
    const float* qp_ = q + ((size_t)bb*LL + qw0 + ln15)*DD + g*8; \
    _Pragma("unroll") for (int c_ = 0; c_ < 4; ++c_){ \
        f32x4 x_ = *(const f32x4*)(qp_ + c_*32); \
        f32x4 y_ = *(const f32x4*)(qp_ + c_*32 + 4); \
        bf16x8 t_; \
        t_[0]=(short)f2bf(x_[0]); t_[1]=(short)f2bf(x_[1]); t_[2]=(short)f2bf(x_[2]); t_[3]=(short)f2bf(x_[3]); \
        t_[4]=(short)f2bf(y_[0]); t_[5]=(short)f2bf(y_[1]); t_[6]=(short)f2bf(y_[2]); t_[7]=(short)f2bf(y_[3]); \
        qa[c_] = t_; } }

// ========== split kernel 1: partial row sums (QTM=128, 512 thr, swapped QK) ==========
__global__ __launch_bounds__(TMAIN, 4) void attn_sums(
    const float* __restrict__ q, const float* __restrict__ k,
    const u64* __restrict__ mb, float* __restrict__ lpart)
{
    __shared__ __attribute__((aligned(16))) unsigned short k_s[KT*DD];   // 16 KB

    const int tid  = threadIdx.x;
    const int w    = tid >> 6;       // 0..7
    const int lane = tid & 63;
    const int ln15 = lane & 15;
    const int g    = lane >> 4;
    const int r0   = tid >> 5;       // 0..15
    const int c4   = tid & 31;

    const int hw   = blockIdx.x;
    const int bidx = (hw & 7) * (NWG2/8) + (hw >> 3);   // XCD-contiguous
    const int bb   = bidx >> 5;
    const int half = (bidx >> 4) & 1;
    const int qt0  = (bidx & 15) * QTM;
    const int qw0  = qt0 + w*16;

    bf16x8 qa[4];
    Q_FRAGS();

    const u64* mrow_bits = mb + ((size_t)bb*LL + qw0 + ln15) * NT;

    const float* kbase = k + (size_t)bb*LL*DD;
    f32x4 kpre[4];
    u64 mc = 0, mn = 0;

    const int T0 = half * SKT;
    float rs = 0.f;
    K_LOAD4(T0); mc = mrow_bits[T0];
    for (int tt = 0; tt < SKT; ++tt){
        const int t = T0 + tt;
        __syncthreads();
        K_WRITE4();
        if (tt+1 < SKT){ K_LOAD4(t+1); mn = mrow_bits[t+1]; }
        __syncthreads();
        #pragma unroll
        for (int cg = 0; cg < 4; ++cg){
            f32x4 acc = {0.f, 0.f, 0.f, 0.f};
            QK_MFMA_SW(acc, cg);
            const int kb0 = cg*16 + 4*g;
            const unsigned nib = (unsigned)(mc >> kb0) & 0xFu;
            #pragma unroll
            for (int r = 0; r < 4; ++r)
                rs += ((nib >> r) & 1u) ? 0.f : __expf(acc[r] * SCALE);
        }
        mc = mn;
    }
    rs += __shfl_xor(rs, 16);
    rs += __shfl_xor(rs, 32);
    if (lane < 16)
        lpart[(size_t)half*BB*LL + (size_t)bb*LL + qw0 + lane] = rs;
}

// ===== split kernel 2 (QTM=128, 512 thr, swapped QK): attn from regs + partial PV =====
__global__ __launch_bounds__(TMAIN, 4) void attn_main(
    const float* __restrict__ q, const float* __restrict__ k, const float* __restrict__ v,
    const u64* __restrict__ mb, const float* __restrict__ lpart,
    float* __restrict__ attn, float* __restrict__ pO)
{
    __shared__ __attribute__((aligned(16))) unsigned short k_s[KT*DD];    // 16 KB
    __shared__ __attribute__((aligned(16))) unsigned short vT_s[DD*KT];   // 16 KB
    __shared__ __attribute__((aligned(16))) unsigned p_u32[8*512];        // 16 KB

    const int tid  = threadIdx.x;
    const int w    = tid >> 6;       // 0..7
    const int lane = tid & 63;
    const int ln15 = lane & 15;
    const int g    = lane >> 4;
    const int r0   = tid >> 5;       // 0..15
    const int c4   = tid & 31;

    const int hw   = blockIdx.x;
    const int bidx = (hw & 7) * (NWG2/8) + (hw >> 3);
    const int bb   = bidx >> 5;
    const int half = (bidx >> 4) & 1;
    const int qt0  = (bidx & 15) * QTM;
    const int qw0  = qt0 + w*16;

    bf16x8 qa[4];
    Q_FRAGS();

    const size_t qrow = (size_t)bb*LL + qw0 + ln15;
    const u64* mrow_bits = mb + qrow * NT;
    float* arow = attn + qrow * (size_t)LL;
    float invl;
    {
        float s = lpart[qrow] + lpart[(size_t)BB*LL + qrow];
        invl = 1.0f / s;
    }

    const float* kbase = k + (size_t)bb*LL*DD;
    const float* vbase = v + (size_t)bb*LL*DD;
    f32x4 kpre[4];
    f32x4 vpre[4];
    u64 mc = 0, mn = 0;

    f32x4 oacc[8];
    #pragma unroll
    for (int d8 = 0; d8 < 8; ++d8) oacc[d8] = (f32x4){0.f, 0.f, 0.f, 0.f};

    unsigned* pw = &p_u32[w*512];   // per-wave: 16 rows x 32 u32 (64 bf16/row)

    const int T0 = half * HKT;
    K_LOAD4(T0); V_LOAD4(T0); mc = mrow_bits[T0];
    for (int tt = 0; tt < HKT; ++tt){
        const int t = T0 + tt;
        __syncthreads();
        K_WRITE4(); V_WRITE4();
        if (tt+1 < HKT){ K_LOAD4(t+1); V_LOAD4(t+1); mn = mrow_bits[t+1]; }
        __syncthreads();
        #pragma unroll
        for (int cg = 0; cg < 4; ++cg){
            f32x4 acc = {0.f, 0.f, 0.f, 0.f};
            QK_MFMA_SW(acc, cg);
            const int kb0 = cg*16 + 4*g;           // lane's 4 consecutive k
            const unsigned nib = (unsigned)(mc >> kb0) & 0xFu;
            f32x4 pv;
            #pragma unroll
            for (int r = 0; r < 4; ++r)
                pv[r] = ((nib >> r) & 1u) ? 0.f : __expf(acc[r] * SCALE) * invl;
            // attn: straight from regs, 16B/lane NT (full 64B sectors per cg)
            __builtin_nontemporal_store(pv, (f32x4*)(arow + t*KT + kb0));
            // P bounce: 1 b64 write, chunk m = kb0/4, rotation swizzle
            const int m  = cg*4 + g;
            const int mp = (m + ln15) & 15;
            u32x2 wv = { pk2(pv[0], pv[1]), pk2(pv[2], pv[3]) };
            *(u32x2*)(&pw[ln15*32 + mp*2]) = wv;
        }
        // read back A-frags: chunks 2g,2g+1 (pa0) and 8+2g,9+2g (pa1)
        const unsigned* prow_ = &pw[ln15*32];
        u32x2 a00 = *(const u32x2*)(&prow_[(((2*g  ) + ln15) & 15)*2]);
        u32x2 a01 = *(const u32x2*)(&prow_[(((2*g+1) + ln15) & 15)*2]);
        u32x2 a10 = *(const u32x2*)(&prow_[(((8+2*g ) + ln15) & 15)*2]);
        u32x2 a11 = *(const u32x2*)(&prow_[(((9+2*g ) + ln15) & 15)*2]);
        union { unsigned u[4]; bf16x8 v8; } A0, A1;
        A0.u[0]=a00[0]; A0.u[1]=a00[1]; A0.u[2]=a01[0]; A0.u[3]=a01[1];
        A1.u[0]=a10[0]; A1.u[1]=a10[1]; A1.u[2]=a11[0]; A1.u[3]=a11[1];
        const bf16x8 pa0 = A0.v8, pa1 = A1.v8;
        #pragma unroll
        for (int d8 = 0; d8 < 8; ++d8){
            const int d = d8*16 + ln15;
            const unsigned short* vb = &vT_s[d*KT];
            const int ev = 8*((4*d8 + (ln15 >> 2)) & 7);
            bf16x8 b0 = *(const bf16x8*)(vb + ((g*8) ^ ev));
            bf16x8 b1 = *(const bf16x8*)(vb + ((32 + g*8) ^ ev));
            oacc[d8] = __builtin_amdgcn_mfma_f32_16x16x32_bf16(pa0, b0, oacc[d8], 0, 0, 0);
            oacc[d8] = __builtin_amdgcn_mfma_f32_16x16x32_bf16(pa1, b1, oacc[d8], 0, 0, 0);
        }
        mc = mn;
    }

    // epilogue: partial O
    float* po = pO + (size_t)half*BB*LL*DD;
    #pragma unroll
    for (int d8 = 0; d8 < 8; ++d8){
        #pragma unroll
        for (int r = 0; r < 4; ++r){
            po[((size_t)bb*LL + qw0 + 4*g + r)*DD + d8*16 + ln15] = oacc[d8][r];
        }
    }
}

__global__ void combine_out(const float* __restrict__ pO, float* __restrict__ out){
    size_t i = ((size_t)blockIdx.x*THREADS + threadIdx.x) * 4;
    f32x4 a = *(const f32x4*)(pO + i);
    f32x4 b = *(const f32x4*)(pO + (size_t)BB*LL*DD + i);
    *(f32x4*)(out + i) = a + b;
}

// ================= fallback: fused two-pass (r7 structure, unswapped) =================
template<int USE_BITS>
__global__ __launch_bounds__(THREADS, 3) void attn_fused(
    const float* __restrict__ q, const float* __restrict__ k, const float* __restrict__ v,
    const unsigned char* __restrict__ maskb, const int* __restrict__ flagp,
    const u64* __restrict__ mb,
    float* __restrict__ out, float* __restrict__ attn)
{
    __shared__ __attribute__((aligned(16))) unsigned short k_s[KT*DD];
    __shared__ __attribute__((aligned(16))) unsigned short vT_s[DD*KT];
    __shared__ __attribute__((aligned(16))) unsigned short p_bf[4*16*64];

    const int tid  = threadIdx.x;
    const int w    = tid >> 6;
    const int lane = tid & 63;
    const int ln15 = lane & 15;
    const int g    = lane >> 4;
    const int r0   = tid >> 5;
    const int c4   = tid & 31;

    const int bidx = blockIdx.x;
    const int bb   = bidx >> 5;
    const int qt0  = (bidx & 31) * QT;
    const int qw0  = qt0 + w*16;

    int msh = 0, madd = 0;
    if (!USE_BITS){
        const int mflag = flagp[0];
        msh  = (mflag == 1) ? 0 : 2;
        madd = (mflag == 2) ? 3 : 0;
    }

    bf16x8 qa[4];
    Q_FRAGS();

    size_t mrow[4];
    const u64* mbB = mb + ((size_t)bb*LL + qw0 + 4*g) * NT;
    #pragma unroll
    for (int r = 0; r < 4; ++r)
        mrow[r] = ((size_t)bb*LL + qw0 + 4*g + r) * (size_t)LL;

    const float* kbase = k + (size_t)bb*LL*DD;
    const float* vbase = v + (size_t)bb*LL*DD;

    f32x4 kpre[8];
    u64 mc[4] = {0,0,0,0}, mn[4] = {0,0,0,0};

    float rs[4] = {0.f, 0.f, 0.f, 0.f};
    K_LOAD(0); if (USE_BITS) M_LOADB(mc, 0);
    for (int t = 0; t < NT; ++t){
        __syncthreads();
        K_WRITE();
        if (t+1 < NT){ K_LOAD(t+1); if (USE_BITS) M_LOADB(mn, t+1); }
        __syncthreads();
        #pragma unroll
        for (int cg = 0; cg < 4; ++cg){
            f32x4 acc = {0.f, 0.f, 0.f, 0.f};
            QK_MFMA(acc, cg);
            const int kc = cg*16 + ln15;
            #pragma unroll
            for (int r = 0; r < 4; ++r){
                bool msk;
                if (USE_BITS) msk = (mc[r] >> kc) & 1ull;
                else          msk = maskb[((mrow[r] + t*KT + kc) << msh) + madd] != 0;
                rs[r] += msk ? 0.f : __expf(acc[r] * SCALE);
            }
        }
        if (USE_BITS){
            #pragma unroll
            for (int r = 0; r < 4; ++r) mc[r] = mn[r];
        }
    }

    float invl[4];
    #pragma unroll
    for (int r = 0; r < 4; ++r){
        float s = rs[r];
        s += __shfl_xor(s, 1); s += __shfl_xor(s, 2);
        s += __shfl_xor(s, 4); s += __shfl_xor(s, 8);
        invl[r] = 1.0f / s;
    }

    f32x4 oacc[8];
    #pragma unroll
    for (int d8 = 0; d8 < 8; ++d8) oacc[d8] = (f32x4){0.f, 0.f, 0.f, 0.f};

    unsigned short* pw = &p_bf[w*1024];
    const int w4 = ln15 >> 2;

    K_LOAD(0); if (USE_BITS) M_LOADB(mc, 0);
    for (int t = 0; t < NT; ++t){
        __syncthreads();
        K_WRITE();
        V_STAGE(t);
        if (t+1 < NT){ K_LOAD(t+1); if (USE_BITS) M_LOADB(mn, t+1); }
        __syncthreads();
        #pragma unroll
        for (int cg = 0; cg < 4; ++cg){
            f32x4 acc = {0.f, 0.f, 0.f, 0.f};
            QK_MFMA(acc, cg);
            const int kc = cg*16 + ln15;
            #pragma unroll
            for (int r = 0; r < 4; ++r){
                bool msk;
                if (USE_BITS) msk = (mc[r] >> kc) & 1ull;
                else          msk = maskb[((mrow[r] + t*KT + kc) << msh) + madd] != 0;
                float p = msk ? 0.f : __expf(acc[r] * SCALE) * invl[r];
                pw[(4*g + r)*64 + (kc ^ (g << 4))] = f2bf(p);
            }
        }
        #pragma unroll
        for (int it = 0; it < 4; ++it){
            int row = it*4 + g;
            u16x4 pb = *(const u16x4*)(&pw[row*64 + ((ln15*4) ^ (it << 4))]);
            f32x4 val = { bf2f(pb[0]), bf2f(pb[1]), bf2f(pb[2]), bf2f(pb[3]) };
            *(f32x4*)(&attn[((size_t)bb*LL + qw0 + row)*(size_t)LL + t*KT + ln15*4]) = val;
        }
        const unsigned short* par = pw + ln15*64;
        bf16x8 pa0 = *(const bf16x8*)(par + ((g*8)      ^ (w4 << 4)));
        bf16x8 pa1 = *(const bf16x8*)(par + ((32 + g*8) ^ (w4 << 4)));
        #pragma unroll
        for (int d8 = 0; d8 < 8; ++d8){
            const int d = d8*16 + ln15;
            const unsigned short* vb = &vT_s[d*KT];
            const int ev = 8*((4*d8 + (ln15 >> 2)) & 7);
            bf16x8 b0 = *(const bf16x8*)(vb + ((g*8) ^ ev));
            bf16x8 b1 = *(const bf16x8*)(vb + ((32 + g*8) ^ ev));
            oacc[d8] = __builtin_amdgcn_mfma_f32_16x16x32_bf16(pa0, b0, oacc[d8], 0, 0, 0);
            oacc[d8] = __builtin_amdgcn_mfma_f32_16x16x32_bf16(pa1, b1, oacc[d8], 0, 0, 0);
        }
        if (USE_BITS){
            #pragma unroll
            for (int r = 0; r < 4; ++r) mc[r] = mn[r];
        }
    }

    #pragma unroll
    for (int d8 = 0; d8 < 8; ++d8){
        #pragma unroll
        for (int r = 0; r < 4; ++r){
            out[((size_t)bb*LL + qw0 + 4*g + r)*DD + d8*16 + ln15] = oacc[d8][r];
        }
    }
}

extern "C" void kernel_launch(void* const* d_in, const int* in_sizes, int n_in,
                              void* d_out, int out_size, void* d_ws, size_t ws_size,
                              hipStream_t stream)
{
    const float* q = (const float*)d_in[0];
    const float* k = (const float*)d_in[1];
    const float* v = (const float*)d_in[2];
    const unsigned char* mask = (const unsigned char*)d_in[3];

    float* out  = (float*)d_out;
    float* attn = out + (size_t)BB*LL*DD;

    const size_t bits_sz = (size_t)BB*LL*NT*sizeof(u64);           // 8 MB
    const size_t off_l   = 256 + bits_sz;
    const size_t l_sz    = (size_t)SPLIT_S*BB*LL*sizeof(float);    // 256 KB
    const size_t off_pO  = off_l + l_sz;
    const size_t pO_sz   = (size_t)SPLIT*BB*LL*DD*sizeof(float);   // 33.5 MB
    const size_t need_split = off_pO + pO_sz;                      // ~42.2 MB
    const size_t need_bits  = 256 + bits_sz;

    int*   flag  = (int*)d_ws;
    u64*   mb    = (u64*)((char*)d_ws + 256);
    float* lpart = (float*)((char*)d_ws + off_l);
    float* pO    = (float*)((char*)d_ws + off_pO);

    detect_mask<<<1, 64, 0, stream>>>((const unsigned*)mask, flag);
    if (ws_size >= need_split){
        prepack_mask<<<(BB*LL*NT)/THREADS, THREADS, 0, stream>>>(mask, flag, mb);
        attn_sums<<<NWG2, TMAIN, 0, stream>>>(q, k, mb, lpart);
        attn_main<<<NWG2, TMAIN, 0, stream>>>(q, k, v, mb, lpart, attn, pO);
        combine_out<<<(BB*LL*DD)/(4*THREADS), THREADS, 0, stream>>>(pO, out);
    } else if (ws_size >= need_bits){
        prepack_mask<<<(BB*LL*NT)/THREADS, THREADS, 0, stream>>>(mask, flag, mb);
        attn_fused<1><<<NWG, THREADS, 0, stream>>>(q, k, v, mask, flag, mb, out, attn);
    } else {
        attn_fused<0><<<NWG, THREADS, 0, stream>>>(q, k, v, mask, flag, mb, out, attn);
    }
}

// Round 10
// 266.635 us; speedup vs baseline: 2.0075x; 1.0626x over previous
//
#include <hip/hip_runtime.h>
#include <hip/hip_bf16.h>

#define BB 16
#define LL 2048
#define DD 128
#define SCALE 0.03125f   // 1/sqrt(1024)

#define QT 64            // fallback q-tile
#define QTM 128          // main/sums q-tile (512-thread blocks)
#define KT 64
#define NT (LL/KT)       // 32
#define SPLIT 2
#define HKT (NT/SPLIT)   // 16
#define SPLIT_S 4
#define SKT (NT/SPLIT_S) // 8
#define THREADS 256
#define TMAIN 512
#define NWG   (BB*(LL/QT))          // 512  (fallback grid)
#define NWG2  (BB*SPLIT*(LL/QTM))   // 512  (main grid)
#define NWG_S (BB*SPLIT_S*(LL/QTM)) // 1024 (sums grid)

using bf16x8 = __attribute__((ext_vector_type(8))) short;
using f32x4  = __attribute__((ext_vector_type(4))) float;
using u16x4  = __attribute__((ext_vector_type(4))) unsigned short;
using u32x2  = __attribute__((ext_vector_type(2))) unsigned;
typedef unsigned long long u64;

__device__ __forceinline__ unsigned short f2bf(float f){
    __hip_bfloat16 h = __float2bfloat16(f);
    return *reinterpret_cast<unsigned short*>(&h);
}
__device__ __forceinline__ float bf2f(unsigned short u){
    union { unsigned u; float f; } a; a.u = ((unsigned)u) << 16;
    return a.f;
}
__device__ __forceinline__ unsigned pk2(float lo, float hi){
    return (unsigned)f2bf(lo) | ((unsigned)f2bf(hi) << 16);
}

// Detect mask element layout: 0 = 4-byte int, 1 = 1-byte bool, 2 = 4-byte float.
__global__ void detect_mask(const unsigned* __restrict__ m, int* __restrict__ flag){
    int lane = threadIdx.x & 63;
    unsigned hi = 0, nl = 0;
    #pragma unroll
    for (int i = 0; i < 16; ++i){
        unsigned d = m[lane*16 + i];
        hi |= (d & 0xFFFFFF00u);
        nl |= (d & 0xFEFEFEFEu);
    }
    unsigned long long bh = __ballot(hi != 0u);
    unsigned long long bn = __ballot(nl != 0u);
    if (lane == 0){
        int f = 0;
        if (bn != 0ull) f = 2;
        else if (bh != 0ull) f = 1;
        flag[0] = f;
    }
}

__global__ void prepack_mask(const unsigned char* __restrict__ m,
                             const int* __restrict__ flagp,
                             u64* __restrict__ mb){
    int id = blockIdx.x * THREADS + threadIdx.x;
    int fl = flagp[0];
    u64 bits = 0;
    if (fl == 1){
        const uint4* mp = (const uint4*)(m + (size_t)id * 64);
        #pragma unroll
        for (int c = 0; c < 4; ++c){
            uint4 u = mp[c];
            unsigned wd[4] = {u.x, u.y, u.z, u.w};
            #pragma unroll
            for (int wi = 0; wi < 4; ++wi){
                #pragma unroll
                for (int b = 0; b < 4; ++b)
                    if ((wd[wi] >> (8*b)) & 0xFFu) bits |= 1ull << (c*16 + wi*4 + b);
            }
        }
    } else {
        const uint4* mp = (const uint4*)m + (size_t)id * 16;
        #pragma unroll
        for (int c = 0; c < 16; ++c){
            uint4 u = mp[c];
            if (u.x) bits |= 1ull << (c*4+0);
            if (u.y) bits |= 1ull << (c*4+1);
            if (u.z) bits |= 1ull << (c*4+2);
            if (u.w) bits |= 1ull << (c*4+3);
        }
    }
    mb[id] = bits;
}

// ---------------- 256-thread staging macros (fallback) ----------------
#define K_LOAD(T) { const float* kp_ = kbase + (size_t)(T)*KT*DD; \
    _Pragma("unroll") for (int i_ = 0; i_ < 8; ++i_) \
        kpre[i_] = *(const f32x4*)(kp_ + (i_*8 + r0)*DD + c4*4); }

#define K_WRITE() { _Pragma("unroll") for (int i_ = 0; i_ < 8; ++i_){ \
        int row_ = i_*8 + r0; int e_ = (c4*4) ^ (8*(row_ & 7)); \
        u16x4 pk_ = { f2bf(kpre[i_][0]), f2bf(kpre[i_][1]), f2bf(kpre[i_][2]), f2bf(kpre[i_][3]) }; \
        *(u16x4*)(&k_s[row_*DD + e_]) = pk_; } }

#define V_STAGE(T) { const float* vp_ = vbase + (size_t)(T)*KT*DD; \
    f32x4 vv_[8]; \
    _Pragma("unroll") for (int i_ = 0; i_ < 2; ++i_) \
        _Pragma("unroll") for (int rr_ = 0; rr_ < 4; ++rr_) \
            vv_[i_*4+rr_] = *(const f32x4*)(vp_ + ((r0 + 8*i_)*4 + rr_)*DD + c4*4); \
    _Pragma("unroll") for (int i_ = 0; i_ < 2; ++i_){ \
        int rb_ = (r0 + 8*i_)*4; int kk_ = rb_ ^ (8*(c4 & 7)); \
        _Pragma("unroll") for (int cc_ = 0; cc_ < 4; ++cc_){ \
            int d_ = c4*4 + cc_; \
            u16x4 pk_ = { f2bf(vv_[i_*4+0][cc_]), f2bf(vv_[i_*4+1][cc_]), \
                          f2bf(vv_[i_*4+2][cc_]), f2bf(vv_[i_*4+3][cc_]) }; \
            *(u16x4*)(&vT_s[d_*KT + kk_]) = pk_; } } }

#define M_LOADB(DST, T) { _Pragma("unroll") for (int r_ = 0; r_ < 4; ++r_) DST[r_] = mbB[r_*NT + (T)]; }

// ---------------- 512-thread staging macros (main & sums) ----------------
#define K_LOAD4(T) { const float* kp_ = kbase + (size_t)(T)*KT*DD; \
    _Pragma("unroll") for (int i_ = 0; i_ < 4; ++i_) \
        kpre[i_] = *(const f32x4*)(kp_ + (i_*16 + r0)*DD + c4*4); }

#define K_WRITE4() { _Pragma("unroll") for (int i_ = 0; i_ < 4; ++i_){ \
        int row_ = i_*16 + r0; int e_ = (c4*4) ^ (8*(row_ & 7)); \
        u16x4 pk_ = { f2bf(kpre[i_][0]), f2bf(kpre[i_][1]), f2bf(kpre[i_][2]), f2bf(kpre[i_][3]) }; \
        *(u16x4*)(&k_s[row_*DD + e_]) = pk_; } }

#define V_LOAD4(T) { const float* vp_ = vbase + (size_t)(T)*KT*DD; \
    _Pragma("unroll") for (int rr_ = 0; rr_ < 4; ++rr_) \
        vpre[rr_] = *(const f32x4*)(vp_ + (r0*4 + rr_)*DD + c4*4); }

// vT swizzle key(d) = ((d>>2)&7) ^ ((d&3)<<1): read-slot 2-regular (floor),
// write stays at its 4-way floor. (Old key was 2x over read floor.)
#define V_WRITE4() { \
    _Pragma("unroll") for (int cc_ = 0; cc_ < 4; ++cc_){ \
        int d_ = c4*4 + cc_; \
        int key_ = (c4 & 7) ^ ((cc_ << 1) & 7); \
        int kk_ = (r0*4) ^ (8*key_); \
        u16x4 pk_ = { f2bf(vpre[0][cc_]), f2bf(vpre[1][cc_]), \
                      f2bf(vpre[2][cc_]), f2bf(vpre[3][cc_]) }; \
        *(u16x4*)(&vT_s[d_*KT + kk_]) = pk_; } }

// original orientation (fallback only)
#define QK_MFMA(ACC, CG) { \
    const int krow_ = (CG)*16 + ln15; \
    const unsigned short* kb_ = &k_s[krow_*DD]; \
    const int sw_ = 8*(krow_ & 7); \
    _Pragma("unroll") for (int c_ = 0; c_ < 4; ++c_){ \
        bf16x8 bf_ = *(const bf16x8*)(kb_ + ((c_*32 + g*8) ^ sw_)); \
        ACC = __builtin_amdgcn_mfma_f32_16x16x32_bf16(qa[c_], bf_, ACC, 0, 0, 0); } }

// SWAPPED: acc[r] = S[q=ln15][k=cg*16+4g+r]
#define QK_MFMA_SW(ACC, CG) { \
    const int krow_ = (CG)*16 + ln15; \
    const unsigned short* kb_ = &k_s[krow_*DD]; \
    const int sw_ = 8*(krow_ & 7); \
    _Pragma("unroll") for (int c_ = 0; c_ < 4; ++c_){ \
        bf16x8 bf_ = *(const bf16x8*)(kb_ + ((c_*32 + g*8) ^ sw_)); \
        ACC = __builtin_amdgcn_mfma_f32_16x16x32_bf16(bf_, qa[c_], ACC, 0, 0, 0); } }

#define Q_FRAGS() { \
    const float* qp_ = q + ((size_t)bb*LL + qw0 + ln15)*DD + g*8; \
    _Pragma("unroll") for (int c_ = 0; c_ < 4; ++c_){ \
        f32x4 x_ = *(const f32x4*)(qp_ + c_*32); \
        f32x4 y_ = *(const f32x4*)(qp_ + c_*32 + 4); \
        bf16x8 t_; \
        t_[0]=(short)f2bf(x_[0]); t_[1]=(short)f2bf(x_[1]); t_[2]=(short)f2bf(x_[2]); t_[3]=(short)f2bf(x_[3]); \
        t_[4]=(short)f2bf(y_[0]); t_[5]=(short)f2bf(y_[1]); t_[6]=(short)f2bf(y_[2]); t_[7]=(short)f2bf(y_[3]); \
        qa[c_] = t_; } }

// ========== split kernel 1: partial row sums (QTM=128, SPLIT_S=4, 512 thr) ==========
__global__ __launch_bounds__(TMAIN, 4) void attn_sums(
    const float* __restrict__ q, const float* __restrict__ k,
    const u64* __restrict__ mb, float* __restrict__ lpart)
{
    __shared__ __attribute__((aligned(16))) unsigned short k_s[KT*DD];   // 16 KB

    const int tid  = threadIdx.x;
    const int w    = tid >> 6;       // 0..7
    const int lane = tid & 63;
    const int ln15 = lane & 15;
    const int g    = lane >> 4;
    const int r0   = tid >> 5;       // 0..15
    const int c4   = tid & 31;

    const int hw    = blockIdx.x;
    const int bidx  = (hw & 7) * (NWG_S/8) + (hw >> 3);   // XCD-contiguous
    const int bb    = bidx >> 6;                          // 64 blocks/batch
    const int quart = (bidx >> 4) & 3;
    const int qt0   = (bidx & 15) * QTM;
    const int qw0   = qt0 + w*16;

    bf16x8 qa[4];
    Q_FRAGS();

    const u64* mrow_bits = mb + ((size_t)bb*LL + qw0 + ln15) * NT;

    const float* kbase = k + (size_t)bb*LL*DD;
    f32x4 kpre[4];
    u64 mc = 0, mn = 0;

    const int T0 = quart * SKT;
    float rs = 0.f;
    K_LOAD4(T0); mc = mrow_bits[T0];
    for (int tt = 0; tt < SKT; ++tt){
        const int t = T0 + tt;
        __syncthreads();
        K_WRITE4();
        if (tt+1 < SKT){ K_LOAD4(t+1); mn = mrow_bits[t+1]; }
        __syncthreads();
        #pragma unroll
        for (int cg = 0; cg < 4; ++cg){
            f32x4 acc = {0.f, 0.f, 0.f, 0.f};
            QK_MFMA_SW(acc, cg);
            const int kb0 = cg*16 + 4*g;
            const unsigned nib = (unsigned)(mc >> kb0) & 0xFu;
            #pragma unroll
            for (int r = 0; r < 4; ++r)
                rs += ((nib >> r) & 1u) ? 0.f : __expf(acc[r] * SCALE);
        }
        mc = mn;
    }
    rs += __shfl_xor(rs, 16);
    rs += __shfl_xor(rs, 32);
    if (lane < 16)
        lpart[(size_t)quart*BB*LL + (size_t)bb*LL + qw0 + lane] = rs;
}

// ===== split kernel 2 (QTM=128, 512 thr, swapped QK): attn via P-LDS + partial PV =====
__global__ __launch_bounds__(TMAIN, 4) void attn_main(
    const float* __restrict__ q, const float* __restrict__ k, const float* __restrict__ v,
    const u64* __restrict__ mb, const float* __restrict__ lpart,
    float* __restrict__ attn, float* __restrict__ pO)
{
    __shared__ __attribute__((aligned(16))) unsigned short k_s[KT*DD];    // 16 KB
    __shared__ __attribute__((aligned(16))) unsigned short vT_s[DD*KT];   // 16 KB
    __shared__ __attribute__((aligned(16))) unsigned p_u32[8*512];        // 16 KB

    const int tid  = threadIdx.x;
    const int w    = tid >> 6;       // 0..7
    const int lane = tid & 63;
    const int ln15 = lane & 15;
    const int g    = lane >> 4;
    const int r0   = tid >> 5;       // 0..15
    const int c4   = tid & 31;

    const int hw   = blockIdx.x;
    const int bidx = (hw & 7) * (NWG2/8) + (hw >> 3);
    const int bb   = bidx >> 5;
    const int half = (bidx >> 4) & 1;
    const int qt0  = (bidx & 15) * QTM;
    const int qw0  = qt0 + w*16;

    bf16x8 qa[4];
    Q_FRAGS();

    const size_t qrow = (size_t)bb*LL + qw0 + ln15;
    const u64* mrow_bits = mb + qrow * NT;
    float invl;
    {
        float s = 0.f;
        #pragma unroll
        for (int sl = 0; sl < SPLIT_S; ++sl)
            s += lpart[(size_t)sl*BB*LL + qrow];
        invl = 1.0f / s;
    }

    const float* kbase = k + (size_t)bb*LL*DD;
    const float* vbase = v + (size_t)bb*LL*DD;
    f32x4 kpre[4];
    f32x4 vpre[4];
    u64 mc = 0, mn = 0;

    f32x4 oacc[8];
    #pragma unroll
    for (int d8 = 0; d8 < 8; ++d8) oacc[d8] = (f32x4){0.f, 0.f, 0.f, 0.f};

    unsigned* pw = &p_u32[w*512];   // per-wave: 16 rows x 32 u32 (64 bf16/row)

    const int T0 = half * HKT;
    K_LOAD4(T0); V_LOAD4(T0); mc = mrow_bits[T0];
    for (int tt = 0; tt < HKT; ++tt){
        const int t = T0 + tt;
        __syncthreads();
        K_WRITE4(); V_WRITE4();
        if (tt+1 < HKT){ K_LOAD4(t+1); V_LOAD4(t+1); mn = mrow_bits[t+1]; }
        __syncthreads();
        #pragma unroll
        for (int cg = 0; cg < 4; ++cg){
            f32x4 acc = {0.f, 0.f, 0.f, 0.f};
            QK_MFMA_SW(acc, cg);
            const int kb0 = cg*16 + 4*g;           // lane's 4 consecutive k
            const unsigned nib = (unsigned)(mc >> kb0) & 0xFu;
            f32x4 pv;
            #pragma unroll
            for (int r = 0; r < 4; ++r)
                pv[r] = ((nib >> r) & 1u) ? 0.f : __expf(acc[r] * SCALE) * invl;
            // P bounce only (attn store moved to remapped pass below)
            const int m  = cg*4 + g;
            const int mp = (m + ln15) & 15;
            u32x2 wv = { pk2(pv[0], pv[1]), pk2(pv[2], pv[3]) };
            *(u32x2*)(&pw[ln15*32 + mp*2]) = wv;
        }
        // attn stores via P LDS: each instr = 4 rows x 256B CONTIGUOUS (vs 16x64B)
        #pragma unroll
        for (int it = 0; it < 4; ++it){
            const int rl = it*4 + g;               // local row 0..15
            u32x2 pb = *(const u32x2*)(&pw[rl*32 + (((ln15 + rl) & 15)*2)]);
            f32x4 val = { bf2f((unsigned short)(pb[0] & 0xFFFFu)),
                          bf2f((unsigned short)(pb[0] >> 16)),
                          bf2f((unsigned short)(pb[1] & 0xFFFFu)),
                          bf2f((unsigned short)(pb[1] >> 16)) };
            __builtin_nontemporal_store(val,
                (f32x4*)(attn + ((size_t)bb*LL + qw0 + rl)*(size_t)LL + t*KT + ln15*4));
        }
        // PV: A-frags from P LDS, B-frags from vT (fixed swizzle key)
        const unsigned* prow_ = &pw[ln15*32];
        u32x2 a00 = *(const u32x2*)(&prow_[(((2*g  ) + ln15) & 15)*2]);
        u32x2 a01 = *(const u32x2*)(&prow_[(((2*g+1) + ln15) & 15)*2]);
        u32x2 a10 = *(const u32x2*)(&prow_[(((8+2*g ) + ln15) & 15)*2]);
        u32x2 a11 = *(const u32x2*)(&prow_[(((9+2*g ) + ln15) & 15)*2]);
        union { unsigned u[4]; bf16x8 v8; } A0, A1;
        A0.u[0]=a00[0]; A0.u[1]=a00[1]; A0.u[2]=a01[0]; A0.u[3]=a01[1];
        A1.u[0]=a10[0]; A1.u[1]=a10[1]; A1.u[2]=a11[0]; A1.u[3]=a11[1];
        const bf16x8 pa0 = A0.v8, pa1 = A1.v8;
        #pragma unroll
        for (int d8 = 0; d8 < 8; ++d8){
            const int d = d8*16 + ln15;
            const unsigned short* vb = &vT_s[d*KT];
            const int ev = 8*((((4*d8 + (ln15 >> 2)) & 7)) ^ ((ln15 & 3) << 1));
            bf16x8 b0 = *(const bf16x8*)(vb + ((g*8) ^ ev));
            bf16x8 b1 = *(const bf16x8*)(vb + ((32 + g*8) ^ ev));
            oacc[d8] = __builtin_amdgcn_mfma_f32_16x16x32_bf16(pa0, b0, oacc[d8], 0, 0, 0);
            oacc[d8] = __builtin_amdgcn_mfma_f32_16x16x32_bf16(pa1, b1, oacc[d8], 0, 0, 0);
        }
        mc = mn;
    }

    // epilogue: partial O
    float* po = pO + (size_t)half*BB*LL*DD;
    #pragma unroll
    for (int d8 = 0; d8 < 8; ++d8){
        #pragma unroll
        for (int r = 0; r < 4; ++r){
            po[((size_t)bb*LL + qw0 + 4*g + r)*DD + d8*16 + ln15] = oacc[d8][r];
        }
    }
}

__global__ void combine_out(const float* __restrict__ pO, float* __restrict__ out){
    size_t i = ((size_t)blockIdx.x*THREADS + threadIdx.x) * 4;
    f32x4 a = *(const f32x4*)(pO + i);
    f32x4 b = *(const f32x4*)(pO + (size_t)BB*LL*DD + i);
    *(f32x4*)(out + i) = a + b;
}

// ================= fallback: fused two-pass (r7 structure, unswapped) =================
template<int USE_BITS>
__global__ __launch_bounds__(THREADS, 3) void attn_fused(
    const float* __restrict__ q, const float* __restrict__ k, const float* __restrict__ v,
    const unsigned char* __restrict__ maskb, const int* __restrict__ flagp,
    const u64* __restrict__ mb,
    float* __restrict__ out, float* __restrict__ attn)
{
    __shared__ __attribute__((aligned(16))) unsigned short k_s[KT*DD];
    __shared__ __attribute__((aligned(16))) unsigned short vT_s[DD*KT];
    __shared__ __attribute__((aligned(16))) unsigned short p_bf[4*16*64];

    const int tid  = threadIdx.x;
    const int w    = tid >> 6;
    const int lane = tid & 63;
    const int ln15 = lane & 15;
    const int g    = lane >> 4;
    const int r0   = tid >> 5;
    const int c4   = tid & 31;

    const int bidx = blockIdx.x;
    const int bb   = bidx >> 5;
    const int qt0  = (bidx & 31) * QT;
    const int qw0  = qt0 + w*16;

    int msh = 0, madd = 0;
    if (!USE_BITS){
        const int mflag = flagp[0];
        msh  = (mflag == 1) ? 0 : 2;
        madd = (mflag == 2) ? 3 : 0;
    }

    bf16x8 qa[4];
    Q_FRAGS();

    size_t mrow[4];
    const u64* mbB = mb + ((size_t)bb*LL + qw0 + 4*g) * NT;
    #pragma unroll
    for (int r = 0; r < 4; ++r)
        mrow[r] = ((size_t)bb*LL + qw0 + 4*g + r) * (size_t)LL;

    const float* kbase = k + (size_t)bb*LL*DD;
    const float* vbase = v + (size_t)bb*LL*DD;

    f32x4 kpre[8];
    u64 mc[4] = {0,0,0,0}, mn[4] = {0,0,0,0};

    float rs[4] = {0.f, 0.f, 0.f, 0.f};
    K_LOAD(0); if (USE_BITS) M_LOADB(mc, 0);
    for (int t = 0; t < NT; ++t){
        __syncthreads();
        K_WRITE();
        if (t+1 < NT){ K_LOAD(t+1); if (USE_BITS) M_LOADB(mn, t+1); }
        __syncthreads();
        #pragma unroll
        for (int cg = 0; cg < 4; ++cg){
            f32x4 acc = {0.f, 0.f, 0.f, 0.f};
            QK_MFMA(acc, cg);
            const int kc = cg*16 + ln15;
            #pragma unroll
            for (int r = 0; r < 4; ++r){
                bool msk;
                if (USE_BITS) msk = (mc[r] >> kc) & 1ull;
                else          msk = maskb[((mrow[r] + t*KT + kc) << msh) + madd] != 0;
                rs[r] += msk ? 0.f : __expf(acc[r] * SCALE);
            }
        }
        if (USE_BITS){
            #pragma unroll
            for (int r = 0; r < 4; ++r) mc[r] = mn[r];
        }
    }

    float invl[4];
    #pragma unroll
    for (int r = 0; r < 4; ++r){
        float s = rs[r];
        s += __shfl_xor(s, 1); s += __shfl_xor(s, 2);
        s += __shfl_xor(s, 4); s += __shfl_xor(s, 8);
        invl[r] = 1.0f / s;
    }

    f32x4 oacc[8];
    #pragma unroll
    for (int d8 = 0; d8 < 8; ++d8) oacc[d8] = (f32x4){0.f, 0.f, 0.f, 0.f};

    unsigned short* pw = &p_bf[w*1024];
    const int w4 = ln15 >> 2;

    K_LOAD(0); if (USE_BITS) M_LOADB(mc, 0);
    for (int t = 0; t < NT; ++t){
        __syncthreads();
        K_WRITE();
        V_STAGE(t);
        if (t+1 < NT){ K_LOAD(t+1); if (USE_BITS) M_LOADB(mn, t+1); }
        __syncthreads();
        #pragma unroll
        for (int cg = 0; cg < 4; ++cg){
            f32x4 acc = {0.f, 0.f, 0.f, 0.f};
            QK_MFMA(acc, cg);
            const int kc = cg*16 + ln15;
            #pragma unroll
            for (int r = 0; r < 4; ++r){
                bool msk;
                if (USE_BITS) msk = (mc[r] >> kc) & 1ull;
                else          msk = maskb[((mrow[r] + t*KT + kc) << msh) + madd] != 0;
                float p = msk ? 0.f : __expf(acc[r] * SCALE) * invl[r];
                pw[(4*g + r)*64 + (kc ^ (g << 4))] = f2bf(p);
            }
        }
        #pragma unroll
        for (int it = 0; it < 4; ++it){
            int row = it*4 + g;
            u16x4 pb = *(const u16x4*)(&pw[row*64 + ((ln15*4) ^ (it << 4))]);
            f32x4 val = { bf2f(pb[0]), bf2f(pb[1]), bf2f(pb[2]), bf2f(pb[3]) };
            *(f32x4*)(&attn[((size_t)bb*LL + qw0 + row)*(size_t)LL + t*KT + ln15*4]) = val;
        }
        const unsigned short* par = pw + ln15*64;
        bf16x8 pa0 = *(const bf16x8*)(par + ((g*8)      ^ (w4 << 4)));
        bf16x8 pa1 = *(const bf16x8*)(par + ((32 + g*8) ^ (w4 << 4)));
        #pragma unroll
        for (int d8 = 0; d8 < 8; ++d8){
            const int d = d8*16 + ln15;
            const unsigned short* vb = &vT_s[d*KT];
            const int ev = 8*((4*d8 + (ln15 >> 2)) & 7);
            bf16x8 b0 = *(const bf16x8*)(vb + ((g*8) ^ ev));
            bf16x8 b1 = *(const bf16x8*)(vb + ((32 + g*8) ^ ev));
            oacc[d8] = __builtin_amdgcn_mfma_f32_16x16x32_bf16(pa0, b0, oacc[d8], 0, 0, 0);
            oacc[d8] = __builtin_amdgcn_mfma_f32_16x16x32_bf16(pa1, b1, oacc[d8], 0, 0, 0);
        }
        if (USE_BITS){
            #pragma unroll
            for (int r = 0; r < 4; ++r) mc[r] = mn[r];
        }
    }

    #pragma unroll
    for (int d8 = 0; d8 < 8; ++d8){
        #pragma unroll
        for (int r = 0; r < 4; ++r){
            out[((size_t)bb*LL + qw0 + 4*g + r)*DD + d8*16 + ln15] = oacc[d8][r];
        }
    }
}

extern "C" void kernel_launch(void* const* d_in, const int* in_sizes, int n_in,
                              void* d_out, int out_size, void* d_ws, size_t ws_size,
                              hipStream_t stream)
{
    const float* q = (const float*)d_in[0];
    const float* k = (const float*)d_in[1];
    const float* v = (const float*)d_in[2];
    const unsigned char* mask = (const unsigned char*)d_in[3];

    float* out  = (float*)d_out;
    float* attn = out + (size_t)BB*LL*DD;

    const size_t bits_sz = (size_t)BB*LL*NT*sizeof(u64);           // 8 MB
    const size_t off_l   = 256 + bits_sz;
    const size_t l_sz    = (size_t)SPLIT_S*BB*LL*sizeof(float);    // 512 KB
    const size_t off_pO  = off_l + l_sz;
    const size_t pO_sz   = (size_t)SPLIT*BB*LL*DD*sizeof(float);   // 33.5 MB
    const size_t need_split = off_pO + pO_sz;                      // ~42.45 MB (r3-proven)
    const size_t need_bits  = 256 + bits_sz;

    int*   flag  = (int*)d_ws;
    u64*   mb    = (u64*)((char*)d_ws + 256);
    float* lpart = (float*)((char*)d_ws + off_l);
    float* pO    = (float*)((char*)d_ws + off_pO);

    detect_mask<<<1, 64, 0, stream>>>((const unsigned*)mask, flag);
    if (ws_size >= need_split){
        prepack_mask<<<(BB*LL*NT)/THREADS, THREADS, 0, stream>>>(mask, flag, mb);
        attn_sums<<<NWG_S, TMAIN, 0, stream>>>(q, k, mb, lpart);
        attn_main<<<NWG2, TMAIN, 0, stream>>>(q, k, v, mb, lpart, attn, pO);
        combine_out<<<(BB*LL*DD)/(4*THREADS), THREADS, 0, stream>>>(pO, out);
    } else if (ws_size >= need_bits){
        prepack_mask<<<(BB*LL*NT)/THREADS, THREADS, 0, stream>>>(mask, flag, mb);
        attn_fused<1><<<NWG, THREADS, 0, stream>>>(q, k, v, mask, flag, mb, out, attn);
    } else {
        attn_fused<0><<<NWG, THREADS, 0, stream>>>(q, k, v, mask, flag, mb, out, attn);
    }
}

// Round 11
// 265.107 us; speedup vs baseline: 2.0191x; 1.0058x over previous
//
#include <hip/hip_runtime.h>
#include <hip/hip_bf16.h>

#define BB 16
#define LL 2048
#define DD 128
#define SCALE 0.03125f   // 1/sqrt(1024)

#define QT 64            // fallback q-tile
#define QTM 128          // main/sums q-tile (512-thread blocks)
#define KT 64
#define NT (LL/KT)       // 32
#define SPLIT_S 4
#define SKT (NT/SPLIT_S) // 8
#define THREADS 256
#define TMAIN 512
#define NWG   (BB*(LL/QT))          // 512  (fallback grid)
#define NWG_S (BB*SPLIT_S*(LL/QTM)) // 1024 (sums grid)

using bf16x8 = __attribute__((ext_vector_type(8))) short;
using f32x4  = __attribute__((ext_vector_type(4))) float;
using u16x4  = __attribute__((ext_vector_type(4))) unsigned short;
using u32x2  = __attribute__((ext_vector_type(2))) unsigned;
typedef unsigned long long u64;

__device__ __forceinline__ unsigned short f2bf(float f){
    __hip_bfloat16 h = __float2bfloat16(f);
    return *reinterpret_cast<unsigned short*>(&h);
}
__device__ __forceinline__ float bf2f(unsigned short u){
    union { unsigned u; float f; } a; a.u = ((unsigned)u) << 16;
    return a.f;
}
__device__ __forceinline__ unsigned pk2(float lo, float hi){
    return (unsigned)f2bf(lo) | ((unsigned)f2bf(hi) << 16);
}

// Mask layout: 0 = 4-byte int, 1 = 1-byte bool, 2 = 4-byte float.
__device__ __forceinline__ int detect_fl(const unsigned* m, int lane){
    unsigned hi = 0, nl = 0;
    #pragma unroll
    for (int i = 0; i < 16; ++i){
        unsigned d = m[lane*16 + i];
        hi |= (d & 0xFFFFFF00u);
        nl |= (d & 0xFEFEFEFEu);
    }
    unsigned long long bh = __ballot(hi != 0u);
    unsigned long long bn = __ballot(nl != 0u);
    return (bn != 0ull) ? 2 : ((bh != 0ull) ? 1 : 0);
}

__global__ void detect_mask(const unsigned* __restrict__ m, int* __restrict__ flag){
    int f = detect_fl(m, threadIdx.x & 63);
    if ((threadIdx.x & 63) == 0) flag[0] = f;
}

// self-detecting prepack (no detect-kernel dependency on the fast path)
__global__ void prepack_mask(const unsigned char* __restrict__ m,
                             u64* __restrict__ mb){
    __shared__ int sfl;
    if (threadIdx.x < 64){
        int f = detect_fl((const unsigned*)m, threadIdx.x);
        if (threadIdx.x == 0) sfl = f;
    }
    __syncthreads();
    const int fl = sfl;
    int id = blockIdx.x * THREADS + threadIdx.x;
    u64 bits = 0;
    if (fl == 1){
        const uint4* mp = (const uint4*)(m + (size_t)id * 64);
        #pragma unroll
        for (int c = 0; c < 4; ++c){
            uint4 u = mp[c];
            unsigned wd[4] = {u.x, u.y, u.z, u.w};
            #pragma unroll
            for (int wi = 0; wi < 4; ++wi){
                #pragma unroll
                for (int b = 0; b < 4; ++b)
                    if ((wd[wi] >> (8*b)) & 0xFFu) bits |= 1ull << (c*16 + wi*4 + b);
            }
        }
    } else {
        const uint4* mp = (const uint4*)m + (size_t)id * 16;
        #pragma unroll
        for (int c = 0; c < 16; ++c){
            uint4 u = mp[c];
            if (u.x) bits |= 1ull << (c*4+0);
            if (u.y) bits |= 1ull << (c*4+1);
            if (u.z) bits |= 1ull << (c*4+2);
            if (u.w) bits |= 1ull << (c*4+3);
        }
    }
    mb[id] = bits;
}

// ---------------- 256-thread staging macros (fallback) ----------------
#define K_LOAD(T) { const float* kp_ = kbase + (size_t)(T)*KT*DD; \
    _Pragma("unroll") for (int i_ = 0; i_ < 8; ++i_) \
        kpre[i_] = *(const f32x4*)(kp_ + (i_*8 + r0)*DD + c4*4); }

#define K_WRITE() { _Pragma("unroll") for (int i_ = 0; i_ < 8; ++i_){ \
        int row_ = i_*8 + r0; int e_ = (c4*4) ^ (8*(row_ & 7)); \
        u16x4 pk_ = { f2bf(kpre[i_][0]), f2bf(kpre[i_][1]), f2bf(kpre[i_][2]), f2bf(kpre[i_][3]) }; \
        *(u16x4*)(&k_s[row_*DD + e_]) = pk_; } }

#define V_STAGE(T) { const float* vp_ = vbase + (size_t)(T)*KT*DD; \
    f32x4 vv_[8]; \
    _Pragma("unroll") for (int i_ = 0; i_ < 2; ++i_) \
        _Pragma("unroll") for (int rr_ = 0; rr_ < 4; ++rr_) \
            vv_[i_*4+rr_] = *(const f32x4*)(vp_ + ((r0 + 8*i_)*4 + rr_)*DD + c4*4); \
    _Pragma("unroll") for (int i_ = 0; i_ < 2; ++i_){ \
        int rb_ = (r0 + 8*i_)*4; int kk_ = rb_ ^ (8*(c4 & 7)); \
        _Pragma("unroll") for (int cc_ = 0; cc_ < 4; ++cc_){ \
            int d_ = c4*4 + cc_; \
            u16x4 pk_ = { f2bf(vv_[i_*4+0][cc_]), f2bf(vv_[i_*4+1][cc_]), \
                          f2bf(vv_[i_*4+2][cc_]), f2bf(vv_[i_*4+3][cc_]) }; \
            *(u16x4*)(&vT_s[d_*KT + kk_]) = pk_; } } }

#define M_LOADB(DST, T) { _Pragma("unroll") for (int r_ = 0; r_ < 4; ++r_) DST[r_] = mbB[r_*NT + (T)]; }

// ---------------- 512-thread staging macros (main & sums) ----------------
#define K_LOAD4(T) { const float* kp_ = kbase + (size_t)(T)*KT*DD; \
    _Pragma("unroll") for (int i_ = 0; i_ < 4; ++i_) \
        kpre[i_] = *(const f32x4*)(kp_ + (i_*16 + r0)*DD + c4*4); }

#define K_WRITE4() { _Pragma("unroll") for (int i_ = 0; i_ < 4; ++i_){ \
        int row_ = i_*16 + r0; int e_ = (c4*4) ^ (8*(row_ & 7)); \
        u16x4 pk_ = { f2bf(kpre[i_][0]), f2bf(kpre[i_][1]), f2bf(kpre[i_][2]), f2bf(kpre[i_][3]) }; \
        *(u16x4*)(&k_s[row_*DD + e_]) = pk_; } }

#define V_LOAD4(T) { const float* vp_ = vbase + (size_t)(T)*KT*DD; \
    _Pragma("unroll") for (int rr_ = 0; rr_ < 4; ++rr_) \
        vpre[rr_] = *(const f32x4*)(vp_ + (r0*4 + rr_)*DD + c4*4); }

#define V_WRITE4() { \
    _Pragma("unroll") for (int cc_ = 0; cc_ < 4; ++cc_){ \
        int d_ = c4*4 + cc_; \
        int key_ = (c4 & 7) ^ ((cc_ << 1) & 7); \
        int kk_ = (r0*4) ^ (8*key_); \
        u16x4 pk_ = { f2bf(vpre[0][cc_]), f2bf(vpre[1][cc_]), \
                      f2bf(vpre[2][cc_]), f2bf(vpre[3][cc_]) }; \
        *(u16x4*)(&vT_s[d_*KT + kk_]) = pk_; } }

// original orientation (fallback only)
#define QK_MFMA(ACC, CG) { \
    const int krow_ = (CG)*16 + ln15; \
    const unsigned short* kb_ = &k_s[krow_*DD]; \
    const int sw_ = 8*(krow_ & 7); \
    _Pragma("unroll") for (int c_ = 0; c_ < 4; ++c_){ \
        bf16x8 bf_ = *(const bf16x8*)(kb_ + ((c_*32 + g*8) ^ sw_)); \
        ACC = __builtin_amdgcn_mfma_f32_16x16x32_bf16(qa[c_], bf_, ACC, 0, 0, 0); } }

// SWAPPED: acc[r] = S[q=ln15][k=cg*16+4g+r]
#define QK_MFMA_SW(ACC, CG) { \
    const int krow_ = (CG)*16 + ln15; \
    const unsigned short* kb_ = &k_s[krow_*DD]; \
    const int sw_ = 8*(krow_ & 7); \
    _Pragma("unroll") for (int c_ = 0; c_ < 4; ++c_){ \
        bf16x8 bf_ = *(const bf16x8*)(kb_ + ((c_*32 + g*8) ^ sw_)); \
        ACC = __builtin_amdgcn_mfma_f32_16x16x32_bf16(bf_, qa[c_], ACC, 0, 0, 0); } }

#define Q_FRAGS() { \
    const float* qp_ = q + ((size_t)bb*LL + qw0 + ln15)*DD + g*8; \
    _Pragma("unroll") for (int c_ = 0; c_ < 4; ++c_){ \
        f32x4 x_ = *(const f32x4*)(qp_ + c_*32); \
        f32x4 y_ = *(const f32x4*)(qp_ + c_*32 + 4); \
        bf16x8 t_; \
        t_[0]=(short)f2bf(x_[0]); t_[1]=(short)f2bf(x_[1]); t_[2]=(short)f2bf(x_[2]); t_[3]=(short)f2bf(x_[3]); \
        t_[4]=(short)f2bf(y_[0]); t_[5]=(short)f2bf(y_[1]); t_[6]=(short)f2bf(y_[2]); t_[7]=(short)f2bf(y_[3]); \
        qa[c_] = t_; } }

// ========== split kernel 1: partial row sums (QTM=128, SPLIT_S=4, 512 thr) ==========
__global__ __launch_bounds__(TMAIN, 4) void attn_sums(
    const float* __restrict__ q, const float* __restrict__ k,
    const u64* __restrict__ mb, float* __restrict__ lpart)
{
    __shared__ __attribute__((aligned(16))) unsigned short k_s[KT*DD];   // 16 KB

    const int tid  = threadIdx.x;
    const int w    = tid >> 6;       // 0..7
    const int lane = tid & 63;
    const int ln15 = lane & 15;
    const int g    = lane >> 4;
    const int r0   = tid >> 5;       // 0..15
    const int c4   = tid & 31;

    const int hw    = blockIdx.x;
    const int bidx  = (hw & 7) * (NWG_S/8) + (hw >> 3);   // XCD-contiguous
    const int bb    = bidx >> 6;                          // 64 blocks/batch
    const int quart = (bidx >> 4) & 3;
    const int qt0   = (bidx & 15) * QTM;
    const int qw0   = qt0 + w*16;

    bf16x8 qa[4];
    Q_FRAGS();

    const u64* mrow_bits = mb + ((size_t)bb*LL + qw0 + ln15) * NT;

    const float* kbase = k + (size_t)bb*LL*DD;
    f32x4 kpre[4];
    u64 mc = 0, mn = 0;

    const int T0 = quart * SKT;
    float rs = 0.f;
    K_LOAD4(T0); mc = mrow_bits[T0];
    for (int tt = 0; tt < SKT; ++tt){
        const int t = T0 + tt;
        __syncthreads();
        K_WRITE4();
        if (tt+1 < SKT){ K_LOAD4(t+1); mn = mrow_bits[t+1]; }
        __syncthreads();
        #pragma unroll
        for (int cg = 0; cg < 4; ++cg){
            f32x4 acc = {0.f, 0.f, 0.f, 0.f};
            QK_MFMA_SW(acc, cg);
            const int kb0 = cg*16 + 4*g;
            const unsigned nib = (unsigned)(mc >> kb0) & 0xFu;
            #pragma unroll
            for (int r = 0; r < 4; ++r)
                rs += ((nib >> r) & 1u) ? 0.f : __expf(acc[r] * SCALE);
        }
        mc = mn;
    }
    rs += __shfl_xor(rs, 16);
    rs += __shfl_xor(rs, 32);
    if (lane < 16)
        lpart[(size_t)quart*BB*LL + (size_t)bb*LL + qw0 + lane] = rs;
}

// ===== split kernel 2 (templated K-split NS): attn via P-LDS + partial PV =====
template<int NS>
__global__ __launch_bounds__(TMAIN, 4) void attn_main(
    const float* __restrict__ q, const float* __restrict__ k, const float* __restrict__ v,
    const u64* __restrict__ mb, const float* __restrict__ lpart,
    float* __restrict__ attn, float* __restrict__ pO)
{
    __shared__ __attribute__((aligned(16))) unsigned short k_s[KT*DD];    // 16 KB
    __shared__ __attribute__((aligned(16))) unsigned short vT_s[DD*KT];   // 16 KB
    __shared__ __attribute__((aligned(16))) unsigned p_u32[8*512];        // 16 KB

    const int tid  = threadIdx.x;
    const int w    = tid >> 6;       // 0..7
    const int lane = tid & 63;
    const int ln15 = lane & 15;
    const int g    = lane >> 4;
    const int r0   = tid >> 5;       // 0..15
    const int c4   = tid & 31;

    const int NWGM = BB*NS*(LL/QTM);
    const int hw   = blockIdx.x;
    const int bidx = (hw & 7) * (NWGM/8) + (hw >> 3);
    const int perb = NS*(LL/QTM);
    const int bb   = bidx / perb;
    const int rem  = bidx % perb;
    const int part = rem >> 4;            // 0..NS-1   (LL/QTM == 16)
    const int qt0  = (rem & 15) * QTM;
    const int qw0  = qt0 + w*16;

    bf16x8 qa[4];
    Q_FRAGS();

    const size_t qrow = (size_t)bb*LL + qw0 + ln15;
    const u64* mrow_bits = mb + qrow * NT;
    float invl;
    {
        float s = 0.f;
        #pragma unroll
        for (int sl = 0; sl < SPLIT_S; ++sl)
            s += lpart[(size_t)sl*BB*LL + qrow];
        invl = 1.0f / s;
    }

    const float* kbase = k + (size_t)bb*LL*DD;
    const float* vbase = v + (size_t)bb*LL*DD;
    f32x4 kpre[4];
    f32x4 vpre[4];
    u64 mc = 0, mn = 0;

    f32x4 oacc[8];
    #pragma unroll
    for (int d8 = 0; d8 < 8; ++d8) oacc[d8] = (f32x4){0.f, 0.f, 0.f, 0.f};

    unsigned* pw = &p_u32[w*512];   // per-wave: 16 rows x 32 u32 (64 bf16/row)

    const int HKTN = NT/NS;
    const int T0 = part * HKTN;
    K_LOAD4(T0); V_LOAD4(T0); mc = mrow_bits[T0];
    for (int tt = 0; tt < HKTN; ++tt){
        const int t = T0 + tt;
        __syncthreads();
        K_WRITE4(); V_WRITE4();
        if (tt+1 < HKTN){ K_LOAD4(t+1); V_LOAD4(t+1); mn = mrow_bits[t+1]; }
        __syncthreads();
        #pragma unroll
        for (int cg = 0; cg < 4; ++cg){
            f32x4 acc = {0.f, 0.f, 0.f, 0.f};
            QK_MFMA_SW(acc, cg);
            const int kb0 = cg*16 + 4*g;           // lane's 4 consecutive k
            const unsigned nib = (unsigned)(mc >> kb0) & 0xFu;
            f32x4 pv;
            #pragma unroll
            for (int r = 0; r < 4; ++r)
                pv[r] = ((nib >> r) & 1u) ? 0.f : __expf(acc[r] * SCALE) * invl;
            const int m  = cg*4 + g;
            const int mp = (m + ln15) & 15;
            u32x2 wv = { pk2(pv[0], pv[1]), pk2(pv[2], pv[3]) };
            *(u32x2*)(&pw[ln15*32 + mp*2]) = wv;
        }
        // attn stores via P LDS: each instr = 4 rows x 256B CONTIGUOUS
        #pragma unroll
        for (int it = 0; it < 4; ++it){
            const int rl = it*4 + g;               // local row 0..15
            u32x2 pb = *(const u32x2*)(&pw[rl*32 + (((ln15 + rl) & 15)*2)]);
            f32x4 val = { bf2f((unsigned short)(pb[0] & 0xFFFFu)),
                          bf2f((unsigned short)(pb[0] >> 16)),
                          bf2f((unsigned short)(pb[1] & 0xFFFFu)),
                          bf2f((unsigned short)(pb[1] >> 16)) };
            __builtin_nontemporal_store(val,
                (f32x4*)(attn + ((size_t)bb*LL + qw0 + rl)*(size_t)LL + t*KT + ln15*4));
        }
        // PV: A-frags from P LDS, B-frags from vT
        const unsigned* prow_ = &pw[ln15*32];
        u32x2 a00 = *(const u32x2*)(&prow_[(((2*g  ) + ln15) & 15)*2]);
        u32x2 a01 = *(const u32x2*)(&prow_[(((2*g+1) + ln15) & 15)*2]);
        u32x2 a10 = *(const u32x2*)(&prow_[(((8+2*g ) + ln15) & 15)*2]);
        u32x2 a11 = *(const u32x2*)(&prow_[(((9+2*g ) + ln15) & 15)*2]);
        union { unsigned u[4]; bf16x8 v8; } A0, A1;
        A0.u[0]=a00[0]; A0.u[1]=a00[1]; A0.u[2]=a01[0]; A0.u[3]=a01[1];
        A1.u[0]=a10[0]; A1.u[1]=a10[1]; A1.u[2]=a11[0]; A1.u[3]=a11[1];
        const bf16x8 pa0 = A0.v8, pa1 = A1.v8;
        #pragma unroll
        for (int d8 = 0; d8 < 8; ++d8){
            const int d = d8*16 + ln15;
            const unsigned short* vb = &vT_s[d*KT];
            const int ev = 8*((((4*d8 + (ln15 >> 2)) & 7)) ^ ((ln15 & 3) << 1));
            bf16x8 b0 = *(const bf16x8*)(vb + ((g*8) ^ ev));
            bf16x8 b1 = *(const bf16x8*)(vb + ((32 + g*8) ^ ev));
            oacc[d8] = __builtin_amdgcn_mfma_f32_16x16x32_bf16(pa0, b0, oacc[d8], 0, 0, 0);
            oacc[d8] = __builtin_amdgcn_mfma_f32_16x16x32_bf16(pa1, b1, oacc[d8], 0, 0, 0);
        }
        mc = mn;
    }

    // epilogue: partial O
    float* po = pO + (size_t)part*BB*LL*DD;
    #pragma unroll
    for (int d8 = 0; d8 < 8; ++d8){
        #pragma unroll
        for (int r = 0; r < 4; ++r){
            po[((size_t)bb*LL + qw0 + 4*g + r)*DD + d8*16 + ln15] = oacc[d8][r];
        }
    }
}

template<int NS>
__global__ void combine_out(const float* __restrict__ pO, float* __restrict__ out){
    size_t i = ((size_t)blockIdx.x*THREADS + threadIdx.x) * 4;
    f32x4 s = *(const f32x4*)(pO + i);
    #pragma unroll
    for (int sl = 1; sl < NS; ++sl)
        s += *(const f32x4*)(pO + (size_t)sl*BB*LL*DD + i);
    *(f32x4*)(out + i) = s;
}

// ================= fallback: fused two-pass (r7 structure, unswapped) =================
template<int USE_BITS>
__global__ __launch_bounds__(THREADS, 3) void attn_fused(
    const float* __restrict__ q, const float* __restrict__ k, const float* __restrict__ v,
    const unsigned char* __restrict__ maskb, const int* __restrict__ flagp,
    const u64* __restrict__ mb,
    float* __restrict__ out, float* __restrict__ attn)
{
    __shared__ __attribute__((aligned(16))) unsigned short k_s[KT*DD];
    __shared__ __attribute__((aligned(16))) unsigned short vT_s[DD*KT];
    __shared__ __attribute__((aligned(16))) unsigned short p_bf[4*16*64];

    const int tid  = threadIdx.x;
    const int w    = tid >> 6;
    const int lane = tid & 63;
    const int ln15 = lane & 15;
    const int g    = lane >> 4;
    const int r0   = tid >> 5;
    const int c4   = tid & 31;

    const int bidx = blockIdx.x;
    const int bb   = bidx >> 5;
    const int qt0  = (bidx & 31) * QT;
    const int qw0  = qt0 + w*16;

    int msh = 0, madd = 0;
    if (!USE_BITS){
        const int mflag = flagp[0];
        msh  = (mflag == 1) ? 0 : 2;
        madd = (mflag == 2) ? 3 : 0;
    }

    bf16x8 qa[4];
    Q_FRAGS();

    size_t mrow[4];
    const u64* mbB = mb + ((size_t)bb*LL + qw0 + 4*g) * NT;
    #pragma unroll
    for (int r = 0; r < 4; ++r)
        mrow[r] = ((size_t)bb*LL + qw0 + 4*g + r) * (size_t)LL;

    const float* kbase = k + (size_t)bb*LL*DD;
    const float* vbase = v + (size_t)bb*LL*DD;

    f32x4 kpre[8];
    u64 mc[4] = {0,0,0,0}, mn[4] = {0,0,0,0};

    float rs[4] = {0.f, 0.f, 0.f, 0.f};
    K_LOAD(0); if (USE_BITS) M_LOADB(mc, 0);
    for (int t = 0; t < NT; ++t){
        __syncthreads();
        K_WRITE();
        if (t+1 < NT){ K_LOAD(t+1); if (USE_BITS) M_LOADB(mn, t+1); }
        __syncthreads();
        #pragma unroll
        for (int cg = 0; cg < 4; ++cg){
            f32x4 acc = {0.f, 0.f, 0.f, 0.f};
            QK_MFMA(acc, cg);
            const int kc = cg*16 + ln15;
            #pragma unroll
            for (int r = 0; r < 4; ++r){
                bool msk;
                if (USE_BITS) msk = (mc[r] >> kc) & 1ull;
                else          msk = maskb[((mrow[r] + t*KT + kc) << msh) + madd] != 0;
                rs[r] += msk ? 0.f : __expf(acc[r] * SCALE);
            }
        }
        if (USE_BITS){
            #pragma unroll
            for (int r = 0; r < 4; ++r) mc[r] = mn[r];
        }
    }

    float invl[4];
    #pragma unroll
    for (int r = 0; r < 4; ++r){
        float s = rs[r];
        s += __shfl_xor(s, 1); s += __shfl_xor(s, 2);
        s += __shfl_xor(s, 4); s += __shfl_xor(s, 8);
        invl[r] = 1.0f / s;
    }

    f32x4 oacc[8];
    #pragma unroll
    for (int d8 = 0; d8 < 8; ++d8) oacc[d8] = (f32x4){0.f, 0.f, 0.f, 0.f};

    unsigned short* pw = &p_bf[w*1024];
    const int w4 = ln15 >> 2;

    K_LOAD(0); if (USE_BITS) M_LOADB(mc, 0);
    for (int t = 0; t < NT; ++t){
        __syncthreads();
        K_WRITE();
        V_STAGE(t);
        if (t+1 < NT){ K_LOAD(t+1); if (USE_BITS) M_LOADB(mn, t+1); }
        __syncthreads();
        #pragma unroll
        for (int cg = 0; cg < 4; ++cg){
            f32x4 acc = {0.f, 0.f, 0.f, 0.f};
            QK_MFMA(acc, cg);
            const int kc = cg*16 + ln15;
            #pragma unroll
            for (int r = 0; r < 4; ++r){
                bool msk;
                if (USE_BITS) msk = (mc[r] >> kc) & 1ull;
                else          msk = maskb[((mrow[r] + t*KT + kc) << msh) + madd] != 0;
                float p = msk ? 0.f : __expf(acc[r] * SCALE) * invl[r];
                pw[(4*g + r)*64 + (kc ^ (g << 4))] = f2bf(p);
            }
        }
        #pragma unroll
        for (int it = 0; it < 4; ++it){
            int row = it*4 + g;
            u16x4 pb = *(const u16x4*)(&pw[row*64 + ((ln15*4) ^ (it << 4))]);
            f32x4 val = { bf2f(pb[0]), bf2f(pb[1]), bf2f(pb[2]), bf2f(pb[3]) };
            *(f32x4*)(&attn[((size_t)bb*LL + qw0 + row)*(size_t)LL + t*KT + ln15*4]) = val;
        }
        const unsigned short* par = pw + ln15*64;
        bf16x8 pa0 = *(const bf16x8*)(par + ((g*8)      ^ (w4 << 4)));
        bf16x8 pa1 = *(const bf16x8*)(par + ((32 + g*8) ^ (w4 << 4)));
        #pragma unroll
        for (int d8 = 0; d8 < 8; ++d8){
            const int d = d8*16 + ln15;
            const unsigned short* vb = &vT_s[d*KT];
            const int ev = 8*((4*d8 + (ln15 >> 2)) & 7);
            bf16x8 b0 = *(const bf16x8*)(vb + ((g*8) ^ ev));
            bf16x8 b1 = *(const bf16x8*)(vb + ((32 + g*8) ^ ev));
            oacc[d8] = __builtin_amdgcn_mfma_f32_16x16x32_bf16(pa0, b0, oacc[d8], 0, 0, 0);
            oacc[d8] = __builtin_amdgcn_mfma_f32_16x16x32_bf16(pa1, b1, oacc[d8], 0, 0, 0);
        }
        if (USE_BITS){
            #pragma unroll
            for (int r = 0; r < 4; ++r) mc[r] = mn[r];
        }
    }

    #pragma unroll
    for (int d8 = 0; d8 < 8; ++d8){
        #pragma unroll
        for (int r = 0; r < 4; ++r){
            out[((size_t)bb*LL + qw0 + 4*g + r)*DD + d8*16 + ln15] = oacc[d8][r];
        }
    }
}

extern "C" void kernel_launch(void* const* d_in, const int* in_sizes, int n_in,
                              void* d_out, int out_size, void* d_ws, size_t ws_size,
                              hipStream_t stream)
{
    const float* q = (const float*)d_in[0];
    const float* k = (const float*)d_in[1];
    const float* v = (const float*)d_in[2];
    const unsigned char* mask = (const unsigned char*)d_in[3];

    float* out  = (float*)d_out;
    float* attn = out + (size_t)BB*LL*DD;

    const size_t bits_sz = (size_t)BB*LL*NT*sizeof(u64);           // 8 MB
    const size_t off_l   = 256 + bits_sz;
    const size_t l_sz    = (size_t)SPLIT_S*BB*LL*sizeof(float);    // 512 KB
    const size_t off_pO  = off_l + l_sz;
    const size_t oO      = (size_t)BB*LL*DD*sizeof(float);         // 16.8 MB / partial
    const size_t need4   = off_pO + 4*oO;                          // ~75.9 MB
    const size_t need2   = off_pO + 2*oO;                          // ~42.4 MB (r10-proven)
    const size_t need_bits = 256 + bits_sz;

    int*   flag  = (int*)d_ws;
    u64*   mb    = (u64*)((char*)d_ws + 256);
    float* lpart = (float*)((char*)d_ws + off_l);
    float* pO    = (float*)((char*)d_ws + off_pO);

    if (ws_size >= need2){
        prepack_mask<<<(BB*LL*NT)/THREADS, THREADS, 0, stream>>>(mask, mb);
        attn_sums<<<NWG_S, TMAIN, 0, stream>>>(q, k, mb, lpart);
        if (ws_size >= need4){
            attn_main<4><<<BB*4*(LL/QTM), TMAIN, 0, stream>>>(q, k, v, mb, lpart, attn, pO);
            combine_out<4><<<(BB*LL*DD)/(4*THREADS), THREADS, 0, stream>>>(pO, out);
        } else {
            attn_main<2><<<BB*2*(LL/QTM), TMAIN, 0, stream>>>(q, k, v, mb, lpart, attn, pO);
            combine_out<2><<<(BB*LL*DD)/(4*THREADS), THREADS, 0, stream>>>(pO, out);
        }
    } else if (ws_size >= need_bits){
        detect_mask<<<1, 64, 0, stream>>>((const unsigned*)mask, flag);
        prepack_mask<<<(BB*LL*NT)/THREADS, THREADS, 0, stream>>>(mask, mb);
        attn_fused<1><<<NWG, THREADS, 0, stream>>>(q, k, v, mask, flag, mb, out, attn);
    } else {
        detect_mask<<<1, 64, 0, stream>>>((const unsigned*)mask, flag);
        attn_fused<0><<<NWG, THREADS, 0, stream>>>(q, k, v, mask, flag, mb, out, attn);
    }
}

// Round 12
// 244.894 us; speedup vs baseline: 2.1857x; 1.0825x over previous
//
#include <hip/hip_runtime.h>
#include <hip/hip_bf16.h>

#define BB 16
#define LL 2048
#define DD 128
#define SCALE 0.03125f   // 1/sqrt(1024)

#define QT 64            // fallback q-tile
#define QTM 128          // main/sums q-tile (512-thread blocks)
#define KT 64
#define NT (LL/KT)       // 32
#define SPLIT_S 4
#define SKT (NT/SPLIT_S) // 8
#define THREADS 256
#define TMAIN 512
#define NWG   (BB*(LL/QT))          // 512  (fallback grid)
#define NWG_S (BB*SPLIT_S*(LL/QTM)) // 1024 (scores grid)

using bf16x8 = __attribute__((ext_vector_type(8))) short;
using f32x4  = __attribute__((ext_vector_type(4))) float;
using u16x4  = __attribute__((ext_vector_type(4))) unsigned short;
using u32x2  = __attribute__((ext_vector_type(2))) unsigned;
typedef unsigned long long u64;

__device__ __forceinline__ unsigned short f2bf(float f){
    __hip_bfloat16 h = __float2bfloat16(f);
    return *reinterpret_cast<unsigned short*>(&h);
}
__device__ __forceinline__ float bf2f(unsigned short u){
    union { unsigned u; float f; } a; a.u = ((unsigned)u) << 16;
    return a.f;
}
__device__ __forceinline__ unsigned pk2(float lo, float hi){
    return (unsigned)f2bf(lo) | ((unsigned)f2bf(hi) << 16);
}

// Mask layout: 0 = 4-byte int, 1 = 1-byte bool, 2 = 4-byte float.
__device__ __forceinline__ int detect_fl(const unsigned* m, int lane){
    unsigned hi = 0, nl = 0;
    #pragma unroll
    for (int i = 0; i < 16; ++i){
        unsigned d = m[lane*16 + i];
        hi |= (d & 0xFFFFFF00u);
        nl |= (d & 0xFEFEFEFEu);
    }
    unsigned long long bh = __ballot(hi != 0u);
    unsigned long long bn = __ballot(nl != 0u);
    return (bn != 0ull) ? 2 : ((bh != 0ull) ? 1 : 0);
}

__global__ void detect_mask(const unsigned* __restrict__ m, int* __restrict__ flag){
    int f = detect_fl(m, threadIdx.x & 63);
    if ((threadIdx.x & 63) == 0) flag[0] = f;
}

__global__ void prepack_mask(const unsigned char* __restrict__ m,
                             u64* __restrict__ mb){
    __shared__ int sfl;
    if (threadIdx.x < 64){
        int f = detect_fl((const unsigned*)m, threadIdx.x);
        if (threadIdx.x == 0) sfl = f;
    }
    __syncthreads();
    const int fl = sfl;
    int id = blockIdx.x * THREADS + threadIdx.x;
    u64 bits = 0;
    if (fl == 1){
        const uint4* mp = (const uint4*)(m + (size_t)id * 64);
        #pragma unroll
        for (int c = 0; c < 4; ++c){
            uint4 u = mp[c];
            unsigned wd[4] = {u.x, u.y, u.z, u.w};
            #pragma unroll
            for (int wi = 0; wi < 4; ++wi){
                #pragma unroll
                for (int b = 0; b < 4; ++b)
                    if ((wd[wi] >> (8*b)) & 0xFFu) bits |= 1ull << (c*16 + wi*4 + b);
            }
        }
    } else {
        const uint4* mp = (const uint4*)m + (size_t)id * 16;
        #pragma unroll
        for (int c = 0; c < 16; ++c){
            uint4 u = mp[c];
            if (u.x) bits |= 1ull << (c*4+0);
            if (u.y) bits |= 1ull << (c*4+1);
            if (u.z) bits |= 1ull << (c*4+2);
            if (u.w) bits |= 1ull << (c*4+3);
        }
    }
    mb[id] = bits;
}

// ---------------- 256-thread staging macros (fallback) ----------------
#define K_LOAD(T) { const float* kp_ = kbase + (size_t)(T)*KT*DD; \
    _Pragma("unroll") for (int i_ = 0; i_ < 8; ++i_) \
        kpre[i_] = *(const f32x4*)(kp_ + (i_*8 + r0)*DD + c4*4); }

#define K_WRITE() { _Pragma("unroll") for (int i_ = 0; i_ < 8; ++i_){ \
        int row_ = i_*8 + r0; int e_ = (c4*4) ^ (8*(row_ & 7)); \
        u16x4 pk_ = { f2bf(kpre[i_][0]), f2bf(kpre[i_][1]), f2bf(kpre[i_][2]), f2bf(kpre[i_][3]) }; \
        *(u16x4*)(&k_s[row_*DD + e_]) = pk_; } }

#define V_STAGE(T) { const float* vp_ = vbase + (size_t)(T)*KT*DD; \
    f32x4 vv_[8]; \
    _Pragma("unroll") for (int i_ = 0; i_ < 2; ++i_) \
        _Pragma("unroll") for (int rr_ = 0; rr_ < 4; ++rr_) \
            vv_[i_*4+rr_] = *(const f32x4*)(vp_ + ((r0 + 8*i_)*4 + rr_)*DD + c4*4); \
    _Pragma("unroll") for (int i_ = 0; i_ < 2; ++i_){ \
        int rb_ = (r0 + 8*i_)*4; int kk_ = rb_ ^ (8*(c4 & 7)); \
        _Pragma("unroll") for (int cc_ = 0; cc_ < 4; ++cc_){ \
            int d_ = c4*4 + cc_; \
            u16x4 pk_ = { f2bf(vv_[i_*4+0][cc_]), f2bf(vv_[i_*4+1][cc_]), \
                          f2bf(vv_[i_*4+2][cc_]), f2bf(vv_[i_*4+3][cc_]) }; \
            *(u16x4*)(&vT_s[d_*KT + kk_]) = pk_; } } }

#define M_LOADB(DST, T) { _Pragma("unroll") for (int r_ = 0; r_ < 4; ++r_) DST[r_] = mbB[r_*NT + (T)]; }

// ---------------- 512-thread staging macros ----------------
#define K_LOAD4(T) { const float* kp_ = kbase + (size_t)(T)*KT*DD; \
    _Pragma("unroll") for (int i_ = 0; i_ < 4; ++i_) \
        kpre[i_] = *(const f32x4*)(kp_ + (i_*16 + r0)*DD + c4*4); }

#define K_WRITE4() { _Pragma("unroll") for (int i_ = 0; i_ < 4; ++i_){ \
        int row_ = i_*16 + r0; int e_ = (c4*4) ^ (8*(row_ & 7)); \
        u16x4 pk_ = { f2bf(kpre[i_][0]), f2bf(kpre[i_][1]), f2bf(kpre[i_][2]), f2bf(kpre[i_][3]) }; \
        *(u16x4*)(&k_s[row_*DD + e_]) = pk_; } }

#define V_LOAD4(T) { const float* vp_ = vbase + (size_t)(T)*KT*DD; \
    _Pragma("unroll") for (int rr_ = 0; rr_ < 4; ++rr_) \
        vpre[rr_] = *(const f32x4*)(vp_ + (r0*4 + rr_)*DD + c4*4); }

#define V_WRITE4() { \
    _Pragma("unroll") for (int cc_ = 0; cc_ < 4; ++cc_){ \
        int d_ = c4*4 + cc_; \
        int key_ = (c4 & 7) ^ ((cc_ << 1) & 7); \
        int kk_ = (r0*4) ^ (8*key_); \
        u16x4 pk_ = { f2bf(vpre[0][cc_]), f2bf(vpre[1][cc_]), \
                      f2bf(vpre[2][cc_]), f2bf(vpre[3][cc_]) }; \
        *(u16x4*)(&vT_s[d_*KT + kk_]) = pk_; } }

// original orientation (fallback only)
#define QK_MFMA(ACC, CG) { \
    const int krow_ = (CG)*16 + ln15; \
    const unsigned short* kb_ = &k_s[krow_*DD]; \
    const int sw_ = 8*(krow_ & 7); \
    _Pragma("unroll") for (int c_ = 0; c_ < 4; ++c_){ \
        bf16x8 bf_ = *(const bf16x8*)(kb_ + ((c_*32 + g*8) ^ sw_)); \
        ACC = __builtin_amdgcn_mfma_f32_16x16x32_bf16(qa[c_], bf_, ACC, 0, 0, 0); } }

// SWAPPED: acc[r] = S[q=ln15][k=cg*16+4g+r]
#define QK_MFMA_SW(ACC, CG) { \
    const int krow_ = (CG)*16 + ln15; \
    const unsigned short* kb_ = &k_s[krow_*DD]; \
    const int sw_ = 8*(krow_ & 7); \
    _Pragma("unroll") for (int c_ = 0; c_ < 4; ++c_){ \
        bf16x8 bf_ = *(const bf16x8*)(kb_ + ((c_*32 + g*8) ^ sw_)); \
        ACC = __builtin_amdgcn_mfma_f32_16x16x32_bf16(bf_, qa[c_], ACC, 0, 0, 0); } }

#define Q_FRAGS() { \
    const float* qp_ = q + ((size_t)bb*LL + qw0 + ln15)*DD + g*8; \
    _Pragma("unroll") for (int c_ = 0; c_ < 4; ++c_){ \
        f32x4 x_ = *(const f32x4*)(qp_ + c_*32); \
        f32x4 y_ = *(const f32x4*)(qp_ + c_*32 + 4); \
        bf16x8 t_; \
        t_[0]=(short)f2bf(x_[0]); t_[1]=(short)f2bf(x_[1]); t_[2]=(short)f2bf(x_[2]); t_[3]=(short)f2bf(x_[3]); \
        t_[4]=(short)f2bf(y_[0]); t_[5]=(short)f2bf(y_[1]); t_[6]=(short)f2bf(y_[2]); t_[7]=(short)f2bf(y_[3]); \
        qa[c_] = t_; } }

// ========== kernel 1: scores — partial row sums + (optional) unnormalized P~ ==========
template<int STOREP>
__global__ __launch_bounds__(TMAIN, 4) void scores(
    const float* __restrict__ q, const float* __restrict__ k,
    const u64* __restrict__ mb, float* __restrict__ lpart,
    unsigned short* __restrict__ pS)
{
    __shared__ __attribute__((aligned(16))) unsigned short k_s[KT*DD];   // 16 KB
    __shared__ __attribute__((aligned(16))) unsigned p_u32[8*512];       // 16 KB

    const int tid  = threadIdx.x;
    const int w    = tid >> 6;
    const int lane = tid & 63;
    const int ln15 = lane & 15;
    const int g    = lane >> 4;
    const int r0   = tid >> 5;
    const int c4   = tid & 31;

    const int hw    = blockIdx.x;
    const int bidx  = (hw & 7) * (NWG_S/8) + (hw >> 3);   // XCD-contiguous
    const int bb    = bidx >> 6;
    const int quart = (bidx >> 4) & 3;
    const int qt0   = (bidx & 15) * QTM;
    const int qw0   = qt0 + w*16;

    bf16x8 qa[4];
    Q_FRAGS();

    const u64* mrow_bits = mb + ((size_t)bb*LL + qw0 + ln15) * NT;

    const float* kbase = k + (size_t)bb*LL*DD;
    f32x4 kpre[4];
    u64 mc = 0, mn = 0;

    unsigned* pw = &p_u32[w*512];

    const int T0 = quart * SKT;
    float rs = 0.f;
    K_LOAD4(T0); mc = mrow_bits[T0];
    for (int tt = 0; tt < SKT; ++tt){
        const int t = T0 + tt;
        __syncthreads();
        K_WRITE4();
        if (tt+1 < SKT){ K_LOAD4(t+1); mn = mrow_bits[t+1]; }
        __syncthreads();
        #pragma unroll
        for (int cg = 0; cg < 4; ++cg){
            f32x4 acc = {0.f, 0.f, 0.f, 0.f};
            QK_MFMA_SW(acc, cg);
            const int kb0 = cg*16 + 4*g;
            const unsigned nib = (unsigned)(mc >> kb0) & 0xFu;
            float p0 = (nib & 1u) ? 0.f : __expf(acc[0] * SCALE);
            float p1 = (nib & 2u) ? 0.f : __expf(acc[1] * SCALE);
            float p2 = (nib & 4u) ? 0.f : __expf(acc[2] * SCALE);
            float p3 = (nib & 8u) ? 0.f : __expf(acc[3] * SCALE);
            rs += (p0 + p1) + (p2 + p3);
            if (STOREP){
                const int mp = ((cg*4 + g) + ln15) & 15;
                u32x2 wv = { pk2(p0, p1), pk2(p2, p3) };
                *(u32x2*)(&pw[ln15*32 + mp*2]) = wv;
            }
        }
        if (STOREP){
            // write P~ tile: per instr 4 rows x 128B contiguous bf16
            #pragma unroll
            for (int i = 0; i < 4; ++i){
                const int rl = i*4 + g;
                u32x2 pb = *(const u32x2*)(&pw[rl*32 + (((ln15 + rl) & 15)*2)]);
                *(u32x2*)(pS + ((size_t)bb*LL + qw0 + rl)*(size_t)LL + t*KT + ln15*4) = pb;
            }
        }
        mc = mn;
    }
    rs += __shfl_xor(rs, 16);
    rs += __shfl_xor(rs, 32);
    if (lane < 16)
        lpart[(size_t)quart*BB*LL + (size_t)bb*LL + qw0 + lane] = rs;
}

// ===== kernel 2 V2: read P~, write attn (normalized) + partial PV — no QK/mask/exp =====
template<int NS>
__global__ __launch_bounds__(TMAIN, 4) void attn_main_v2(
    const float* __restrict__ v, const unsigned short* __restrict__ pS,
    const float* __restrict__ lpart,
    float* __restrict__ attn, float* __restrict__ pO)
{
    __shared__ __attribute__((aligned(16))) unsigned short vT_s[DD*KT];   // 16 KB

    const int tid  = threadIdx.x;
    const int w    = tid >> 6;
    const int lane = tid & 63;
    const int ln15 = lane & 15;
    const int g    = lane >> 4;
    const int r0   = tid >> 5;
    const int c4   = tid & 31;

    const int NWGM = BB*NS*(LL/QTM);
    const int hw   = blockIdx.x;
    const int bidx = (hw & 7) * (NWGM/8) + (hw >> 3);
    const int perb = NS*(LL/QTM);
    const int bb   = bidx / perb;
    const int rem  = bidx % perb;
    const int part = rem >> 4;
    const int qt0  = (rem & 15) * QTM;
    const int qw0  = qt0 + w*16;

    // inverse row sums: invlA[i] for attn rows (i*4+g), invlE[r] for O rows (4g+r)
    float invlA[4], invlE[4];
    #pragma unroll
    for (int i = 0; i < 4; ++i){
        float sA = 0.f, sE = 0.f;
        #pragma unroll
        for (int sl = 0; sl < SPLIT_S; ++sl){
            sA += lpart[(size_t)sl*BB*LL + (size_t)bb*LL + qw0 + i*4 + g];
            sE += lpart[(size_t)sl*BB*LL + (size_t)bb*LL + qw0 + 4*g + i];
        }
        invlA[i] = 1.0f / sA;
        invlE[i] = 1.0f / sE;
    }

    const float* vbase = v + (size_t)bb*LL*DD;
    f32x4 vpre[4];

    const unsigned short* prow = pS + ((size_t)bb*LL + qw0 + ln15)*(size_t)LL;
    size_t arow_off[4];
    #pragma unroll
    for (int i = 0; i < 4; ++i)
        arow_off[i] = ((size_t)bb*LL + qw0 + i*4 + g)*(size_t)LL;

    f32x4 oacc[8];
    #pragma unroll
    for (int d8 = 0; d8 < 8; ++d8) oacc[d8] = (f32x4){0.f, 0.f, 0.f, 0.f};

    const int HKTN = NT/NS;
    const int T0 = part * HKTN;
    V_LOAD4(T0);
    for (int tt = 0; tt < HKTN; ++tt){
        const int t = T0 + tt;
        // issue P~ loads early (global, independent of LDS barriers)
        bf16x8 pa0 = *(const bf16x8*)(prow + t*KT + 8*g);
        bf16x8 pa1 = *(const bf16x8*)(prow + t*KT + 32 + 8*g);
        u32x2 pb[4];
        #pragma unroll
        for (int i = 0; i < 4; ++i)
            pb[i] = *(const u32x2*)(pS + arow_off[i] + t*KT + ln15*4);
        __syncthreads();
        V_WRITE4();
        if (tt+1 < HKTN) V_LOAD4(t+1);
        __syncthreads();
        // attn: normalized, 256B-contiguous NT stores (4 rows per instr)
        #pragma unroll
        for (int i = 0; i < 4; ++i){
            f32x4 val = { bf2f((unsigned short)(pb[i][0] & 0xFFFFu)) * invlA[i],
                          bf2f((unsigned short)(pb[i][0] >> 16))     * invlA[i],
                          bf2f((unsigned short)(pb[i][1] & 0xFFFFu)) * invlA[i],
                          bf2f((unsigned short)(pb[i][1] >> 16))     * invlA[i] };
            __builtin_nontemporal_store(val,
                (f32x4*)(attn + arow_off[i] + t*KT + ln15*4));
        }
        // PV on raw P~ (invl applied at epilogue)
        #pragma unroll
        for (int d8 = 0; d8 < 8; ++d8){
            const int d = d8*16 + ln15;
            const unsigned short* vb = &vT_s[d*KT];
            const int ev = 8*((((4*d8 + (ln15 >> 2)) & 7)) ^ ((ln15 & 3) << 1));
            bf16x8 b0 = *(const bf16x8*)(vb + ((g*8) ^ ev));
            bf16x8 b1 = *(const bf16x8*)(vb + ((32 + g*8) ^ ev));
            oacc[d8] = __builtin_amdgcn_mfma_f32_16x16x32_bf16(pa0, b0, oacc[d8], 0, 0, 0);
            oacc[d8] = __builtin_amdgcn_mfma_f32_16x16x32_bf16(pa1, b1, oacc[d8], 0, 0, 0);
        }
    }

    // epilogue: partial O, scaled by invlE
    float* po = pO + (size_t)part*BB*LL*DD;
    #pragma unroll
    for (int d8 = 0; d8 < 8; ++d8){
        #pragma unroll
        for (int r = 0; r < 4; ++r){
            po[((size_t)bb*LL + qw0 + 4*g + r)*DD + d8*16 + ln15] = oacc[d8][r] * invlE[r];
        }
    }
}

// ===== old kernel 2 (r11-proven fallback): QK in-kernel =====
template<int NS>
__global__ __launch_bounds__(TMAIN, 4) void attn_main(
    const float* __restrict__ q, const float* __restrict__ k, const float* __restrict__ v,
    const u64* __restrict__ mb, const float* __restrict__ lpart,
    float* __restrict__ attn, float* __restrict__ pO)
{
    __shared__ __attribute__((aligned(16))) unsigned short k_s[KT*DD];
    __shared__ __attribute__((aligned(16))) unsigned short vT_s[DD*KT];
    __shared__ __attribute__((aligned(16))) unsigned p_u32[8*512];

    const int tid  = threadIdx.x;
    const int w    = tid >> 6;
    const int lane = tid & 63;
    const int ln15 = lane & 15;
    const int g    = lane >> 4;
    const int r0   = tid >> 5;
    const int c4   = tid & 31;

    const int NWGM = BB*NS*(LL/QTM);
    const int hw   = blockIdx.x;
    const int bidx = (hw & 7) * (NWGM/8) + (hw >> 3);
    const int perb = NS*(LL/QTM);
    const int bb   = bidx / perb;
    const int rem  = bidx % perb;
    const int part = rem >> 4;
    const int qt0  = (rem & 15) * QTM;
    const int qw0  = qt0 + w*16;

    bf16x8 qa[4];
    Q_FRAGS();

    const size_t qrow = (size_t)bb*LL + qw0 + ln15;
    const u64* mrow_bits = mb + qrow * NT;
    float invl;
    {
        float s = 0.f;
        #pragma unroll
        for (int sl = 0; sl < SPLIT_S; ++sl)
            s += lpart[(size_t)sl*BB*LL + qrow];
        invl = 1.0f / s;
    }

    const float* kbase = k + (size_t)bb*LL*DD;
    const float* vbase = v + (size_t)bb*LL*DD;
    f32x4 kpre[4];
    f32x4 vpre[4];
    u64 mc = 0, mn = 0;

    f32x4 oacc[8];
    #pragma unroll
    for (int d8 = 0; d8 < 8; ++d8) oacc[d8] = (f32x4){0.f, 0.f, 0.f, 0.f};

    unsigned* pw = &p_u32[w*512];

    const int HKTN = NT/NS;
    const int T0 = part * HKTN;
    K_LOAD4(T0); V_LOAD4(T0); mc = mrow_bits[T0];
    for (int tt = 0; tt < HKTN; ++tt){
        const int t = T0 + tt;
        __syncthreads();
        K_WRITE4(); V_WRITE4();
        if (tt+1 < HKTN){ K_LOAD4(t+1); V_LOAD4(t+1); mn = mrow_bits[t+1]; }
        __syncthreads();
        #pragma unroll
        for (int cg = 0; cg < 4; ++cg){
            f32x4 acc = {0.f, 0.f, 0.f, 0.f};
            QK_MFMA_SW(acc, cg);
            const int kb0 = cg*16 + 4*g;
            const unsigned nib = (unsigned)(mc >> kb0) & 0xFu;
            f32x4 pv;
            #pragma unroll
            for (int r = 0; r < 4; ++r)
                pv[r] = ((nib >> r) & 1u) ? 0.f : __expf(acc[r] * SCALE) * invl;
            const int m  = cg*4 + g;
            const int mp = (m + ln15) & 15;
            u32x2 wv = { pk2(pv[0], pv[1]), pk2(pv[2], pv[3]) };
            *(u32x2*)(&pw[ln15*32 + mp*2]) = wv;
        }
        #pragma unroll
        for (int it = 0; it < 4; ++it){
            const int rl = it*4 + g;
            u32x2 pb = *(const u32x2*)(&pw[rl*32 + (((ln15 + rl) & 15)*2)]);
            f32x4 val = { bf2f((unsigned short)(pb[0] & 0xFFFFu)),
                          bf2f((unsigned short)(pb[0] >> 16)),
                          bf2f((unsigned short)(pb[1] & 0xFFFFu)),
                          bf2f((unsigned short)(pb[1] >> 16)) };
            __builtin_nontemporal_store(val,
                (f32x4*)(attn + ((size_t)bb*LL + qw0 + rl)*(size_t)LL + t*KT + ln15*4));
        }
        const unsigned* prow_ = &pw[ln15*32];
        u32x2 a00 = *(const u32x2*)(&prow_[(((2*g  ) + ln15) & 15)*2]);
        u32x2 a01 = *(const u32x2*)(&prow_[(((2*g+1) + ln15) & 15)*2]);
        u32x2 a10 = *(const u32x2*)(&prow_[(((8+2*g ) + ln15) & 15)*2]);
        u32x2 a11 = *(const u32x2*)(&prow_[(((9+2*g ) + ln15) & 15)*2]);
        union { unsigned u[4]; bf16x8 v8; } A0, A1;
        A0.u[0]=a00[0]; A0.u[1]=a00[1]; A0.u[2]=a01[0]; A0.u[3]=a01[1];
        A1.u[0]=a10[0]; A1.u[1]=a10[1]; A1.u[2]=a11[0]; A1.u[3]=a11[1];
        const bf16x8 pa0 = A0.v8, pa1 = A1.v8;
        #pragma unroll
        for (int d8 = 0; d8 < 8; ++d8){
            const int d = d8*16 + ln15;
            const unsigned short* vb = &vT_s[d*KT];
            const int ev = 8*((((4*d8 + (ln15 >> 2)) & 7)) ^ ((ln15 & 3) << 1));
            bf16x8 b0 = *(const bf16x8*)(vb + ((g*8) ^ ev));
            bf16x8 b1 = *(const bf16x8*)(vb + ((32 + g*8) ^ ev));
            oacc[d8] = __builtin_amdgcn_mfma_f32_16x16x32_bf16(pa0, b0, oacc[d8], 0, 0, 0);
            oacc[d8] = __builtin_amdgcn_mfma_f32_16x16x32_bf16(pa1, b1, oacc[d8], 0, 0, 0);
        }
        mc = mn;
    }

    float* po = pO + (size_t)part*BB*LL*DD;
    #pragma unroll
    for (int d8 = 0; d8 < 8; ++d8){
        #pragma unroll
        for (int r = 0; r < 4; ++r){
            po[((size_t)bb*LL + qw0 + 4*g + r)*DD + d8*16 + ln15] = oacc[d8][r];
        }
    }
}

template<int NS>
__global__ void combine_out(const float* __restrict__ pO, float* __restrict__ out){
    size_t i = ((size_t)blockIdx.x*THREADS + threadIdx.x) * 4;
    f32x4 s = *(const f32x4*)(pO + i);
    #pragma unroll
    for (int sl = 1; sl < NS; ++sl)
        s += *(const f32x4*)(pO + (size_t)sl*BB*LL*DD + i);
    *(f32x4*)(out + i) = s;
}

// ================= fallback: fused two-pass (unswapped) =================
template<int USE_BITS>
__global__ __launch_bounds__(THREADS, 3) void attn_fused(
    const float* __restrict__ q, const float* __restrict__ k, const float* __restrict__ v,
    const unsigned char* __restrict__ maskb, const int* __restrict__ flagp,
    const u64* __restrict__ mb,
    float* __restrict__ out, float* __restrict__ attn)
{
    __shared__ __attribute__((aligned(16))) unsigned short k_s[KT*DD];
    __shared__ __attribute__((aligned(16))) unsigned short vT_s[DD*KT];
    __shared__ __attribute__((aligned(16))) unsigned short p_bf[4*16*64];

    const int tid  = threadIdx.x;
    const int w    = tid >> 6;
    const int lane = tid & 63;
    const int ln15 = lane & 15;
    const int g    = lane >> 4;
    const int r0   = tid >> 5;
    const int c4   = tid & 31;

    const int bidx = blockIdx.x;
    const int bb   = bidx >> 5;
    const int qt0  = (bidx & 31) * QT;
    const int qw0  = qt0 + w*16;

    int msh = 0, madd = 0;
    if (!USE_BITS){
        const int mflag = flagp[0];
        msh  = (mflag == 1) ? 0 : 2;
        madd = (mflag == 2) ? 3 : 0;
    }

    bf16x8 qa[4];
    Q_FRAGS();

    size_t mrow[4];
    const u64* mbB = mb + ((size_t)bb*LL + qw0 + 4*g) * NT;
    #pragma unroll
    for (int r = 0; r < 4; ++r)
        mrow[r] = ((size_t)bb*LL + qw0 + 4*g + r) * (size_t)LL;

    const float* kbase = k + (size_t)bb*LL*DD;
    const float* vbase = v + (size_t)bb*LL*DD;

    f32x4 kpre[8];
    u64 mc[4] = {0,0,0,0}, mn[4] = {0,0,0,0};

    float rs[4] = {0.f, 0.f, 0.f, 0.f};
    K_LOAD(0); if (USE_BITS) M_LOADB(mc, 0);
    for (int t = 0; t < NT; ++t){
        __syncthreads();
        K_WRITE();
        if (t+1 < NT){ K_LOAD(t+1); if (USE_BITS) M_LOADB(mn, t+1); }
        __syncthreads();
        #pragma unroll
        for (int cg = 0; cg < 4; ++cg){
            f32x4 acc = {0.f, 0.f, 0.f, 0.f};
            QK_MFMA(acc, cg);
            const int kc = cg*16 + ln15;
            #pragma unroll
            for (int r = 0; r < 4; ++r){
                bool msk;
                if (USE_BITS) msk = (mc[r] >> kc) & 1ull;
                else          msk = maskb[((mrow[r] + t*KT + kc) << msh) + madd] != 0;
                rs[r] += msk ? 0.f : __expf(acc[r] * SCALE);
            }
        }
        if (USE_BITS){
            #pragma unroll
            for (int r = 0; r < 4; ++r) mc[r] = mn[r];
        }
    }

    float invl[4];
    #pragma unroll
    for (int r = 0; r < 4; ++r){
        float s = rs[r];
        s += __shfl_xor(s, 1); s += __shfl_xor(s, 2);
        s += __shfl_xor(s, 4); s += __shfl_xor(s, 8);
        invl[r] = 1.0f / s;
    }

    f32x4 oacc[8];
    #pragma unroll
    for (int d8 = 0; d8 < 8; ++d8) oacc[d8] = (f32x4){0.f, 0.f, 0.f, 0.f};

    unsigned short* pw = &p_bf[w*1024];
    const int w4 = ln15 >> 2;

    K_LOAD(0); if (USE_BITS) M_LOADB(mc, 0);
    for (int t = 0; t < NT; ++t){
        __syncthreads();
        K_WRITE();
        V_STAGE(t);
        if (t+1 < NT){ K_LOAD(t+1); if (USE_BITS) M_LOADB(mn, t+1); }
        __syncthreads();
        #pragma unroll
        for (int cg = 0; cg < 4; ++cg){
            f32x4 acc = {0.f, 0.f, 0.f, 0.f};
            QK_MFMA(acc, cg);
            const int kc = cg*16 + ln15;
            #pragma unroll
            for (int r = 0; r < 4; ++r){
                bool msk;
                if (USE_BITS) msk = (mc[r] >> kc) & 1ull;
                else          msk = maskb[((mrow[r] + t*KT + kc) << msh) + madd] != 0;
                float p = msk ? 0.f : __expf(acc[r] * SCALE) * invl[r];
                pw[(4*g + r)*64 + (kc ^ (g << 4))] = f2bf(p);
            }
        }
        #pragma unroll
        for (int it = 0; it < 4; ++it){
            int row = it*4 + g;
            u16x4 pb = *(const u16x4*)(&pw[row*64 + ((ln15*4) ^ (it << 4))]);
            f32x4 val = { bf2f(pb[0]), bf2f(pb[1]), bf2f(pb[2]), bf2f(pb[3]) };
            *(f32x4*)(&attn[((size_t)bb*LL + qw0 + row)*(size_t)LL + t*KT + ln15*4]) = val;
        }
        const unsigned short* par = pw + ln15*64;
        bf16x8 pa0 = *(const bf16x8*)(par + ((g*8)      ^ (w4 << 4)));
        bf16x8 pa1 = *(const bf16x8*)(par + ((32 + g*8) ^ (w4 << 4)));
        #pragma unroll
        for (int d8 = 0; d8 < 8; ++d8){
            const int d = d8*16 + ln15;
            const unsigned short* vb = &vT_s[d*KT];
            const int ev = 8*((4*d8 + (ln15 >> 2)) & 7);
            bf16x8 b0 = *(const bf16x8*)(vb + ((g*8) ^ ev));
            bf16x8 b1 = *(const bf16x8*)(vb + ((32 + g*8) ^ ev));
            oacc[d8] = __builtin_amdgcn_mfma_f32_16x16x32_bf16(pa0, b0, oacc[d8], 0, 0, 0);
            oacc[d8] = __builtin_amdgcn_mfma_f32_16x16x32_bf16(pa1, b1, oacc[d8], 0, 0, 0);
        }
        if (USE_BITS){
            #pragma unroll
            for (int r = 0; r < 4; ++r) mc[r] = mn[r];
        }
    }

    #pragma unroll
    for (int d8 = 0; d8 < 8; ++d8){
        #pragma unroll
        for (int r = 0; r < 4; ++r){
            out[((size_t)bb*LL + qw0 + 4*g + r)*DD + d8*16 + ln15] = oacc[d8][r];
        }
    }
}

extern "C" void kernel_launch(void* const* d_in, const int* in_sizes, int n_in,
                              void* d_out, int out_size, void* d_ws, size_t ws_size,
                              hipStream_t stream)
{
    const float* q = (const float*)d_in[0];
    const float* k = (const float*)d_in[1];
    const float* v = (const float*)d_in[2];
    const unsigned char* mask = (const unsigned char*)d_in[3];

    float* out  = (float*)d_out;
    float* attn = out + (size_t)BB*LL*DD;

    const size_t oO      = (size_t)BB*LL*DD*sizeof(float);         // 16.8 MB / partial
    const size_t bits_sz = (size_t)BB*LL*NT*sizeof(u64);           // 8.39 MB
    const size_t off_lp  = 256 + bits_sz;
    const size_t lp_sz   = (size_t)SPLIT_S*BB*LL*sizeof(float);    // 512 KB
    const size_t off_pS  = off_lp + lp_sz;
    const size_t pS_sz   = (size_t)BB*LL*LL*sizeof(unsigned short);// 134.2 MB
    const size_t off_pOv2= off_pS + pS_sz;
    const size_t need_v2 = off_pOv2 + 2*oO;                        // ~176.7 MB
    const size_t off_pOo = off_pS;                                 // old paths: pO where pS would be
    const size_t need_o4 = off_pOo + 4*oO;                         // ~75.9 MB (r11-proven)
    const size_t need_o2 = off_pOo + 2*oO;                         // ~42.4 MB (r10-proven)
    const size_t need_bits = off_lp;

    int*   flag  = (int*)d_ws;
    u64*   mb    = (u64*)((char*)d_ws + 256);
    float* lpart = (float*)((char*)d_ws + off_lp);
    unsigned short* pS = (unsigned short*)((char*)d_ws + off_pS);
    float* pOv2  = (float*)((char*)d_ws + off_pOv2);
    float* pOo   = (float*)((char*)d_ws + off_pOo);

    if (ws_size >= need_v2){
        prepack_mask<<<(BB*LL*NT)/THREADS, THREADS, 0, stream>>>(mask, mb);
        scores<1><<<NWG_S, TMAIN, 0, stream>>>(q, k, mb, lpart, pS);
        attn_main_v2<2><<<BB*2*(LL/QTM), TMAIN, 0, stream>>>(v, pS, lpart, attn, pOv2);
        combine_out<2><<<(BB*LL*DD)/(4*THREADS), THREADS, 0, stream>>>(pOv2, out);
    } else if (ws_size >= need_o4){
        prepack_mask<<<(BB*LL*NT)/THREADS, THREADS, 0, stream>>>(mask, mb);
        scores<0><<<NWG_S, TMAIN, 0, stream>>>(q, k, mb, lpart, pS);
        attn_main<4><<<BB*4*(LL/QTM), TMAIN, 0, stream>>>(q, k, v, mb, lpart, attn, pOo);
        combine_out<4><<<(BB*LL*DD)/(4*THREADS), THREADS, 0, stream>>>(pOo, out);
    } else if (ws_size >= need_o2){
        prepack_mask<<<(BB*LL*NT)/THREADS, THREADS, 0, stream>>>(mask, mb);
        scores<0><<<NWG_S, TMAIN, 0, stream>>>(q, k, mb, lpart, pS);
        attn_main<2><<<BB*2*(LL/QTM), TMAIN, 0, stream>>>(q, k, v, mb, lpart, attn, pOo);
        combine_out<2><<<(BB*LL*DD)/(4*THREADS), THREADS, 0, stream>>>(pOo, out);
    } else if (ws_size >= need_bits){
        detect_mask<<<1, 64, 0, stream>>>((const unsigned*)mask, flag);
        prepack_mask<<<(BB*LL*NT)/THREADS, THREADS, 0, stream>>>(mask, mb);
        attn_fused<1><<<NWG, THREADS, 0, stream>>>(q, k, v, mask, flag, mb, out, attn);
    } else {
        detect_mask<<<1, 64, 0, stream>>>((const unsigned*)mask, flag);
        attn_fused<0><<<NWG, THREADS, 0, stream>>>(q, k, v, mask, flag, mb, out, attn);
    }
}

// Round 13
// 241.601 us; speedup vs baseline: 2.2155x; 1.0136x over previous
//
#include <hip/hip_runtime.h>
#include <hip/hip_bf16.h>

#define BB 16
#define LL 2048
#define DD 128
#define SCALE 0.03125f   // 1/sqrt(1024)

#define QT 64            // fallback q-tile
#define QTM 128          // main/scores q-tile (512-thread blocks)
#define KT 64
#define NT (LL/KT)       // 32
#define SPLIT_S 4
#define SKT (NT/SPLIT_S) // 8
#define THREADS 256
#define TMAIN 512
#define NWG   (BB*(LL/QT))          // 512  (fallback grid)
#define NWG_S (BB*SPLIT_S*(LL/QTM)) // 1024 (scores grid)

using bf16x8 = __attribute__((ext_vector_type(8))) short;
using f32x4  = __attribute__((ext_vector_type(4))) float;
using u16x4  = __attribute__((ext_vector_type(4))) unsigned short;
using u32x2  = __attribute__((ext_vector_type(2))) unsigned;
typedef unsigned long long u64;

__device__ __forceinline__ unsigned short f2bf(float f){
    __hip_bfloat16 h = __float2bfloat16(f);
    return *reinterpret_cast<unsigned short*>(&h);
}
__device__ __forceinline__ float bf2f(unsigned short u){
    union { unsigned u; float f; } a; a.u = ((unsigned)u) << 16;
    return a.f;
}
__device__ __forceinline__ unsigned pk2(float lo, float hi){
    return (unsigned)f2bf(lo) | ((unsigned)f2bf(hi) << 16);
}

// Mask layout: 0 = 4-byte int, 1 = 1-byte bool, 2 = 4-byte float.
__device__ __forceinline__ int detect_fl(const unsigned* m, int lane){
    unsigned hi = 0, nl = 0;
    #pragma unroll
    for (int i = 0; i < 16; ++i){
        unsigned d = m[lane*16 + i];
        hi |= (d & 0xFFFFFF00u);
        nl |= (d & 0xFEFEFEFEu);
    }
    unsigned long long bh = __ballot(hi != 0u);
    unsigned long long bn = __ballot(nl != 0u);
    return (bn != 0ull) ? 2 : ((bh != 0ull) ? 1 : 0);
}

__global__ void detect_mask(const unsigned* __restrict__ m, int* __restrict__ flag){
    int f = detect_fl(m, threadIdx.x & 63);
    if ((threadIdx.x & 63) == 0) flag[0] = f;
}

// bit-prepack (fallback paths only now)
__global__ void prepack_mask(const unsigned char* __restrict__ m,
                             u64* __restrict__ mb){
    __shared__ int sfl;
    if (threadIdx.x < 64){
        int f = detect_fl((const unsigned*)m, threadIdx.x);
        if (threadIdx.x == 0) sfl = f;
    }
    __syncthreads();
    const int fl = sfl;
    int id = blockIdx.x * THREADS + threadIdx.x;
    u64 bits = 0;
    if (fl == 1){
        const uint4* mp = (const uint4*)(m + (size_t)id * 64);
        #pragma unroll
        for (int c = 0; c < 4; ++c){
            uint4 u = mp[c];
            unsigned wd[4] = {u.x, u.y, u.z, u.w};
            #pragma unroll
            for (int wi = 0; wi < 4; ++wi){
                #pragma unroll
                for (int b = 0; b < 4; ++b)
                    if ((wd[wi] >> (8*b)) & 0xFFu) bits |= 1ull << (c*16 + wi*4 + b);
            }
        }
    } else {
        const uint4* mp = (const uint4*)m + (size_t)id * 16;
        #pragma unroll
        for (int c = 0; c < 16; ++c){
            uint4 u = mp[c];
            if (u.x) bits |= 1ull << (c*4+0);
            if (u.y) bits |= 1ull << (c*4+1);
            if (u.z) bits |= 1ull << (c*4+2);
            if (u.w) bits |= 1ull << (c*4+3);
        }
    }
    mb[id] = bits;
}

// ---------------- 256-thread staging macros (fallback) ----------------
#define K_LOAD(T) { const float* kp_ = kbase + (size_t)(T)*KT*DD; \
    _Pragma("unroll") for (int i_ = 0; i_ < 8; ++i_) \
        kpre[i_] = *(const f32x4*)(kp_ + (i_*8 + r0)*DD + c4*4); }

#define K_WRITE() { _Pragma("unroll") for (int i_ = 0; i_ < 8; ++i_){ \
        int row_ = i_*8 + r0; int e_ = (c4*4) ^ (8*(row_ & 7)); \
        u16x4 pk_ = { f2bf(kpre[i_][0]), f2bf(kpre[i_][1]), f2bf(kpre[i_][2]), f2bf(kpre[i_][3]) }; \
        *(u16x4*)(&k_s[row_*DD + e_]) = pk_; } }

#define V_STAGE(T) { const float* vp_ = vbase + (size_t)(T)*KT*DD; \
    f32x4 vv_[8]; \
    _Pragma("unroll") for (int i_ = 0; i_ < 2; ++i_) \
        _Pragma("unroll") for (int rr_ = 0; rr_ < 4; ++rr_) \
            vv_[i_*4+rr_] = *(const f32x4*)(vp_ + ((r0 + 8*i_)*4 + rr_)*DD + c4*4); \
    _Pragma("unroll") for (int i_ = 0; i_ < 2; ++i_){ \
        int rb_ = (r0 + 8*i_)*4; int kk_ = rb_ ^ (8*(c4 & 7)); \
        _Pragma("unroll") for (int cc_ = 0; cc_ < 4; ++cc_){ \
            int d_ = c4*4 + cc_; \
            u16x4 pk_ = { f2bf(vv_[i_*4+0][cc_]), f2bf(vv_[i_*4+1][cc_]), \
                          f2bf(vv_[i_*4+2][cc_]), f2bf(vv_[i_*4+3][cc_]) }; \
            *(u16x4*)(&vT_s[d_*KT + kk_]) = pk_; } } }

#define M_LOADB(DST, T) { _Pragma("unroll") for (int r_ = 0; r_ < 4; ++r_) DST[r_] = mbB[r_*NT + (T)]; }

// ---------------- 512-thread staging macros ----------------
#define K_LOAD4(T) { const float* kp_ = kbase + (size_t)(T)*KT*DD; \
    _Pragma("unroll") for (int i_ = 0; i_ < 4; ++i_) \
        kpre[i_] = *(const f32x4*)(kp_ + (i_*16 + r0)*DD + c4*4); }

#define K_WRITE4() { _Pragma("unroll") for (int i_ = 0; i_ < 4; ++i_){ \
        int row_ = i_*16 + r0; int e_ = (c4*4) ^ (8*(row_ & 7)); \
        u16x4 pk_ = { f2bf(kpre[i_][0]), f2bf(kpre[i_][1]), f2bf(kpre[i_][2]), f2bf(kpre[i_][3]) }; \
        *(u16x4*)(&k_s[row_*DD + e_]) = pk_; } }

#define V_LOAD4(T) { const float* vp_ = vbase + (size_t)(T)*KT*DD; \
    _Pragma("unroll") for (int rr_ = 0; rr_ < 4; ++rr_) \
        vpre[rr_] = *(const f32x4*)(vp_ + (r0*4 + rr_)*DD + c4*4); }

#define V_WRITE4() { \
    _Pragma("unroll") for (int cc_ = 0; cc_ < 4; ++cc_){ \
        int d_ = c4*4 + cc_; \
        int key_ = (c4 & 7) ^ ((cc_ << 1) & 7); \
        int kk_ = (r0*4) ^ (8*key_); \
        u16x4 pk_ = { f2bf(vpre[0][cc_]), f2bf(vpre[1][cc_]), \
                      f2bf(vpre[2][cc_]), f2bf(vpre[3][cc_]) }; \
        *(u16x4*)(&vT_s[d_*KT + kk_]) = pk_; } }

// original orientation (fallback only)
#define QK_MFMA(ACC, CG) { \
    const int krow_ = (CG)*16 + ln15; \
    const unsigned short* kb_ = &k_s[krow_*DD]; \
    const int sw_ = 8*(krow_ & 7); \
    _Pragma("unroll") for (int c_ = 0; c_ < 4; ++c_){ \
        bf16x8 bf_ = *(const bf16x8*)(kb_ + ((c_*32 + g*8) ^ sw_)); \
        ACC = __builtin_amdgcn_mfma_f32_16x16x32_bf16(qa[c_], bf_, ACC, 0, 0, 0); } }

// SWAPPED: acc[r] = S[q=ln15][k=cg*16+4g+r]
#define QK_MFMA_SW(ACC, CG) { \
    const int krow_ = (CG)*16 + ln15; \
    const unsigned short* kb_ = &k_s[krow_*DD]; \
    const int sw_ = 8*(krow_ & 7); \
    _Pragma("unroll") for (int c_ = 0; c_ < 4; ++c_){ \
        bf16x8 bf_ = *(const bf16x8*)(kb_ + ((c_*32 + g*8) ^ sw_)); \
        ACC = __builtin_amdgcn_mfma_f32_16x16x32_bf16(bf_, qa[c_], ACC, 0, 0, 0); } }

#define Q_FRAGS() { \
    const float* qp_ = q + ((size_t)bb*LL + qw0 + ln15)*DD + g*8; \
    _Pragma("unroll") for (int c_ = 0; c_ < 4; ++c_){ \
        f32x4 x_ = *(const f32x4*)(qp_ + c_*32); \
        f32x4 y_ = *(const f32x4*)(qp_ + c_*32 + 4); \
        bf16x8 t_; \
        t_[0]=(short)f2bf(x_[0]); t_[1]=(short)f2bf(x_[1]); t_[2]=(short)f2bf(x_[2]); t_[3]=(short)f2bf(x_[3]); \
        t_[4]=(short)f2bf(y_[0]); t_[5]=(short)f2bf(y_[1]); t_[6]=(short)f2bf(y_[2]); t_[7]=(short)f2bf(y_[3]); \
        qa[c_] = t_; } }

// ===== kernel 1: scores — direct-mask QK + exp; partial row sums + optional P~ =====
// Mask read folded in (wide: one uint4/lane/cg; byte: one uint) — lanes
// (ln15, g=0..3) cover 64B contiguous, each mask element read once grid-wide.
template<int STOREP>
__global__ __launch_bounds__(TMAIN, 4) void scores(
    const float* __restrict__ q, const float* __restrict__ k,
    const unsigned char* __restrict__ maskb, const int* __restrict__ flagp,
    float* __restrict__ lpart, unsigned short* __restrict__ pS)
{
    __shared__ __attribute__((aligned(16))) unsigned short k_s[KT*DD];   // 16 KB
    __shared__ __attribute__((aligned(16))) unsigned p_u32[8*512];       // 16 KB

    const int tid  = threadIdx.x;
    const int w    = tid >> 6;
    const int lane = tid & 63;
    const int ln15 = lane & 15;
    const int g    = lane >> 4;
    const int r0   = tid >> 5;
    const int c4   = tid & 31;

    const int hw    = blockIdx.x;
    const int bidx  = (hw & 7) * (NWG_S/8) + (hw >> 3);   // XCD-contiguous
    const int bb    = bidx >> 6;
    const int quart = (bidx >> 4) & 3;
    const int qt0   = (bidx & 15) * QTM;
    const int qw0   = qt0 + w*16;

    bf16x8 qa[4];
    Q_FRAGS();

    const int fl = flagp[0];                      // uniform (s-branch)
    const size_t qrow = (size_t)bb*LL + qw0 + ln15;
    const unsigned char* mrowB = maskb + qrow*(size_t)LL;       // byte layout
    const unsigned char* mrowW = maskb + qrow*(size_t)LL*4;     // 4B layouts

    const float* kbase = k + (size_t)bb*LL*DD;
    f32x4 kpre[4];
    uint4 m4c[4], m4n[4];
    unsigned m1c[4], m1n[4];

#define MSK_LOAD(W4, B1, T) { \
    if (fl != 1){ _Pragma("unroll") for (int c_ = 0; c_ < 4; ++c_) \
        W4[c_] = *(const uint4*)(mrowW + ((size_t)(T)*KT + c_*16 + 4*g)*4); } \
    else        { _Pragma("unroll") for (int c_ = 0; c_ < 4; ++c_) \
        B1[c_] = *(const unsigned*)(mrowB + (size_t)(T)*KT + c_*16 + 4*g); } }

    unsigned* pw = &p_u32[w*512];

    const int T0 = quart * SKT;
    float rs = 0.f;
    K_LOAD4(T0); MSK_LOAD(m4c, m1c, T0);
    for (int tt = 0; tt < SKT; ++tt){
        const int t = T0 + tt;
        __syncthreads();
        K_WRITE4();
        if (tt+1 < SKT){ K_LOAD4(t+1); MSK_LOAD(m4n, m1n, t+1); }
        __syncthreads();
        #pragma unroll
        for (int cg = 0; cg < 4; ++cg){
            f32x4 acc = {0.f, 0.f, 0.f, 0.f};
            QK_MFMA_SW(acc, cg);
            bool k0, k1, k2, k3;
            if (fl != 1){
                uint4 u = m4c[cg];
                k0 = u.x != 0u; k1 = u.y != 0u; k2 = u.z != 0u; k3 = u.w != 0u;
            } else {
                unsigned u = m1c[cg];
                k0 = (u & 0xFFu) != 0u;       k1 = (u & 0xFF00u) != 0u;
                k2 = (u & 0xFF0000u) != 0u;   k3 = (u & 0xFF000000u) != 0u;
            }
            float p0 = k0 ? 0.f : __expf(acc[0] * SCALE);
            float p1 = k1 ? 0.f : __expf(acc[1] * SCALE);
            float p2 = k2 ? 0.f : __expf(acc[2] * SCALE);
            float p3 = k3 ? 0.f : __expf(acc[3] * SCALE);
            rs += (p0 + p1) + (p2 + p3);
            if (STOREP){
                const int mp = ((cg*4 + g) + ln15) & 15;
                u32x2 wv = { pk2(p0, p1), pk2(p2, p3) };
                *(u32x2*)(&pw[ln15*32 + mp*2]) = wv;
            }
        }
        if (STOREP){
            // write P~ tile: per instr 4 rows x 128B contiguous bf16 (cached,
            // NOT nontemporal — main_v2 wants these L2/L3-resident)
            #pragma unroll
            for (int i = 0; i < 4; ++i){
                const int rl = i*4 + g;
                u32x2 pb = *(const u32x2*)(&pw[rl*32 + (((ln15 + rl) & 15)*2)]);
                *(u32x2*)(pS + ((size_t)bb*LL + qw0 + rl)*(size_t)LL + t*KT + ln15*4) = pb;
            }
        }
        #pragma unroll
        for (int c_ = 0; c_ < 4; ++c_){ m4c[c_] = m4n[c_]; m1c[c_] = m1n[c_]; }
    }
    rs += __shfl_xor(rs, 16);
    rs += __shfl_xor(rs, 32);
    if (lane < 16)
        lpart[(size_t)quart*BB*LL + (size_t)bb*LL + qw0 + lane] = rs;
#undef MSK_LOAD
}

// ===== kernel 2 V2: read P~ (pipelined), write attn (normalized) + partial PV =====
template<int NS>
__global__ __launch_bounds__(TMAIN, 4) void attn_main_v2(
    const float* __restrict__ v, const unsigned short* __restrict__ pS,
    const float* __restrict__ lpart,
    float* __restrict__ attn, float* __restrict__ pO)
{
    __shared__ __attribute__((aligned(16))) unsigned short vT_s[DD*KT];   // 16 KB

    const int tid  = threadIdx.x;
    const int w    = tid >> 6;
    const int lane = tid & 63;
    const int ln15 = lane & 15;
    const int g    = lane >> 4;
    const int r0   = tid >> 5;
    const int c4   = tid & 31;

    const int NWGM = BB*NS*(LL/QTM);
    const int hw   = blockIdx.x;
    const int bidx = (hw & 7) * (NWGM/8) + (hw >> 3);
    const int perb = NS*(LL/QTM);
    const int bb   = bidx / perb;
    const int rem  = bidx % perb;
    const int part = rem >> 4;
    const int qt0  = (rem & 15) * QTM;
    const int qw0  = qt0 + w*16;

    float invlA[4], invlE[4];
    #pragma unroll
    for (int i = 0; i < 4; ++i){
        float sA = 0.f, sE = 0.f;
        #pragma unroll
        for (int sl = 0; sl < SPLIT_S; ++sl){
            sA += lpart[(size_t)sl*BB*LL + (size_t)bb*LL + qw0 + i*4 + g];
            sE += lpart[(size_t)sl*BB*LL + (size_t)bb*LL + qw0 + 4*g + i];
        }
        invlA[i] = 1.0f / sA;
        invlE[i] = 1.0f / sE;
    }

    const float* vbase = v + (size_t)bb*LL*DD;
    f32x4 vpre[4];

    const unsigned short* prow = pS + ((size_t)bb*LL + qw0 + ln15)*(size_t)LL;
    size_t arow_off[4];
    #pragma unroll
    for (int i = 0; i < 4; ++i)
        arow_off[i] = ((size_t)bb*LL + qw0 + i*4 + g)*(size_t)LL;

#define P_LOAD(PA0, PA1, PB, T) { \
    PA0 = *(const bf16x8*)(prow + (size_t)(T)*KT + 8*g); \
    PA1 = *(const bf16x8*)(prow + (size_t)(T)*KT + 32 + 8*g); \
    _Pragma("unroll") for (int i_ = 0; i_ < 4; ++i_) \
        PB[i_] = *(const u32x2*)(pS + arow_off[i_] + (size_t)(T)*KT + ln15*4); }

    f32x4 oacc[8];
    #pragma unroll
    for (int d8 = 0; d8 < 8; ++d8) oacc[d8] = (f32x4){0.f, 0.f, 0.f, 0.f};

    bf16x8 pa0c, pa1c, pa0n, pa1n;
    u32x2 pbc[4], pbn[4];

    const int HKTN = NT/NS;
    const int T0 = part * HKTN;
    V_LOAD4(T0);
    P_LOAD(pa0c, pa1c, pbc, T0);
    for (int tt = 0; tt < HKTN; ++tt){
        const int t = T0 + tt;
        __syncthreads();
        V_WRITE4();
        if (tt+1 < HKTN){
            V_LOAD4(t+1);
            P_LOAD(pa0n, pa1n, pbn, t+1);   // full tile of compute covers L3 latency
        }
        __syncthreads();
        // attn: normalized, 256B-contiguous NT stores (4 rows per instr)
        #pragma unroll
        for (int i = 0; i < 4; ++i){
            f32x4 val = { bf2f((unsigned short)(pbc[i][0] & 0xFFFFu)) * invlA[i],
                          bf2f((unsigned short)(pbc[i][0] >> 16))     * invlA[i],
                          bf2f((unsigned short)(pbc[i][1] & 0xFFFFu)) * invlA[i],
                          bf2f((unsigned short)(pbc[i][1] >> 16))     * invlA[i] };
            __builtin_nontemporal_store(val,
                (f32x4*)(attn + arow_off[i] + (size_t)t*KT + ln15*4));
        }
        // PV on raw P~ (invl applied at epilogue)
        #pragma unroll
        for (int d8 = 0; d8 < 8; ++d8){
            const int d = d8*16 + ln15;
            const unsigned short* vb = &vT_s[d*KT];
            const int ev = 8*((((4*d8 + (ln15 >> 2)) & 7)) ^ ((ln15 & 3) << 1));
            bf16x8 b0 = *(const bf16x8*)(vb + ((g*8) ^ ev));
            bf16x8 b1 = *(const bf16x8*)(vb + ((32 + g*8) ^ ev));
            oacc[d8] = __builtin_amdgcn_mfma_f32_16x16x32_bf16(pa0c, b0, oacc[d8], 0, 0, 0);
            oacc[d8] = __builtin_amdgcn_mfma_f32_16x16x32_bf16(pa1c, b1, oacc[d8], 0, 0, 0);
        }
        pa0c = pa0n; pa1c = pa1n;
        #pragma unroll
        for (int i = 0; i < 4; ++i) pbc[i] = pbn[i];
    }
#undef P_LOAD

    // epilogue: partial O, scaled by invlE
    float* po = pO + (size_t)part*BB*LL*DD;
    #pragma unroll
    for (int d8 = 0; d8 < 8; ++d8){
        #pragma unroll
        for (int r = 0; r < 4; ++r){
            po[((size_t)bb*LL + qw0 + 4*g + r)*DD + d8*16 + ln15] = oacc[d8][r] * invlE[r];
        }
    }
}

// ===== old kernel 2 (r11-proven fallback): QK in-kernel =====
template<int NS>
__global__ __launch_bounds__(TMAIN, 4) void attn_main(
    const float* __restrict__ q, const float* __restrict__ k, const float* __restrict__ v,
    const u64* __restrict__ mb, const float* __restrict__ lpart,
    float* __restrict__ attn, float* __restrict__ pO)
{
    __shared__ __attribute__((aligned(16))) unsigned short k_s[KT*DD];
    __shared__ __attribute__((aligned(16))) unsigned short vT_s[DD*KT];
    __shared__ __attribute__((aligned(16))) unsigned p_u32[8*512];

    const int tid  = threadIdx.x;
    const int w    = tid >> 6;
    const int lane = tid & 63;
    const int ln15 = lane & 15;
    const int g    = lane >> 4;
    const int r0   = tid >> 5;
    const int c4   = tid & 31;

    const int NWGM = BB*NS*(LL/QTM);
    const int hw   = blockIdx.x;
    const int bidx = (hw & 7) * (NWGM/8) + (hw >> 3);
    const int perb = NS*(LL/QTM);
    const int bb   = bidx / perb;
    const int rem  = bidx % perb;
    const int part = rem >> 4;
    const int qt0  = (rem & 15) * QTM;
    const int qw0  = qt0 + w*16;

    bf16x8 qa[4];
    Q_FRAGS();

    const size_t qrow = (size_t)bb*LL + qw0 + ln15;
    const u64* mrow_bits = mb + qrow * NT;
    float invl;
    {
        float s = 0.f;
        #pragma unroll
        for (int sl = 0; sl < SPLIT_S; ++sl)
            s += lpart[(size_t)sl*BB*LL + qrow];
        invl = 1.0f / s;
    }

    const float* kbase = k + (size_t)bb*LL*DD;
    const float* vbase = v + (size_t)bb*LL*DD;
    f32x4 kpre[4];
    f32x4 vpre[4];
    u64 mc = 0, mn = 0;

    f32x4 oacc[8];
    #pragma unroll
    for (int d8 = 0; d8 < 8; ++d8) oacc[d8] = (f32x4){0.f, 0.f, 0.f, 0.f};

    unsigned* pw = &p_u32[w*512];

    const int HKTN = NT/NS;
    const int T0 = part * HKTN;
    K_LOAD4(T0); V_LOAD4(T0); mc = mrow_bits[T0];
    for (int tt = 0; tt < HKTN; ++tt){
        const int t = T0 + tt;
        __syncthreads();
        K_WRITE4(); V_WRITE4();
        if (tt+1 < HKTN){ K_LOAD4(t+1); V_LOAD4(t+1); mn = mrow_bits[t+1]; }
        __syncthreads();
        #pragma unroll
        for (int cg = 0; cg < 4; ++cg){
            f32x4 acc = {0.f, 0.f, 0.f, 0.f};
            QK_MFMA_SW(acc, cg);
            const int kb0 = cg*16 + 4*g;
            const unsigned nib = (unsigned)(mc >> kb0) & 0xFu;
            f32x4 pv;
            #pragma unroll
            for (int r = 0; r < 4; ++r)
                pv[r] = ((nib >> r) & 1u) ? 0.f : __expf(acc[r] * SCALE) * invl;
            const int m  = cg*4 + g;
            const int mp = (m + ln15) & 15;
            u32x2 wv = { pk2(pv[0], pv[1]), pk2(pv[2], pv[3]) };
            *(u32x2*)(&pw[ln15*32 + mp*2]) = wv;
        }
        #pragma unroll
        for (int it = 0; it < 4; ++it){
            const int rl = it*4 + g;
            u32x2 pb = *(const u32x2*)(&pw[rl*32 + (((ln15 + rl) & 15)*2)]);
            f32x4 val = { bf2f((unsigned short)(pb[0] & 0xFFFFu)),
                          bf2f((unsigned short)(pb[0] >> 16)),
                          bf2f((unsigned short)(pb[1] & 0xFFFFu)),
                          bf2f((unsigned short)(pb[1] >> 16)) };
            __builtin_nontemporal_store(val,
                (f32x4*)(attn + ((size_t)bb*LL + qw0 + rl)*(size_t)LL + t*KT + ln15*4));
        }
        const unsigned* prow_ = &pw[ln15*32];
        u32x2 a00 = *(const u32x2*)(&prow_[(((2*g  ) + ln15) & 15)*2]);
        u32x2 a01 = *(const u32x2*)(&prow_[(((2*g+1) + ln15) & 15)*2]);
        u32x2 a10 = *(const u32x2*)(&prow_[(((8+2*g ) + ln15) & 15)*2]);
        u32x2 a11 = *(const u32x2*)(&prow_[(((9+2*g ) + ln15) & 15)*2]);
        union { unsigned u[4]; bf16x8 v8; } A0, A1;
        A0.u[0]=a00[0]; A0.u[1]=a00[1]; A0.u[2]=a01[0]; A0.u[3]=a01[1];
        A1.u[0]=a10[0]; A1.u[1]=a10[1]; A1.u[2]=a11[0]; A1.u[3]=a11[1];
        const bf16x8 pa0 = A0.v8, pa1 = A1.v8;
        #pragma unroll
        for (int d8 = 0; d8 < 8; ++d8){
            const int d = d8*16 + ln15;
            const unsigned short* vb = &vT_s[d*KT];
            const int ev = 8*((((4*d8 + (ln15 >> 2)) & 7)) ^ ((ln15 & 3) << 1));
            bf16x8 b0 = *(const bf16x8*)(vb + ((g*8) ^ ev));
            bf16x8 b1 = *(const bf16x8*)(vb + ((32 + g*8) ^ ev));
            oacc[d8] = __builtin_amdgcn_mfma_f32_16x16x32_bf16(pa0, b0, oacc[d8], 0, 0, 0);
            oacc[d8] = __builtin_amdgcn_mfma_f32_16x16x32_bf16(pa1, b1, oacc[d8], 0, 0, 0);
        }
        mc = mn;
    }

    float* po = pO + (size_t)part*BB*LL*DD;
    #pragma unroll
    for (int d8 = 0; d8 < 8; ++d8){
        #pragma unroll
        for (int r = 0; r < 4; ++r){
            po[((size_t)bb*LL + qw0 + 4*g + r)*DD + d8*16 + ln15] = oacc[d8][r];
        }
    }
}

template<int NS>
__global__ void combine_out(const float* __restrict__ pO, float* __restrict__ out){
    size_t i = ((size_t)blockIdx.x*THREADS + threadIdx.x) * 4;
    f32x4 s = *(const f32x4*)(pO + i);
    #pragma unroll
    for (int sl = 1; sl < NS; ++sl)
        s += *(const f32x4*)(pO + (size_t)sl*BB*LL*DD + i);
    *(f32x4*)(out + i) = s;
}

// ================= fallback: fused two-pass (unswapped) =================
template<int USE_BITS>
__global__ __launch_bounds__(THREADS, 3) void attn_fused(
    const float* __restrict__ q, const float* __restrict__ k, const float* __restrict__ v,
    const unsigned char* __restrict__ maskb, const int* __restrict__ flagp,
    const u64* __restrict__ mb,
    float* __restrict__ out, float* __restrict__ attn)
{
    __shared__ __attribute__((aligned(16))) unsigned short k_s[KT*DD];
    __shared__ __attribute__((aligned(16))) unsigned short vT_s[DD*KT];
    __shared__ __attribute__((aligned(16))) unsigned short p_bf[4*16*64];

    const int tid  = threadIdx.x;
    const int w    = tid >> 6;
    const int lane = tid & 63;
    const int ln15 = lane & 15;
    const int g    = lane >> 4;
    const int r0   = tid >> 5;
    const int c4   = tid & 31;

    const int bidx = blockIdx.x;
    const int bb   = bidx >> 5;
    const int qt0  = (bidx & 31) * QT;
    const int qw0  = qt0 + w*16;

    int msh = 0, madd = 0;
    if (!USE_BITS){
        const int mflag = flagp[0];
        msh  = (mflag == 1) ? 0 : 2;
        madd = (mflag == 2) ? 3 : 0;
    }

    bf16x8 qa[4];
    Q_FRAGS();

    size_t mrow[4];
    const u64* mbB = mb + ((size_t)bb*LL + qw0 + 4*g) * NT;
    #pragma unroll
    for (int r = 0; r < 4; ++r)
        mrow[r] = ((size_t)bb*LL + qw0 + 4*g + r) * (size_t)LL;

    const float* kbase = k + (size_t)bb*LL*DD;
    const float* vbase = v + (size_t)bb*LL*DD;

    f32x4 kpre[8];
    u64 mc[4] = {0,0,0,0}, mn[4] = {0,0,0,0};

    float rs[4] = {0.f, 0.f, 0.f, 0.f};
    K_LOAD(0); if (USE_BITS) M_LOADB(mc, 0);
    for (int t = 0; t < NT; ++t){
        __syncthreads();
        K_WRITE();
        if (t+1 < NT){ K_LOAD(t+1); if (USE_BITS) M_LOADB(mn, t+1); }
        __syncthreads();
        #pragma unroll
        for (int cg = 0; cg < 4; ++cg){
            f32x4 acc = {0.f, 0.f, 0.f, 0.f};
            QK_MFMA(acc, cg);
            const int kc = cg*16 + ln15;
            #pragma unroll
            for (int r = 0; r < 4; ++r){
                bool msk;
                if (USE_BITS) msk = (mc[r] >> kc) & 1ull;
                else          msk = maskb[((mrow[r] + t*KT + kc) << msh) + madd] != 0;
                rs[r] += msk ? 0.f : __expf(acc[r] * SCALE);
            }
        }
        if (USE_BITS){
            #pragma unroll
            for (int r = 0; r < 4; ++r) mc[r] = mn[r];
        }
    }

    float invl[4];
    #pragma unroll
    for (int r = 0; r < 4; ++r){
        float s = rs[r];
        s += __shfl_xor(s, 1); s += __shfl_xor(s, 2);
        s += __shfl_xor(s, 4); s += __shfl_xor(s, 8);
        invl[r] = 1.0f / s;
    }

    f32x4 oacc[8];
    #pragma unroll
    for (int d8 = 0; d8 < 8; ++d8) oacc[d8] = (f32x4){0.f, 0.f, 0.f, 0.f};

    unsigned short* pw = &p_bf[w*1024];
    const int w4 = ln15 >> 2;

    K_LOAD(0); if (USE_BITS) M_LOADB(mc, 0);
    for (int t = 0; t < NT; ++t){
        __syncthreads();
        K_WRITE();
        V_STAGE(t);
        if (t+1 < NT){ K_LOAD(t+1); if (USE_BITS) M_LOADB(mn, t+1); }
        __syncthreads();
        #pragma unroll
        for (int cg = 0; cg < 4; ++cg){
            f32x4 acc = {0.f, 0.f, 0.f, 0.f};
            QK_MFMA(acc, cg);
            const int kc = cg*16 + ln15;
            #pragma unroll
            for (int r = 0; r < 4; ++r){
                bool msk;
                if (USE_BITS) msk = (mc[r] >> kc) & 1ull;
                else          msk = maskb[((mrow[r] + t*KT + kc) << msh) + madd] != 0;
                float p = msk ? 0.f : __expf(acc[r] * SCALE) * invl[r];
                pw[(4*g + r)*64 + (kc ^ (g << 4))] = f2bf(p);
            }
        }
        #pragma unroll
        for (int it = 0; it < 4; ++it){
            int row = it*4 + g;
            u16x4 pb = *(const u16x4*)(&pw[row*64 + ((ln15*4) ^ (it << 4))]);
            f32x4 val = { bf2f(pb[0]), bf2f(pb[1]), bf2f(pb[2]), bf2f(pb[3]) };
            *(f32x4*)(&attn[((size_t)bb*LL + qw0 + row)*(size_t)LL + t*KT + ln15*4]) = val;
        }
        const unsigned short* par = pw + ln15*64;
        bf16x8 pa0 = *(const bf16x8*)(par + ((g*8)      ^ (w4 << 4)));
        bf16x8 pa1 = *(const bf16x8*)(par + ((32 + g*8) ^ (w4 << 4)));
        #pragma unroll
        for (int d8 = 0; d8 < 8; ++d8){
            const int d = d8*16 + ln15;
            const unsigned short* vb = &vT_s[d*KT];
            const int ev = 8*((4*d8 + (ln15 >> 2)) & 7);
            bf16x8 b0 = *(const bf16x8*)(vb + ((g*8) ^ ev));
            bf16x8 b1 = *(const bf16x8*)(vb + ((32 + g*8) ^ ev));
            oacc[d8] = __builtin_amdgcn_mfma_f32_16x16x32_bf16(pa0, b0, oacc[d8], 0, 0, 0);
            oacc[d8] = __builtin_amdgcn_mfma_f32_16x16x32_bf16(pa1, b1, oacc[d8], 0, 0, 0);
        }
        if (USE_BITS){
            #pragma unroll
            for (int r = 0; r < 4; ++r) mc[r] = mn[r];
        }
    }

    #pragma unroll
    for (int d8 = 0; d8 < 8; ++d8){
        #pragma unroll
        for (int r = 0; r < 4; ++r){
            out[((size_t)bb*LL + qw0 + 4*g + r)*DD + d8*16 + ln15] = oacc[d8][r];
        }
    }
}

extern "C" void kernel_launch(void* const* d_in, const int* in_sizes, int n_in,
                              void* d_out, int out_size, void* d_ws, size_t ws_size,
                              hipStream_t stream)
{
    const float* q = (const float*)d_in[0];
    const float* k = (const float*)d_in[1];
    const float* v = (const float*)d_in[2];
    const unsigned char* mask = (const unsigned char*)d_in[3];

    float* out  = (float*)d_out;
    float* attn = out + (size_t)BB*LL*DD;

    const size_t oO      = (size_t)BB*LL*DD*sizeof(float);         // 16.8 MB / partial
    const size_t bits_sz = (size_t)BB*LL*NT*sizeof(u64);           // 8.39 MB
    const size_t off_lp  = 256 + bits_sz;
    const size_t lp_sz   = (size_t)SPLIT_S*BB*LL*sizeof(float);    // 512 KB
    const size_t off_pS  = off_lp + lp_sz;
    const size_t pS_sz   = (size_t)BB*LL*LL*sizeof(unsigned short);// 134.2 MB
    const size_t off_pOv2= off_pS + pS_sz;
    const size_t need_v2 = off_pOv2 + 2*oO;                        // ~176.7 MB (r12-proven)
    const size_t off_pOo = off_pS;
    const size_t need_o4 = off_pOo + 4*oO;                         // ~75.9 MB (r11-proven)
    const size_t need_o2 = off_pOo + 2*oO;                         // ~42.4 MB (r10-proven)
    const size_t need_bits = off_lp;

    int*   flag  = (int*)d_ws;
    u64*   mb    = (u64*)((char*)d_ws + 256);
    float* lpart = (float*)((char*)d_ws + off_lp);
    unsigned short* pS = (unsigned short*)((char*)d_ws + off_pS);
    float* pOv2  = (float*)((char*)d_ws + off_pOv2);
    float* pOo   = (float*)((char*)d_ws + off_pOo);

    if (ws_size >= need_v2){
        detect_mask<<<1, 64, 0, stream>>>((const unsigned*)mask, flag);
        scores<1><<<NWG_S, TMAIN, 0, stream>>>(q, k, mask, flag, lpart, pS);
        attn_main_v2<2><<<BB*2*(LL/QTM), TMAIN, 0, stream>>>(v, pS, lpart, attn, pOv2);
        combine_out<2><<<(BB*LL*DD)/(4*THREADS), THREADS, 0, stream>>>(pOv2, out);
    } else if (ws_size >= need_o4){
        detect_mask<<<1, 64, 0, stream>>>((const unsigned*)mask, flag);
        prepack_mask<<<(BB*LL*NT)/THREADS, THREADS, 0, stream>>>(mask, mb);
        scores<0><<<NWG_S, TMAIN, 0, stream>>>(q, k, mask, flag, lpart, pS);
        attn_main<4><<<BB*4*(LL/QTM), TMAIN, 0, stream>>>(q, k, v, mb, lpart, attn, pOo);
        combine_out<4><<<(BB*LL*DD)/(4*THREADS), THREADS, 0, stream>>>(pOo, out);
    } else if (ws_size >= need_o2){
        detect_mask<<<1, 64, 0, stream>>>((const unsigned*)mask, flag);
        prepack_mask<<<(BB*LL*NT)/THREADS, THREADS, 0, stream>>>(mask, mb);
        scores<0><<<NWG_S, TMAIN, 0, stream>>>(q, k, mask, flag, lpart, pS);
        attn_main<2><<<BB*2*(LL/QTM), TMAIN, 0, stream>>>(q, k, v, mb, lpart, attn, pOo);
        combine_out<2><<<(BB*LL*DD)/(4*THREADS), THREADS, 0, stream>>>(pOo, out);
    } else if (ws_size >= need_bits){
        detect_mask<<<1, 64, 0, stream>>>((const unsigned*)mask, flag);
        prepack_mask<<<(BB*LL*NT)/THREADS, THREADS, 0, stream>>>(mask, mb);
        attn_fused<1><<<NWG, THREADS, 0, stream>>>(q, k, v, mask, flag, mb, out, attn);
    } else {
        detect_mask<<<1, 64, 0, stream>>>((const unsigned*)mask, flag);
        attn_fused<0><<<NWG, THREADS, 0, stream>>>(q, k, v, mask, flag, mb, out, attn);
    }
}